// Round 1
// baseline (20000.121 us; speedup 1.0000x reference)
//
#include <hip/hip_runtime.h>
#include <hip/hip_bf16.h>
#include <math.h>

#define D_MODEL 768
#define T_SEQ   1024
#define B_BATCH 8
#define NHEAD   12
#define HDIM    64
#define NLAYER  8

static constexpr size_t BTD  = (size_t)B_BATCH * T_SEQ * D_MODEL;  // 6291456
static constexpr int    ROWS = B_BATCH * T_SEQ;                    // 8192
static constexpr float  EPSF = 1.1920928955078125e-07f;            // FLT_EPSILON

// ---------------------------------------------------------------- utilities

__global__ __launch_bounds__(256) void fill_zero4(float4* __restrict__ p, int n4) {
    int i = blockIdx.x * 256 + threadIdx.x;
    if (i < n4) p[i] = make_float4(0.f, 0.f, 0.f, 0.f);
}

__device__ __forceinline__ float block_reduce_sum(float v, float* sbuf) {
    #pragma unroll
    for (int off = 32; off > 0; off >>= 1) v += __shfl_down(v, off);
    __syncthreads();                       // protect sbuf from previous call
    if ((threadIdx.x & 63) == 0) sbuf[threadIdx.x >> 6] = v;
    __syncthreads();
    return sbuf[0] + sbuf[1] + sbuf[2] + sbuf[3];
}

__device__ __forceinline__ float gelu_tanh(float x) {
    float x3 = x * x * x;
    float t  = tanhf(0.7978845608028654f * (x + 0.044715f * x3));
    return 0.5f * x * (1.f + t);
}

// ------------------------------------------------- aggregate + rmsnorm fuse
// h = aggregate(V[0..N-1], q)  (keys rms-normed, softmax over N, values raw)
// xn = rms_norm(h) * ln_s      (feeds the following GEMM directly)
template<int N>
__global__ __launch_bounds__(256)
void agg_norm_kernel(const float* __restrict__ v0, const float* __restrict__ v1,
                     const float* __restrict__ v2, const float* __restrict__ v3,
                     const float* __restrict__ v4, const float* __restrict__ v5,
                     const float* __restrict__ q,  const float* __restrict__ lns,
                     float* __restrict__ xn) {
    __shared__ float sbuf[4];
    const float* V[6] = {v0, v1, v2, v3, v4, v5};
    const size_t row = blockIdx.x;
    const int tid = threadIdx.x;

    float qv[3];
    #pragma unroll
    for (int j = 0; j < 3; ++j) qv[j] = q[tid + j * 256];

    float vv[N][3];
    float logits[N];
    #pragma unroll
    for (int i = 0; i < N; ++i) {
        const float* vr = V[i] + row * D_MODEL;
        float ssq = 0.f, qd = 0.f;
        #pragma unroll
        for (int j = 0; j < 3; ++j) {
            float x = vr[tid + j * 256];
            vv[i][j] = x;
            ssq = fmaf(x, x, ssq);
            qd  = fmaf(qv[j], x, qd);
        }
        float S  = block_reduce_sum(ssq, sbuf);
        float Qd = block_reduce_sum(qd,  sbuf);
        logits[i] = Qd * rsqrtf(S * (1.f / 768.f) + EPSF);
    }
    float mx = logits[0];
    #pragma unroll
    for (int i = 1; i < N; ++i) mx = fmaxf(mx, logits[i]);
    float w[N];
    float wsum = 0.f;
    #pragma unroll
    for (int i = 0; i < N; ++i) { w[i] = __expf(logits[i] - mx); wsum += w[i]; }
    float inv = 1.f / wsum;

    float outv[3] = {0.f, 0.f, 0.f};
    #pragma unroll
    for (int i = 0; i < N; ++i) {
        float wi = w[i] * inv;
        #pragma unroll
        for (int j = 0; j < 3; ++j) outv[j] = fmaf(wi, vv[i][j], outv[j]);
    }
    float ssq = 0.f;
    #pragma unroll
    for (int j = 0; j < 3; ++j) ssq = fmaf(outv[j], outv[j], ssq);
    float S2 = block_reduce_sum(ssq, sbuf);
    float scale = lns[0] * rsqrtf(S2 * (1.f / 768.f) + EPSF);
    #pragma unroll
    for (int j = 0; j < 3; ++j)
        xn[row * D_MODEL + tid + j * 256] = outv[j] * scale;
}

// ------------------------------------------------------------- fp32 GEMM
// C[M,N] = A[M,K] @ W[K,N];  EPI: 0=store, 1=gelu-store, 2=C += scale[n]*acc
template<int EPI>
__global__ __launch_bounds__(256)
void gemm_f32(const float* __restrict__ A, const float* __restrict__ W,
              float* __restrict__ C, const float* __restrict__ scale,
              int M, int N, int K) {
    __shared__ float As[16][65];   // transposed A tile, padded
    __shared__ float Bs[16][64];
    const int bm = blockIdx.y << 6, bn = blockIdx.x << 6;
    const int tid = threadIdx.x;
    const int tx = tid & 15, ty = tid >> 4;
    const int la_r = tid >> 2, la_c = (tid & 3) << 2;
    const int lb_r = tid >> 4, lb_c = (tid & 15) << 2;
    const float* Aptr = A + (size_t)(bm + la_r) * K + la_c;
    const float* Wptr = W + (size_t)lb_r * N + bn + lb_c;

    float acc[4][4] = {};
    for (int k0 = 0; k0 < K; k0 += 16) {
        float4 av = *(const float4*)(Aptr + k0);
        float4 bv = *(const float4*)(Wptr + (size_t)k0 * N);
        __syncthreads();
        As[la_c + 0][la_r] = av.x;
        As[la_c + 1][la_r] = av.y;
        As[la_c + 2][la_r] = av.z;
        As[la_c + 3][la_r] = av.w;
        *(float4*)&Bs[lb_r][lb_c] = bv;
        __syncthreads();
        #pragma unroll
        for (int k = 0; k < 16; ++k) {
            float a0 = As[k][ty * 4 + 0], a1 = As[k][ty * 4 + 1];
            float a2 = As[k][ty * 4 + 2], a3 = As[k][ty * 4 + 3];
            float4 b = *(const float4*)&Bs[k][tx * 4];
            acc[0][0] = fmaf(a0, b.x, acc[0][0]); acc[0][1] = fmaf(a0, b.y, acc[0][1]);
            acc[0][2] = fmaf(a0, b.z, acc[0][2]); acc[0][3] = fmaf(a0, b.w, acc[0][3]);
            acc[1][0] = fmaf(a1, b.x, acc[1][0]); acc[1][1] = fmaf(a1, b.y, acc[1][1]);
            acc[1][2] = fmaf(a1, b.z, acc[1][2]); acc[1][3] = fmaf(a1, b.w, acc[1][3]);
            acc[2][0] = fmaf(a2, b.x, acc[2][0]); acc[2][1] = fmaf(a2, b.y, acc[2][1]);
            acc[2][2] = fmaf(a2, b.z, acc[2][2]); acc[2][3] = fmaf(a2, b.w, acc[2][3]);
            acc[3][0] = fmaf(a3, b.x, acc[3][0]); acc[3][1] = fmaf(a3, b.y, acc[3][1]);
            acc[3][2] = fmaf(a3, b.z, acc[3][2]); acc[3][3] = fmaf(a3, b.w, acc[3][3]);
        }
    }
    #pragma unroll
    for (int i = 0; i < 4; ++i) {
        size_t row = (size_t)(bm + ty * 4 + i);
        float* cp = C + row * (size_t)N + bn + tx * 4;
        if (EPI == 0) {
            *(float4*)cp = make_float4(acc[i][0], acc[i][1], acc[i][2], acc[i][3]);
        } else if (EPI == 1) {
            *(float4*)cp = make_float4(gelu_tanh(acc[i][0]), gelu_tanh(acc[i][1]),
                                       gelu_tanh(acc[i][2]), gelu_tanh(acc[i][3]));
        } else {
            float4 old = *(const float4*)cp;
            const float* sp = scale + bn + tx * 4;
            *(float4*)cp = make_float4(old.x + sp[0] * acc[i][0],
                                       old.y + sp[1] * acc[i][1],
                                       old.z + sp[2] * acc[i][2],
                                       old.w + sp[3] * acc[i][3]);
        }
    }
}

// --------------------------------------------------- causal flash attention
// qkv: [B*T, 3*D] rows; q cols [0,768), k [768,1536), v [1536,2304)
// ctx: [B*T, D]   (attn output pre-Wo)
__global__ __launch_bounds__(256)
void flash_attn(const float* __restrict__ qkv, float* __restrict__ ctx) {
    const int bh = blockIdx.y;
    const int b = bh / NHEAD, h = bh % NHEAD;
    const int r = blockIdx.x * 256 + threadIdx.x;   // this thread's query row
    const float* base = qkv + (size_t)b * T_SEQ * 2304;

    float q[HDIM];
    {
        const float* qrow = base + (size_t)r * 2304 + h * HDIM;
        #pragma unroll
        for (int d = 0; d < HDIM; d += 4) {
            float4 t = *(const float4*)&qrow[d];
            q[d] = t.x; q[d + 1] = t.y; q[d + 2] = t.z; q[d + 3] = t.w;
        }
    }
    float o[HDIM];
    #pragma unroll
    for (int d = 0; d < HDIM; ++d) o[d] = 0.f;
    float m = -1e30f, lsum = 0.f;

    __shared__ float Ks[64][HDIM];
    __shared__ float Vs[64][HDIM];
    const int lr = threadIdx.x >> 2, lc = (threadIdx.x & 3) << 4;
    const int ktiles = blockIdx.x * 4 + 4;   // causal: keys up to block's max row

    for (int kt = 0; kt < ktiles; ++kt) {
        const int k0 = kt * 64;
        __syncthreads();
        {
            const float* krow = base + (size_t)(k0 + lr) * 2304 + 768  + h * HDIM;
            const float* vrow = base + (size_t)(k0 + lr) * 2304 + 1536 + h * HDIM;
            #pragma unroll
            for (int j = 0; j < 16; j += 4) {
                *(float4*)&Ks[lr][lc + j] = *(const float4*)&krow[lc + j];
                *(float4*)&Vs[lr][lc + j] = *(const float4*)&vrow[lc + j];
            }
        }
        __syncthreads();
        const int jmax = r - k0;
        if (jmax >= 0) {
            const int jend = jmax < 63 ? jmax : 63;
            for (int j = 0; j <= jend; ++j) {
                float s = 0.f;
                #pragma unroll
                for (int d = 0; d < HDIM; ++d) s = fmaf(q[d], Ks[j][d], s);
                s *= 0.125f;   // 1/sqrt(64)
                if (s > m) {
                    float c = __expf(m - s);
                    m = s;
                    lsum *= c;
                    #pragma unroll
                    for (int d = 0; d < HDIM; ++d) o[d] *= c;
                }
                float p = __expf(s - m);
                lsum += p;
                #pragma unroll
                for (int d = 0; d < HDIM; ++d) o[d] = fmaf(p, Vs[j][d], o[d]);
            }
        }
    }
    float inv = 1.f / lsum;
    float* orow = ctx + ((size_t)b * T_SEQ + r) * D_MODEL + h * HDIM;
    #pragma unroll
    for (int d = 0; d < HDIM; d += 4) {
        *(float4*)&orow[d] = make_float4(o[d] * inv, o[d + 1] * inv,
                                         o[d + 2] * inv, o[d + 3] * inv);
    }
}

// ------------------------------------------------------------------- host

extern "C" void kernel_launch(void* const* d_in, const int* in_sizes, int n_in,
                              void* d_out, int out_size, void* d_ws, size_t ws_size,
                              hipStream_t stream) {
    const float* x0     = (const float*)d_in[0];
    const float* aproj  = (const float*)d_in[1];
    const float* mproj  = (const float*)d_in[2];
    const float* Wqkv   = (const float*)d_in[3];
    const float* Wo     = (const float*)d_in[4];
    const float* Wm1    = (const float*)d_in[5];
    const float* Wm2    = (const float*)d_in[6];
    const float* ascale = (const float*)d_in[7];
    const float* mscale = (const float*)d_in[8];
    const float* lns    = (const float*)d_in[9];
    float* out = (float*)d_out;
    float* ws  = (float*)d_ws;

    // workspace layout (floats): p1,p2,p3 | xn | mid(4 BTD, aliases qkv+ctx)
    float* pb[3] = { ws, ws + BTD, ws + 2 * BTD };
    float* xn  = ws + 3 * BTD;
    float* mid = ws + 4 * BTD;   // [8192, 3072]
    float* qkv = ws + 4 * BTD;   // [8192, 2304]  (aliases mid, disjoint in time)
    float* ctx = ws + 7 * BTD;   // [8192, 768]

    const float* hist[6];
    int nh = 1;
    hist[0] = x0;
    const float* partial_c = x0;   // read view of current partial
    float* partial_w = nullptr;    // write view (set at first boundary)
    int pidx = 0;

    auto launch_agg = [&](int n, const float* Vl[6], const float* qvec,
                          const float* lnsl, float* xout) {
        switch (n) {
        case 2: agg_norm_kernel<2><<<dim3(ROWS), 256, 0, stream>>>(Vl[0], Vl[1], Vl[2], Vl[3], Vl[4], Vl[5], qvec, lnsl, xout); break;
        case 3: agg_norm_kernel<3><<<dim3(ROWS), 256, 0, stream>>>(Vl[0], Vl[1], Vl[2], Vl[3], Vl[4], Vl[5], qvec, lnsl, xout); break;
        case 4: agg_norm_kernel<4><<<dim3(ROWS), 256, 0, stream>>>(Vl[0], Vl[1], Vl[2], Vl[3], Vl[4], Vl[5], qvec, lnsl, xout); break;
        case 5: agg_norm_kernel<5><<<dim3(ROWS), 256, 0, stream>>>(Vl[0], Vl[1], Vl[2], Vl[3], Vl[4], Vl[5], qvec, lnsl, xout); break;
        default: agg_norm_kernel<6><<<dim3(ROWS), 256, 0, stream>>>(Vl[0], Vl[1], Vl[2], Vl[3], Vl[4], Vl[5], qvec, lnsl, xout); break;
        }
    };

    for (int l = 0; l < NLAYER; ++l) {
        // ---- attention-path aggregate (reads OLD partial) → xn
        const float* Vl[6] = {nullptr, nullptr, nullptr, nullptr, nullptr, nullptr};
        for (int i = 0; i < nh; ++i) Vl[i] = hist[i];
        Vl[nh] = partial_c;
        launch_agg(nh + 1, Vl, aproj + (size_t)l * D_MODEL, lns + l, xn);

        // ---- block boundary: commit partial to hist, start fresh partial
        if ((l & 1) == 0) {
            hist[nh++] = partial_c;
            float* np = (pidx < 3) ? pb[pidx] : out;
            ++pidx;
            fill_zero4<<<dim3((int)(BTD / 4 / 256)), 256, 0, stream>>>((float4*)np, (int)(BTD / 4));
            partial_w = np;
            partial_c = np;
        }

        // ---- MHA: qkv = xn @ Wqkv ; flash ; partial += attn_scale * (ctx @ Wo)
        gemm_f32<0><<<dim3(3 * D_MODEL / 64, ROWS / 64), 256, 0, stream>>>(
            xn, Wqkv + (size_t)l * D_MODEL * 3 * D_MODEL, qkv, nullptr,
            ROWS, 3 * D_MODEL, D_MODEL);
        flash_attn<<<dim3(T_SEQ / 256, B_BATCH * NHEAD), 256, 0, stream>>>(qkv, ctx);
        gemm_f32<2><<<dim3(D_MODEL / 64, ROWS / 64), 256, 0, stream>>>(
            ctx, Wo + (size_t)l * D_MODEL * D_MODEL, partial_w,
            ascale + (size_t)l * D_MODEL, ROWS, D_MODEL, D_MODEL);

        // ---- mlp-path aggregate (reads NEW partial) → xn
        const float* V2[6] = {nullptr, nullptr, nullptr, nullptr, nullptr, nullptr};
        for (int i = 0; i < nh; ++i) V2[i] = hist[i];
        V2[nh] = partial_c;
        launch_agg(nh + 1, V2, mproj + (size_t)l * D_MODEL, lns + l, xn);

        // ---- MLP: mid = gelu(xn @ Wm1) ; partial += mlp_scale * (mid @ Wm2)
        gemm_f32<1><<<dim3(4 * D_MODEL / 64, ROWS / 64), 256, 0, stream>>>(
            xn, Wm1 + (size_t)l * D_MODEL * 4 * D_MODEL, mid, nullptr,
            ROWS, 4 * D_MODEL, D_MODEL);
        gemm_f32<2><<<dim3(D_MODEL / 64, ROWS / 64), 256, 0, stream>>>(
            mid, Wm2 + (size_t)l * 4 * D_MODEL * D_MODEL, partial_w,
            mscale + (size_t)l * D_MODEL, ROWS, D_MODEL, 4 * D_MODEL);
    }
}

// Round 2
// 10862.554 us; speedup vs baseline: 1.8412x; 1.8412x over previous
//
#include <hip/hip_runtime.h>
#include <hip/hip_bf16.h>
#include <math.h>
#include <stdint.h>

#define D_MODEL 768
#define T_SEQ   1024
#define B_BATCH 8
#define NHEAD   12
#define HDIM    64
#define NLAYER  8

typedef unsigned short u16;
typedef __attribute__((ext_vector_type(8))) short bf16x8;
typedef __attribute__((ext_vector_type(4))) float f32x4;

static constexpr size_t BTD  = (size_t)B_BATCH * T_SEQ * D_MODEL;  // 6291456
static constexpr int    ROWS = B_BATCH * T_SEQ;                    // 8192
static constexpr float  EPSF = 1.1920928955078125e-07f;            // FLT_EPSILON

// ---------------------------------------------------------------- helpers

__device__ __forceinline__ u16 f2bf(float x) {
    __hip_bfloat16 h = __float2bfloat16(x);
    return __builtin_bit_cast(u16, h);
}
__device__ __forceinline__ float bf2f(u16 u) {
    __hip_bfloat16 h = __builtin_bit_cast(__hip_bfloat16, u);
    return __bfloat162float(h);
}
__device__ __forceinline__ void split_bf(float x, u16& hi, u16& lo) {
    hi = f2bf(x);
    lo = f2bf(x - bf2f(hi));
}

// async global->LDS, 16B per lane; LDS dest must be wave-uniform base (HW adds lane*16)
__device__ __forceinline__ void gl_lds16(const void* g, void* l) {
    auto gp = reinterpret_cast<const __attribute__((address_space(1))) char*>(
        reinterpret_cast<uintptr_t>(g));
    auto lp = reinterpret_cast<__attribute__((address_space(3))) char*>(
        static_cast<uint32_t>(reinterpret_cast<uintptr_t>(l)));
    __builtin_amdgcn_global_load_lds(gp, lp, 16, 0, 0);
}

__global__ __launch_bounds__(256) void fill_zero4(float4* __restrict__ p, int n4) {
    int i = blockIdx.x * 256 + threadIdx.x;
    if (i < n4) p[i] = make_float4(0.f, 0.f, 0.f, 0.f);
}

__device__ __forceinline__ float block_reduce_sum(float v, float* sbuf) {
    #pragma unroll
    for (int off = 32; off > 0; off >>= 1) v += __shfl_down(v, off);
    __syncthreads();
    if ((threadIdx.x & 63) == 0) sbuf[threadIdx.x >> 6] = v;
    __syncthreads();
    return sbuf[0] + sbuf[1] + sbuf[2] + sbuf[3];
}

__device__ __forceinline__ float gelu_tanh(float x) {
    float x3 = x * x * x;
    float t  = tanhf(0.7978845608028654f * (x + 0.044715f * x3));
    return 0.5f * x * (1.f + t);
}

// ------------------------------------------------- aggregate + rmsnorm fuse
// h = aggregate(V[0..N-1], q); xn = rms_norm(h)*ln_s, emitted as bf16 hi/lo
template<int N>
__global__ __launch_bounds__(256)
void agg_norm_kernel(const float* __restrict__ v0, const float* __restrict__ v1,
                     const float* __restrict__ v2, const float* __restrict__ v3,
                     const float* __restrict__ v4, const float* __restrict__ v5,
                     const float* __restrict__ q,  const float* __restrict__ lns,
                     u16* __restrict__ xh, u16* __restrict__ xl) {
    __shared__ float sbuf[4];
    const float* V[6] = {v0, v1, v2, v3, v4, v5};
    const size_t row = blockIdx.x;
    const int tid = threadIdx.x;

    float qv[3];
    #pragma unroll
    for (int j = 0; j < 3; ++j) qv[j] = q[tid + j * 256];

    float vv[N][3];
    float logits[N];
    #pragma unroll
    for (int i = 0; i < N; ++i) {
        const float* vr = V[i] + row * D_MODEL;
        float ssq = 0.f, qd = 0.f;
        #pragma unroll
        for (int j = 0; j < 3; ++j) {
            float x = vr[tid + j * 256];
            vv[i][j] = x;
            ssq = fmaf(x, x, ssq);
            qd  = fmaf(qv[j], x, qd);
        }
        float S  = block_reduce_sum(ssq, sbuf);
        float Qd = block_reduce_sum(qd,  sbuf);
        logits[i] = Qd * rsqrtf(S * (1.f / 768.f) + EPSF);
    }
    float mx = logits[0];
    #pragma unroll
    for (int i = 1; i < N; ++i) mx = fmaxf(mx, logits[i]);
    float w[N];
    float wsum = 0.f;
    #pragma unroll
    for (int i = 0; i < N; ++i) { w[i] = __expf(logits[i] - mx); wsum += w[i]; }
    float inv = 1.f / wsum;

    float outv[3] = {0.f, 0.f, 0.f};
    #pragma unroll
    for (int i = 0; i < N; ++i) {
        float wi = w[i] * inv;
        #pragma unroll
        for (int j = 0; j < 3; ++j) outv[j] = fmaf(wi, vv[i][j], outv[j]);
    }
    float ssq = 0.f;
    #pragma unroll
    for (int j = 0; j < 3; ++j) ssq = fmaf(outv[j], outv[j], ssq);
    float S2 = block_reduce_sum(ssq, sbuf);
    float scale = lns[0] * rsqrtf(S2 * (1.f / 768.f) + EPSF);
    #pragma unroll
    for (int j = 0; j < 3; ++j) {
        float x = outv[j] * scale;
        u16 hi, lo;
        split_bf(x, hi, lo);
        size_t idx = row * D_MODEL + tid + j * 256;
        xh[idx] = hi;
        xl[idx] = lo;
    }
}

// ---------------------------------------------- weight transpose + bf split
// W[K][N] fp32 -> Th/Tl[N][K] bf16
__global__ __launch_bounds__(256)
void transpose_split(const float* __restrict__ W, u16* __restrict__ Th,
                     u16* __restrict__ Tl, int K, int N) {
    __shared__ float t[32][33];
    const int bk = blockIdx.x * 32, bn = blockIdx.y * 32;
    const int r = threadIdx.x >> 3, c4 = (threadIdx.x & 7) * 4;
    float4 v = *(const float4*)&W[(size_t)(bk + r) * N + bn + c4];
    t[r][c4 + 0] = v.x; t[r][c4 + 1] = v.y; t[r][c4 + 2] = v.z; t[r][c4 + 3] = v.w;
    __syncthreads();
    u16 h[4], lo[4];
    #pragma unroll
    for (int j = 0; j < 4; ++j) split_bf(t[c4 + j][r], h[j], lo[j]);
    size_t o = (size_t)(bn + r) * K + bk + c4;
    *(uint2*)&Th[o] = make_uint2((uint32_t)h[0]  | ((uint32_t)h[1]  << 16),
                                 (uint32_t)h[2]  | ((uint32_t)h[3]  << 16));
    *(uint2*)&Tl[o] = make_uint2((uint32_t)lo[0] | ((uint32_t)lo[1] << 16),
                                 (uint32_t)lo[2] | ((uint32_t)lo[3] << 16));
}

// ------------------------------------------------- split-bf16 MFMA GEMM
// C[M,N] = (Ah+Al)[M,K] @ (Bh+Bl)^T  (B given as [N][K]); 3-term product.
// EPI: 0 = store fp32, 1 = gelu -> bf16 hi/lo, 2 = Cf += scale[n]*acc
template<int EPI>
__global__ __launch_bounds__(256)
void gemm_bf3(const u16* __restrict__ Ah, const u16* __restrict__ Al,
              const u16* __restrict__ Bh, const u16* __restrict__ Bl,
              float* __restrict__ Cf, u16* __restrict__ Ch, u16* __restrict__ Cl,
              const float* __restrict__ scale, int M, int N, int K) {
    // LDS: Ah [0,8KB) Al [8,16) Bh [16,24) Bl [24,32) ; each tile [128][32] bf16
    __shared__ u16 smem[16384];
    const int tid = threadIdx.x;
    const int bm = blockIdx.y << 7, bn = blockIdx.x << 7;
    const int w = tid >> 6, l = tid & 63;
    const int wr = w >> 1, wc = w & 1;

    const size_t aoff0 = (size_t)(bm + (tid >> 2)) * K + ((tid & 3) << 3);
    const size_t boff0 = (size_t)(bn + (tid >> 2)) * K + ((tid & 3) << 3);
    const size_t s64 = (size_t)64 * K;
    char* sb = (char*)smem;
    const uint32_t wq = (uint32_t)w << 10;

    f32x4 acc[4][4] = {};

    for (int k0 = 0; k0 < K; k0 += 32) {
        __syncthreads();
        gl_lds16(Ah + aoff0 + k0,       sb + 0     + wq);
        gl_lds16(Ah + aoff0 + s64 + k0, sb + 4096  + wq);
        gl_lds16(Al + aoff0 + k0,       sb + 8192  + wq);
        gl_lds16(Al + aoff0 + s64 + k0, sb + 12288 + wq);
        gl_lds16(Bh + boff0 + k0,       sb + 16384 + wq);
        gl_lds16(Bh + boff0 + s64 + k0, sb + 20480 + wq);
        gl_lds16(Bl + boff0 + k0,       sb + 24576 + wq);
        gl_lds16(Bl + boff0 + s64 + k0, sb + 28672 + wq);
        __syncthreads();

        const int koff = (l >> 4) << 3;
        const int arow = wr * 64 + (l & 15);
        const int brow = wc * 64 + (l & 15);
        bf16x8 ah[4], al4[4], bh4[4], bl4[4];
        #pragma unroll
        for (int i = 0; i < 4; ++i) {
            ah[i]  = *(const bf16x8*)&smem[(arow + i * 16) * 32 + koff];
            al4[i] = *(const bf16x8*)&smem[4096  + (arow + i * 16) * 32 + koff];
            bh4[i] = *(const bf16x8*)&smem[8192  + (brow + i * 16) * 32 + koff];
            bl4[i] = *(const bf16x8*)&smem[12288 + (brow + i * 16) * 32 + koff];
        }
        #pragma unroll
        for (int i = 0; i < 4; ++i) {
            #pragma unroll
            for (int j = 0; j < 4; ++j) {
                acc[i][j] = __builtin_amdgcn_mfma_f32_16x16x32_bf16(ah[i],  bh4[j], acc[i][j], 0, 0, 0);
                acc[i][j] = __builtin_amdgcn_mfma_f32_16x16x32_bf16(ah[i],  bl4[j], acc[i][j], 0, 0, 0);
                acc[i][j] = __builtin_amdgcn_mfma_f32_16x16x32_bf16(al4[i], bh4[j], acc[i][j], 0, 0, 0);
            }
        }
    }

    // C/D frag: col = lane&15, row = (lane>>4)*4 + reg   [m89/m91]
    const int crow0 = bm + wr * 64 + ((l >> 4) << 2);
    const int ccol0 = bn + wc * 64 + (l & 15);
    #pragma unroll
    for (int i = 0; i < 4; ++i) {
        #pragma unroll
        for (int j = 0; j < 4; ++j) {
            const int col = ccol0 + j * 16;
            #pragma unroll
            for (int r = 0; r < 4; ++r) {
                const size_t o = (size_t)(crow0 + i * 16 + r) * N + col;
                float v = acc[i][j][r];
                if (EPI == 0) {
                    Cf[o] = v;
                } else if (EPI == 1) {
                    float g = gelu_tanh(v);
                    u16 hi, lo;
                    split_bf(g, hi, lo);
                    Ch[o] = hi; Cl[o] = lo;
                } else {
                    Cf[o] += scale[col] * v;
                }
            }
        }
    }
}

// --------------------------------------------------- causal flash attention
// qkv: [B*T, 3*D] fp32; writes ctx as bf16 hi/lo [B*T, D]
__global__ __launch_bounds__(128)
void flash_attn(const float* __restrict__ qkv, u16* __restrict__ ch,
                u16* __restrict__ cl) {
    const int bh = blockIdx.y;
    const int b = bh / NHEAD, h = bh % NHEAD;
    const int r = blockIdx.x * 128 + threadIdx.x;
    const float* base = qkv + (size_t)b * T_SEQ * 2304;

    float4 q4[16];
    {
        const float* qrow = base + (size_t)r * 2304 + h * HDIM;
        #pragma unroll
        for (int d = 0; d < 16; ++d) q4[d] = *(const float4*)&qrow[d * 4];
    }
    float4 o4[16];
    #pragma unroll
    for (int d = 0; d < 16; ++d) o4[d] = make_float4(0.f, 0.f, 0.f, 0.f);
    float m = -1e30f, lsum = 0.f;

    __shared__ float Ks[64][68];
    __shared__ float Vs[64][68];
    const int lr = threadIdx.x >> 1, lc0 = (threadIdx.x & 1) * 32;
    const int ktiles = blockIdx.x * 2 + 2;

    for (int kt = 0; kt < ktiles; ++kt) {
        const int k0 = kt * 64;
        __syncthreads();
        {
            const float* krow = base + (size_t)(k0 + lr) * 2304 + 768  + h * HDIM + lc0;
            const float* vrow = base + (size_t)(k0 + lr) * 2304 + 1536 + h * HDIM + lc0;
            #pragma unroll
            for (int j = 0; j < 32; j += 4) {
                *(float4*)&Ks[lr][lc0 + j] = *(const float4*)&krow[j];
                *(float4*)&Vs[lr][lc0 + j] = *(const float4*)&vrow[j];
            }
        }
        __syncthreads();
        const int jmax = r - k0;
        if (jmax < 0) continue;
        const int jend = jmax < 63 ? jmax : 63;
        for (int j = 0; j <= jend; ++j) {
            const float4* kr = (const float4*)&Ks[j][0];
            float c0 = 0.f, c1 = 0.f, c2 = 0.f, c3 = 0.f;
            #pragma unroll
            for (int d = 0; d < 16; d += 4) {
                float4 k0v = kr[d], k1v = kr[d + 1], k2v = kr[d + 2], k3v = kr[d + 3];
                c0 = fmaf(q4[d].x,     k0v.x, fmaf(q4[d].y,     k0v.y, fmaf(q4[d].z,     k0v.z, fmaf(q4[d].w,     k0v.w, c0))));
                c1 = fmaf(q4[d + 1].x, k1v.x, fmaf(q4[d + 1].y, k1v.y, fmaf(q4[d + 1].z, k1v.z, fmaf(q4[d + 1].w, k1v.w, c1))));
                c2 = fmaf(q4[d + 2].x, k2v.x, fmaf(q4[d + 2].y, k2v.y, fmaf(q4[d + 2].z, k2v.z, fmaf(q4[d + 2].w, k2v.w, c2))));
                c3 = fmaf(q4[d + 3].x, k3v.x, fmaf(q4[d + 3].y, k3v.y, fmaf(q4[d + 3].z, k3v.z, fmaf(q4[d + 3].w, k3v.w, c3))));
            }
            float s = ((c0 + c1) + (c2 + c3)) * 0.125f;
            if (s > m) {
                float c = __expf(m - s);
                m = s;
                lsum *= c;
                #pragma unroll
                for (int d = 0; d < 16; ++d) {
                    o4[d].x *= c; o4[d].y *= c; o4[d].z *= c; o4[d].w *= c;
                }
            }
            float p = __expf(s - m);
            lsum += p;
            const float4* vr = (const float4*)&Vs[j][0];
            #pragma unroll
            for (int d = 0; d < 16; ++d) {
                float4 vv = vr[d];
                o4[d].x = fmaf(p, vv.x, o4[d].x);
                o4[d].y = fmaf(p, vv.y, o4[d].y);
                o4[d].z = fmaf(p, vv.z, o4[d].z);
                o4[d].w = fmaf(p, vv.w, o4[d].w);
            }
        }
    }
    float inv = 1.f / lsum;
    size_t obase = ((size_t)b * T_SEQ + r) * D_MODEL + h * HDIM;
    #pragma unroll
    for (int d = 0; d < 16; ++d) {
        float x0 = o4[d].x * inv, x1 = o4[d].y * inv, x2 = o4[d].z * inv, x3 = o4[d].w * inv;
        u16 h0, l0, h1, l1, h2, l2, h3, l3;
        split_bf(x0, h0, l0); split_bf(x1, h1, l1);
        split_bf(x2, h2, l2); split_bf(x3, h3, l3);
        *(uint2*)&ch[obase + d * 4] = make_uint2((uint32_t)h0 | ((uint32_t)h1 << 16),
                                                 (uint32_t)h2 | ((uint32_t)h3 << 16));
        *(uint2*)&cl[obase + d * 4] = make_uint2((uint32_t)l0 | ((uint32_t)l1 << 16),
                                                 (uint32_t)l2 | ((uint32_t)l3 << 16));
    }
}

// ------------------------------------------------------------------- host

extern "C" void kernel_launch(void* const* d_in, const int* in_sizes, int n_in,
                              void* d_out, int out_size, void* d_ws, size_t ws_size,
                              hipStream_t stream) {
    const float* x0     = (const float*)d_in[0];
    const float* aproj  = (const float*)d_in[1];
    const float* mproj  = (const float*)d_in[2];
    const float* Wqkv   = (const float*)d_in[3];
    const float* Wo     = (const float*)d_in[4];
    const float* Wm1    = (const float*)d_in[5];
    const float* Wm2    = (const float*)d_in[6];
    const float* ascale = (const float*)d_in[7];
    const float* mscale = (const float*)d_in[8];
    const float* lns    = (const float*)d_in[9];
    float* out = (float*)d_out;
    char*  W0  = (char*)d_ws;

    // layout (bytes): p1,p2,p3 (12*BTD) | xn hi/lo (4*BTD) | R (16*BTD) | Wt (9.4MB)
    float* p1  = (float*)W0;
    float* p2  = p1 + BTD;
    float* p3  = p2 + BTD;
    u16*   xnh = (u16*)(W0 + 12 * BTD);
    u16*   xnl = xnh + BTD;
    char*  R   = W0 + 16 * BTD;
    float* qkv  = (float*)R;                  // 12*BTD bytes
    u16*   ctxh = (u16*)(R + 12 * BTD);
    u16*   ctxl = ctxh + BTD;
    u16*   midh = (u16*)R;                    // [8192,3072] hi  (aliases qkv+ctx)
    u16*   midl = midh + 4 * BTD;
    u16*   wth  = (u16*)(W0 + 32 * BTD);
    u16*   wtl  = wth + (size_t)3072 * 768;

    float* pb[3] = {p1, p2, p3};
    const float* hist[6];
    int nh = 1;
    hist[0] = x0;
    const float* partial_c = x0;
    float* partial_w = nullptr;
    int pidx = 0;

    auto launch_agg = [&](int n, const float* Vl[6], const float* qvec,
                          const float* lnsl) {
        switch (n) {
        case 2: agg_norm_kernel<2><<<dim3(ROWS), 256, 0, stream>>>(Vl[0], Vl[1], Vl[2], Vl[3], Vl[4], Vl[5], qvec, lnsl, xnh, xnl); break;
        case 3: agg_norm_kernel<3><<<dim3(ROWS), 256, 0, stream>>>(Vl[0], Vl[1], Vl[2], Vl[3], Vl[4], Vl[5], qvec, lnsl, xnh, xnl); break;
        case 4: agg_norm_kernel<4><<<dim3(ROWS), 256, 0, stream>>>(Vl[0], Vl[1], Vl[2], Vl[3], Vl[4], Vl[5], qvec, lnsl, xnh, xnl); break;
        case 5: agg_norm_kernel<5><<<dim3(ROWS), 256, 0, stream>>>(Vl[0], Vl[1], Vl[2], Vl[3], Vl[4], Vl[5], qvec, lnsl, xnh, xnl); break;
        default: agg_norm_kernel<6><<<dim3(ROWS), 256, 0, stream>>>(Vl[0], Vl[1], Vl[2], Vl[3], Vl[4], Vl[5], qvec, lnsl, xnh, xnl); break;
        }
    };

    for (int l = 0; l < NLAYER; ++l) {
        // ---- attention-path aggregate (reads OLD partial) -> xn hi/lo
        const float* Vl[6] = {nullptr, nullptr, nullptr, nullptr, nullptr, nullptr};
        for (int i = 0; i < nh; ++i) Vl[i] = hist[i];
        Vl[nh] = partial_c;
        launch_agg(nh + 1, Vl, aproj + (size_t)l * D_MODEL, lns + l);

        // ---- block boundary
        if ((l & 1) == 0) {
            hist[nh++] = partial_c;
            float* np = (pidx < 3) ? pb[pidx] : out;
            ++pidx;
            fill_zero4<<<dim3((int)(BTD / 4 / 256)), 256, 0, stream>>>((float4*)np, (int)(BTD / 4));
            partial_w = np;
            partial_c = np;
        }

        // ---- QKV GEMM -> qkv (fp32)
        transpose_split<<<dim3(D_MODEL / 32, 3 * D_MODEL / 32), 256, 0, stream>>>(
            Wqkv + (size_t)l * D_MODEL * 3 * D_MODEL, wth, wtl, D_MODEL, 3 * D_MODEL);
        gemm_bf3<0><<<dim3(3 * D_MODEL / 128, ROWS / 128), 256, 0, stream>>>(
            xnh, xnl, wth, wtl, qkv, nullptr, nullptr, nullptr,
            ROWS, 3 * D_MODEL, D_MODEL);

        // ---- flash attention -> ctx hi/lo
        flash_attn<<<dim3(T_SEQ / 128, B_BATCH * NHEAD), 128, 0, stream>>>(qkv, ctxh, ctxl);

        // ---- Wo GEMM: partial += attn_scale * (ctx @ Wo)
        transpose_split<<<dim3(D_MODEL / 32, D_MODEL / 32), 256, 0, stream>>>(
            Wo + (size_t)l * D_MODEL * D_MODEL, wth, wtl, D_MODEL, D_MODEL);
        gemm_bf3<2><<<dim3(D_MODEL / 128, ROWS / 128), 256, 0, stream>>>(
            ctxh, ctxl, wth, wtl, partial_w, nullptr, nullptr,
            ascale + (size_t)l * D_MODEL, ROWS, D_MODEL, D_MODEL);

        // ---- mlp-path aggregate (reads NEW partial) -> xn hi/lo
        const float* V2[6] = {nullptr, nullptr, nullptr, nullptr, nullptr, nullptr};
        for (int i = 0; i < nh; ++i) V2[i] = hist[i];
        V2[nh] = partial_c;
        launch_agg(nh + 1, V2, mproj + (size_t)l * D_MODEL, lns + l);

        // ---- MLP: mid = gelu(xn @ Wm1) (bf16 hi/lo); partial += mlp_scale*(mid @ Wm2)
        transpose_split<<<dim3(D_MODEL / 32, 4 * D_MODEL / 32), 256, 0, stream>>>(
            Wm1 + (size_t)l * D_MODEL * 4 * D_MODEL, wth, wtl, D_MODEL, 4 * D_MODEL);
        gemm_bf3<1><<<dim3(4 * D_MODEL / 128, ROWS / 128), 256, 0, stream>>>(
            xnh, xnl, wth, wtl, nullptr, midh, midl, nullptr,
            ROWS, 4 * D_MODEL, D_MODEL);
        transpose_split<<<dim3(4 * D_MODEL / 32, D_MODEL / 32), 256, 0, stream>>>(
            Wm2 + (size_t)l * 4 * D_MODEL * D_MODEL, wth, wtl, 4 * D_MODEL, D_MODEL);
        gemm_bf3<2><<<dim3(D_MODEL / 128, ROWS / 128), 256, 0, stream>>>(
            midh, midl, wth, wtl, partial_w, nullptr, nullptr,
            mscale + (size_t)l * D_MODEL, ROWS, D_MODEL, 4 * D_MODEL);
    }
}

// Round 4
// 7071.229 us; speedup vs baseline: 2.8284x; 1.5362x over previous
//
#include <hip/hip_runtime.h>
#include <hip/hip_bf16.h>
#include <math.h>
#include <stdint.h>

#define D_MODEL 768
#define T_SEQ   1024
#define B_BATCH 8
#define NHEAD   12
#define HDIM    64
#define NLAYER  8

typedef unsigned short u16;
typedef __attribute__((ext_vector_type(8))) short bf16x8;
typedef __attribute__((ext_vector_type(4))) float f32x4;

static constexpr size_t BTD  = (size_t)B_BATCH * T_SEQ * D_MODEL;  // 6291456
static constexpr int    ROWS = B_BATCH * T_SEQ;                    // 8192
static constexpr float  EPSF = 1.1920928955078125e-07f;            // FLT_EPSILON

// ---------------------------------------------------------------- helpers

__device__ __forceinline__ u16 f2bf(float x) {
    __hip_bfloat16 h = __float2bfloat16(x);
    return __builtin_bit_cast(u16, h);
}
__device__ __forceinline__ float bf2f(u16 u) {
    __hip_bfloat16 h = __builtin_bit_cast(__hip_bfloat16, u);
    return __bfloat162float(h);
}
__device__ __forceinline__ void split_bf(float x, u16& hi, u16& lo) {
    hi = f2bf(x);
    lo = f2bf(x - bf2f(hi));
}
__device__ __forceinline__ uint32_t cvt_pk_bf16(float a, float b) {
    uint32_t r;
    asm("v_cvt_pk_bf16_f32 %0, %1, %2" : "=v"(r) : "v"(a), "v"(b));
    return r;
}
__device__ __forceinline__ f32x4 mfma16(bf16x8 a, bf16x8 b, f32x4 c) {
    return __builtin_amdgcn_mfma_f32_16x16x32_bf16(a, b, c, 0, 0, 0);
}

// async global->LDS, 16B/lane; LDS dest wave-uniform base (HW adds lane*16)
__device__ __forceinline__ void gl_lds16(const void* g, void* l) {
    auto gp = reinterpret_cast<const __attribute__((address_space(1))) char*>(
        reinterpret_cast<uintptr_t>(g));
    auto lp = reinterpret_cast<__attribute__((address_space(3))) char*>(
        static_cast<uint32_t>(reinterpret_cast<uintptr_t>(l)));
    __builtin_amdgcn_global_load_lds(gp, lp, 16, 0, 0);
}

__global__ __launch_bounds__(256) void fill_zero4(float4* __restrict__ p, int n4) {
    int i = blockIdx.x * 256 + threadIdx.x;
    if (i < n4) p[i] = make_float4(0.f, 0.f, 0.f, 0.f);
}

__device__ __forceinline__ float block_reduce_sum(float v, float* sbuf) {
    #pragma unroll
    for (int off = 32; off > 0; off >>= 1) v += __shfl_down(v, off);
    __syncthreads();
    if ((threadIdx.x & 63) == 0) sbuf[threadIdx.x >> 6] = v;
    __syncthreads();
    return sbuf[0] + sbuf[1] + sbuf[2] + sbuf[3];
}

__device__ __forceinline__ float gelu_tanh(float x) {
    float x3 = x * x * x;
    float t  = tanhf(0.7978845608028654f * (x + 0.044715f * x3));
    return 0.5f * x * (1.f + t);
}

// ------------------------------------------------- aggregate + rmsnorm fuse
template<int N>
__global__ __launch_bounds__(256)
void agg_norm_kernel(const float* __restrict__ v0, const float* __restrict__ v1,
                     const float* __restrict__ v2, const float* __restrict__ v3,
                     const float* __restrict__ v4, const float* __restrict__ v5,
                     const float* __restrict__ q,  const float* __restrict__ lns,
                     u16* __restrict__ xh, u16* __restrict__ xl) {
    __shared__ float sbuf[4];
    const float* V[6] = {v0, v1, v2, v3, v4, v5};
    const size_t row = blockIdx.x;
    const int tid = threadIdx.x;

    float qv[3];
    #pragma unroll
    for (int j = 0; j < 3; ++j) qv[j] = q[tid + j * 256];

    float vv[N][3];
    float logits[N];
    #pragma unroll
    for (int i = 0; i < N; ++i) {
        const float* vr = V[i] + row * D_MODEL;
        float ssq = 0.f, qd = 0.f;
        #pragma unroll
        for (int j = 0; j < 3; ++j) {
            float x = vr[tid + j * 256];
            vv[i][j] = x;
            ssq = fmaf(x, x, ssq);
            qd  = fmaf(qv[j], x, qd);
        }
        float S  = block_reduce_sum(ssq, sbuf);
        float Qd = block_reduce_sum(qd,  sbuf);
        logits[i] = Qd * rsqrtf(S * (1.f / 768.f) + EPSF);
    }
    float mx = logits[0];
    #pragma unroll
    for (int i = 1; i < N; ++i) mx = fmaxf(mx, logits[i]);
    float w[N];
    float wsum = 0.f;
    #pragma unroll
    for (int i = 0; i < N; ++i) { w[i] = __expf(logits[i] - mx); wsum += w[i]; }
    float inv = 1.f / wsum;

    float outv[3] = {0.f, 0.f, 0.f};
    #pragma unroll
    for (int i = 0; i < N; ++i) {
        float wi = w[i] * inv;
        #pragma unroll
        for (int j = 0; j < 3; ++j) outv[j] = fmaf(wi, vv[i][j], outv[j]);
    }
    float ssq = 0.f;
    #pragma unroll
    for (int j = 0; j < 3; ++j) ssq = fmaf(outv[j], outv[j], ssq);
    float S2 = block_reduce_sum(ssq, sbuf);
    float scale = lns[0] * rsqrtf(S2 * (1.f / 768.f) + EPSF);
    #pragma unroll
    for (int j = 0; j < 3; ++j) {
        float x = outv[j] * scale;
        u16 hi, lo;
        split_bf(x, hi, lo);
        size_t idx = row * D_MODEL + tid + j * 256;
        xh[idx] = hi;
        xl[idx] = lo;
    }
}

// ---------------------------------------------- weight transpose + bf split
__global__ __launch_bounds__(256)
void transpose_split(const float* __restrict__ W, u16* __restrict__ Th,
                     u16* __restrict__ Tl, int K, int N) {
    __shared__ float t[32][33];
    const int bk = blockIdx.x * 32, bn = blockIdx.y * 32;
    const int r = threadIdx.x >> 3, c4 = (threadIdx.x & 7) * 4;
    float4 v = *(const float4*)&W[(size_t)(bk + r) * N + bn + c4];
    t[r][c4 + 0] = v.x; t[r][c4 + 1] = v.y; t[r][c4 + 2] = v.z; t[r][c4 + 3] = v.w;
    __syncthreads();
    u16 h[4], lo[4];
    #pragma unroll
    for (int j = 0; j < 4; ++j) split_bf(t[c4 + j][r], h[j], lo[j]);
    size_t o = (size_t)(bn + r) * K + bk + c4;
    *(uint2*)&Th[o] = make_uint2((uint32_t)h[0]  | ((uint32_t)h[1]  << 16),
                                 (uint32_t)h[2]  | ((uint32_t)h[3]  << 16));
    *(uint2*)&Tl[o] = make_uint2((uint32_t)lo[0] | ((uint32_t)lo[1] << 16),
                                 (uint32_t)lo[2] | ((uint32_t)lo[3] << 16));
}

// ---------------------------------------------- V transpose (head-major)
// in  vh/vl [bh][1024][64] -> out vth/vtl [bh][64][1024]
__global__ __launch_bounds__(256)
void vt_transpose(const u16* __restrict__ vh, const u16* __restrict__ vl,
                  u16* __restrict__ vth, u16* __restrict__ vtl) {
    __shared__ u16 th[32][36];
    __shared__ u16 tl[32][36];
    const int bh = blockIdx.z;
    const int t0 = blockIdx.x * 32, d0 = blockIdx.y * 32;
    const int r = threadIdx.x >> 3, c = (threadIdx.x & 7) * 4;
    const size_t ib = ((size_t)(bh << 10) + t0 + r) * 64 + d0 + c;
    *(uint2*)&th[r][c] = *(const uint2*)&vh[ib];
    *(uint2*)&tl[r][c] = *(const uint2*)&vl[ib];
    __syncthreads();
    const size_t ob = ((size_t)(bh << 6) + d0 + r) * 1024 + t0 + c;
    u16 a0 = th[c + 0][r], a1 = th[c + 1][r], a2 = th[c + 2][r], a3 = th[c + 3][r];
    *(uint2*)&vth[ob] = make_uint2((uint32_t)a0 | ((uint32_t)a1 << 16),
                                   (uint32_t)a2 | ((uint32_t)a3 << 16));
    u16 b0 = tl[c + 0][r], b1 = tl[c + 1][r], b2 = tl[c + 2][r], b3 = tl[c + 3][r];
    *(uint2*)&vtl[ob] = make_uint2((uint32_t)b0 | ((uint32_t)b1 << 16),
                                   (uint32_t)b2 | ((uint32_t)b3 << 16));
}

// ------------------------------------------------- split-bf16 MFMA GEMM
// C[M,N] = (Ah+Al)[M,K] @ (Bh+Bl)^T  (B given as [N][K]); 3-term product.
// EPI: 1 = gelu -> bf16 hi/lo, 2 = Cf += scale[n]*acc,
//      3 = scatter qkv (q*0.125) into head-major split buffers
template<int EPI>
__global__ __launch_bounds__(256)
void gemm_bf3(const u16* __restrict__ Ah, const u16* __restrict__ Al,
              const u16* __restrict__ Bh, const u16* __restrict__ Bl,
              float* __restrict__ Cf, u16* __restrict__ Ch, u16* __restrict__ Cl,
              const float* __restrict__ scale, int M, int N, int K,
              u16* __restrict__ Qh, u16* __restrict__ Ql,
              u16* __restrict__ Kh, u16* __restrict__ Kl,
              u16* __restrict__ Vh, u16* __restrict__ Vl) {
    __shared__ u16 smem[16384];
    const int tid = threadIdx.x;
    const int bm = blockIdx.y << 7, bn = blockIdx.x << 7;
    const int w = tid >> 6, l = tid & 63;
    const int wr = w >> 1, wc = w & 1;

    const size_t aoff0 = (size_t)(bm + (tid >> 2)) * K + ((tid & 3) << 3);
    const size_t boff0 = (size_t)(bn + (tid >> 2)) * K + ((tid & 3) << 3);
    const size_t s64 = (size_t)64 * K;
    char* sb = (char*)smem;
    const uint32_t wq = (uint32_t)w << 10;

    f32x4 acc[4][4] = {};

    for (int k0 = 0; k0 < K; k0 += 32) {
        __syncthreads();
        gl_lds16(Ah + aoff0 + k0,       sb + 0     + wq);
        gl_lds16(Ah + aoff0 + s64 + k0, sb + 4096  + wq);
        gl_lds16(Al + aoff0 + k0,       sb + 8192  + wq);
        gl_lds16(Al + aoff0 + s64 + k0, sb + 12288 + wq);
        gl_lds16(Bh + boff0 + k0,       sb + 16384 + wq);
        gl_lds16(Bh + boff0 + s64 + k0, sb + 20480 + wq);
        gl_lds16(Bl + boff0 + k0,       sb + 24576 + wq);
        gl_lds16(Bl + boff0 + s64 + k0, sb + 28672 + wq);
        __syncthreads();

        const int koff = (l >> 4) << 3;
        const int arow = wr * 64 + (l & 15);
        const int brow = wc * 64 + (l & 15);
        bf16x8 ah[4], al4[4], bh4[4], bl4[4];
        #pragma unroll
        for (int i = 0; i < 4; ++i) {
            ah[i]  = *(const bf16x8*)&smem[(arow + i * 16) * 32 + koff];
            al4[i] = *(const bf16x8*)&smem[4096  + (arow + i * 16) * 32 + koff];
            bh4[i] = *(const bf16x8*)&smem[8192  + (brow + i * 16) * 32 + koff];
            bl4[i] = *(const bf16x8*)&smem[12288 + (brow + i * 16) * 32 + koff];
        }
        #pragma unroll
        for (int i = 0; i < 4; ++i) {
            #pragma unroll
            for (int j = 0; j < 4; ++j) {
                acc[i][j] = __builtin_amdgcn_mfma_f32_16x16x32_bf16(ah[i],  bh4[j], acc[i][j], 0, 0, 0);
                acc[i][j] = __builtin_amdgcn_mfma_f32_16x16x32_bf16(ah[i],  bl4[j], acc[i][j], 0, 0, 0);
                acc[i][j] = __builtin_amdgcn_mfma_f32_16x16x32_bf16(al4[i], bh4[j], acc[i][j], 0, 0, 0);
            }
        }
    }

    // C/D frag: col = lane&15, row = (lane>>4)*4 + reg
    const int crow0 = bm + wr * 64 + ((l >> 4) << 2);
    const int ccol0 = bn + wc * 64 + (l & 15);
    #pragma unroll
    for (int i = 0; i < 4; ++i) {
        #pragma unroll
        for (int j = 0; j < 4; ++j) {
            const int col = ccol0 + j * 16;
            #pragma unroll
            for (int r = 0; r < 4; ++r) {
                const int row = crow0 + i * 16 + r;
                const size_t o = (size_t)row * N + col;
                float v = acc[i][j][r];
                if (EPI == 1) {
                    float g = gelu_tanh(v);
                    u16 hi, lo;
                    split_bf(g, hi, lo);
                    Ch[o] = hi; Cl[o] = lo;
                } else if (EPI == 2) {
                    Cf[o] += scale[col] * v;
                } else if (EPI == 3) {
                    const int which = (col >= 1536) ? 2 : ((col >= 768) ? 1 : 0);
                    const int hcol = col - which * 768;
                    const size_t dst = ((size_t)((row >> 10) * NHEAD + (hcol >> 6)) * 1024
                                        + (row & 1023)) * 64 + (hcol & 63);
                    if (which == 0) v *= 0.125f;
                    u16 hi, lo;
                    split_bf(v, hi, lo);
                    if (which == 0)      { Qh[dst] = hi; Ql[dst] = lo; }
                    else if (which == 1) { Kh[dst] = hi; Kl[dst] = lo; }
                    else                 { Vh[dst] = hi; Vl[dst] = lo; }
                }
            }
        }
    }
}

// --------------------------------------------------- MFMA flash attention
// 16x16x32 shape only (all fragment layouts proven by gemm_bf3 in r2).
// q/k [bh][t][64] split bf16 (q pre-scaled 0.125); vt [bh][64][t] split.
// ctx out [token][768] split bf16. 4 waves x 16 q-rows; 32-key tiles.
// No cross-wave LDS, no barriers, no staging: K/V frags read from global (L2).
__global__ __launch_bounds__(256)
void flash16(const u16* __restrict__ qh, const u16* __restrict__ ql,
             const u16* __restrict__ kh, const u16* __restrict__ kl,
             const u16* __restrict__ vth, const u16* __restrict__ vtl,
             u16* __restrict__ ch, u16* __restrict__ cl) {
    __shared__ u16 plds[4][16][32];   // per-wave P buffer
    const int bh = blockIdx.y, hh = bh % NHEAD, bb = bh / NHEAD;
    const int tid = threadIdx.x, w = tid >> 6, l = tid & 63;
    const int lq = l & 15, lg = l >> 4;
    const int wq = blockIdx.x * 64 + w * 16;
    const int q = wq + lq;
    const size_t hb = (size_t)bh << 16;   // bh * 1024 * 64

    // Q B-frags: B[col=q=lq][k-chunk lg*8], d = half*32 + lg*8 + e
    bf16x8 qf00, qf01, qf10, qf11;
    {
        const size_t qb = hb + ((size_t)q << 6) + lg * 8;
        qf00 = *(const bf16x8*)(qh + qb);
        qf01 = *(const bf16x8*)(ql + qb);
        qf10 = *(const bf16x8*)(qh + qb + 32);
        qf11 = *(const bf16x8*)(ql + qb + 32);
    }

    f32x4 o[4] = {};   // O^T[d = dt*16 + 4*lg + r][q = lq]
    float m = -30000.f, lsum = 0.f;
    const int ntiles = (wq >> 5) + 1;

    for (int kt = 0; kt < ntiles; ++kt) {
        const int k0 = kt * 32;
        // ---- S^T = K x Q^T, two 16-key subtiles, 3-term hi/lo split
        f32x4 s0 = {}, s1 = {};
        {
            const size_t kb0 = hb + (size_t)(k0 + lq) * 64 + lg * 8;
            bf16x8 ah0 = *(const bf16x8*)(kh + kb0);
            bf16x8 ah1 = *(const bf16x8*)(kh + kb0 + 32);
            bf16x8 al0 = *(const bf16x8*)(kl + kb0);
            bf16x8 al1 = *(const bf16x8*)(kl + kb0 + 32);
            s0 = mfma16(ah0, qf00, s0);
            s0 = mfma16(ah0, qf01, s0);
            s0 = mfma16(al0, qf00, s0);
            s0 = mfma16(ah1, qf10, s0);
            s0 = mfma16(ah1, qf11, s0);
            s0 = mfma16(al1, qf10, s0);
            const size_t kb1 = kb0 + 16 * 64;
            bf16x8 bh0 = *(const bf16x8*)(kh + kb1);
            bf16x8 bh1 = *(const bf16x8*)(kh + kb1 + 32);
            bf16x8 bl0 = *(const bf16x8*)(kl + kb1);
            bf16x8 bl1 = *(const bf16x8*)(kl + kb1 + 32);
            s1 = mfma16(bh0, qf00, s1);
            s1 = mfma16(bh0, qf01, s1);
            s1 = mfma16(bl0, qf00, s1);
            s1 = mfma16(bh1, qf10, s1);
            s1 = mfma16(bh1, qf11, s1);
            s1 = mfma16(bl1, qf10, s1);
        }
        // ---- causal mask: s[.] holds S^T[key = k0 + sub*16 + 4*lg + r][q]
        if (k0 + 31 > wq) {
            #pragma unroll
            for (int r = 0; r < 4; ++r) {
                if (k0 + 4 * lg + r > q)      s0[r] = -30000.f;
                if (k0 + 16 + 4 * lg + r > q) s1[r] = -30000.f;
            }
        }
        // ---- online softmax (per q = lq; combine 4 lane-groups)
        float tm = fmaxf(fmaxf(fmaxf(s0[0], s0[1]), fmaxf(s0[2], s0[3])),
                         fmaxf(fmaxf(s1[0], s1[1]), fmaxf(s1[2], s1[3])));
        tm = fmaxf(tm, __shfl_xor(tm, 16));
        tm = fmaxf(tm, __shfl_xor(tm, 32));
        const float mnew = fmaxf(m, tm);
        const float fac = __expf(m - mnew);
        m = mnew;
        lsum *= fac;
        #pragma unroll
        for (int dt = 0; dt < 4; ++dt) {
            o[dt][0] *= fac; o[dt][1] *= fac; o[dt][2] *= fac; o[dt][3] *= fac;
        }
        float ps = 0.f;
        #pragma unroll
        for (int r = 0; r < 4; ++r) {
            s0[r] = __expf(s0[r] - m); ps += s0[r];
            s1[r] = __expf(s1[r] - m); ps += s1[r];
        }
        lsum += ps;
        // ---- P -> per-wave LDS (write P[q=lq][k]), read back as B-frag
        *(uint32_t*)&plds[w][lq][4 * lg]          = cvt_pk_bf16(s0[0], s0[1]);
        *(uint32_t*)&plds[w][lq][4 * lg + 2]      = cvt_pk_bf16(s0[2], s0[3]);
        *(uint32_t*)&plds[w][lq][16 + 4 * lg]     = cvt_pk_bf16(s1[0], s1[1]);
        *(uint32_t*)&plds[w][lq][16 + 4 * lg + 2] = cvt_pk_bf16(s1[2], s1[3]);
        asm volatile("s_waitcnt lgkmcnt(0)" ::: "memory");
        __builtin_amdgcn_sched_barrier(0);
        bf16x8 pb = *(const bf16x8*)&plds[w][lq][lg * 8];   // B[col=q][k=lg*8+e]
        // ---- O^T += V^T x P^T  (A = V^T frag from vt, 2-term hi/lo)
        #pragma unroll
        for (int dt = 0; dt < 4; ++dt) {
            const size_t vb = hb + (size_t)(dt * 16 + lq) * 1024 + k0 + lg * 8;
            bf16x8 vfh = *(const bf16x8*)(vth + vb);
            bf16x8 vfl = *(const bf16x8*)(vtl + vb);
            o[dt] = mfma16(vfh, pb, o[dt]);
            o[dt] = mfma16(vfl, pb, o[dt]);
        }
    }
    // ---- normalize + write ctx (all per-lane: q = lq)
    lsum += __shfl_xor(lsum, 16);
    lsum += __shfl_xor(lsum, 32);
    const float inv = 1.f / lsum;
    const size_t cb = ((size_t)(bb * 1024 + q)) * 768 + hh * 64;
    #pragma unroll
    for (int dt = 0; dt < 4; ++dt) {
        u16 h4[4], l4[4];
        #pragma unroll
        for (int r = 0; r < 4; ++r) split_bf(o[dt][r] * inv, h4[r], l4[r]);
        const size_t co = cb + dt * 16 + 4 * lg;
        *(uint2*)&ch[co] = make_uint2((uint32_t)h4[0] | ((uint32_t)h4[1] << 16),
                                      (uint32_t)h4[2] | ((uint32_t)h4[3] << 16));
        *(uint2*)&cl[co] = make_uint2((uint32_t)l4[0] | ((uint32_t)l4[1] << 16),
                                      (uint32_t)l4[2] | ((uint32_t)l4[3] << 16));
    }
}

// ------------------------------------------------------------------- host

extern "C" void kernel_launch(void* const* d_in, const int* in_sizes, int n_in,
                              void* d_out, int out_size, void* d_ws, size_t ws_size,
                              hipStream_t stream) {
    const float* x0     = (const float*)d_in[0];
    const float* aproj  = (const float*)d_in[1];
    const float* mproj  = (const float*)d_in[2];
    const float* Wqkv   = (const float*)d_in[3];
    const float* Wo     = (const float*)d_in[4];
    const float* Wm1    = (const float*)d_in[5];
    const float* Wm2    = (const float*)d_in[6];
    const float* ascale = (const float*)d_in[7];
    const float* mscale = (const float*)d_in[8];
    const float* lns    = (const float*)d_in[9];
    float* out = (float*)d_out;
    char*  base = (char*)d_ws;

    // layout (bytes): p1..p3 (12 BTD) | xn hi/lo (4 BTD) | wt (9.44MB) | qkv family (16 BTD)
    float* p1  = (float*)base;
    float* p2  = p1 + BTD;
    float* p3  = p2 + BTD;
    u16*   xnh = (u16*)(base + 12 * BTD);
    u16*   xnl = xnh + BTD;
    u16*   wth = (u16*)(base + 16 * BTD);
    u16*   wtl = wth + (size_t)3072 * 768;
    char*  QB  = base + 16 * BTD + (size_t)2 * 2 * 3072 * 768;
    u16* qh  = (u16*)QB;
    u16* ql  = qh + BTD;
    u16* kh  = ql + BTD;
    u16* kl  = kh + BTD;
    u16* vh  = kl + BTD;
    u16* vl  = vh + BTD;
    u16* vth = vl + BTD;
    u16* vtl = vth + BTD;
    u16* midh = qh;   // [8192,3072] hi: spans qh..kl (dead then)
    u16* midl = vh;   // lo: spans vh..vtl (dead then)
    u16* ctxh = vh;   // flash out aliases normal-layout V (dead after vt pass)
    u16* ctxl = vl;

    float* pb[3] = {p1, p2, p3};
    const float* hist[6];
    int nh = 1;
    hist[0] = x0;
    const float* partial_c = x0;
    float* partial_w = nullptr;
    int pidx = 0;

    auto launch_agg = [&](int n, const float* Vl6[6], const float* qvec,
                          const float* lnsl) {
        switch (n) {
        case 2: agg_norm_kernel<2><<<dim3(ROWS), 256, 0, stream>>>(Vl6[0], Vl6[1], Vl6[2], Vl6[3], Vl6[4], Vl6[5], qvec, lnsl, xnh, xnl); break;
        case 3: agg_norm_kernel<3><<<dim3(ROWS), 256, 0, stream>>>(Vl6[0], Vl6[1], Vl6[2], Vl6[3], Vl6[4], Vl6[5], qvec, lnsl, xnh, xnl); break;
        case 4: agg_norm_kernel<4><<<dim3(ROWS), 256, 0, stream>>>(Vl6[0], Vl6[1], Vl6[2], Vl6[3], Vl6[4], Vl6[5], qvec, lnsl, xnh, xnl); break;
        case 5: agg_norm_kernel<5><<<dim3(ROWS), 256, 0, stream>>>(Vl6[0], Vl6[1], Vl6[2], Vl6[3], Vl6[4], Vl6[5], qvec, lnsl, xnh, xnl); break;
        default: agg_norm_kernel<6><<<dim3(ROWS), 256, 0, stream>>>(Vl6[0], Vl6[1], Vl6[2], Vl6[3], Vl6[4], Vl6[5], qvec, lnsl, xnh, xnl); break;
        }
    };

    for (int l = 0; l < NLAYER; ++l) {
        // ---- attention-path aggregate (reads OLD partial) -> xn hi/lo
        const float* Vl6[6] = {nullptr, nullptr, nullptr, nullptr, nullptr, nullptr};
        for (int i = 0; i < nh; ++i) Vl6[i] = hist[i];
        Vl6[nh] = partial_c;
        launch_agg(nh + 1, Vl6, aproj + (size_t)l * D_MODEL, lns + l);

        // ---- block boundary
        if ((l & 1) == 0) {
            hist[nh++] = partial_c;
            float* np = (pidx < 3) ? pb[pidx] : out;
            ++pidx;
            fill_zero4<<<dim3((int)(BTD / 4 / 256)), 256, 0, stream>>>((float4*)np, (int)(BTD / 4));
            partial_w = np;
            partial_c = np;
        }

        // ---- QKV GEMM -> head-major split q/k/v
        transpose_split<<<dim3(D_MODEL / 32, 3 * D_MODEL / 32), 256, 0, stream>>>(
            Wqkv + (size_t)l * D_MODEL * 3 * D_MODEL, wth, wtl, D_MODEL, 3 * D_MODEL);
        gemm_bf3<3><<<dim3(3 * D_MODEL / 128, ROWS / 128), 256, 0, stream>>>(
            xnh, xnl, wth, wtl, nullptr, nullptr, nullptr, nullptr,
            ROWS, 3 * D_MODEL, D_MODEL, qh, ql, kh, kl, vh, vl);

        // ---- V transpose -> vt
        vt_transpose<<<dim3(T_SEQ / 32, HDIM / 32, B_BATCH * NHEAD), 256, 0, stream>>>(
            vh, vl, vth, vtl);

        // ---- flash attention -> ctx (aliases vh/vl; flash reads vth/vtl only)
        flash16<<<dim3(T_SEQ / 64, B_BATCH * NHEAD), 256, 0, stream>>>(
            qh, ql, kh, kl, vth, vtl, ctxh, ctxl);

        // ---- Wo GEMM: partial += attn_scale * (ctx @ Wo)
        transpose_split<<<dim3(D_MODEL / 32, D_MODEL / 32), 256, 0, stream>>>(
            Wo + (size_t)l * D_MODEL * D_MODEL, wth, wtl, D_MODEL, D_MODEL);
        gemm_bf3<2><<<dim3(D_MODEL / 128, ROWS / 128), 256, 0, stream>>>(
            ctxh, ctxl, wth, wtl, partial_w, nullptr, nullptr,
            ascale + (size_t)l * D_MODEL, ROWS, D_MODEL, D_MODEL,
            nullptr, nullptr, nullptr, nullptr, nullptr, nullptr);

        // ---- mlp-path aggregate (reads NEW partial) -> xn hi/lo
        const float* V26[6] = {nullptr, nullptr, nullptr, nullptr, nullptr, nullptr};
        for (int i = 0; i < nh; ++i) V26[i] = hist[i];
        V26[nh] = partial_c;
        launch_agg(nh + 1, V26, mproj + (size_t)l * D_MODEL, lns + l);

        // ---- MLP
        transpose_split<<<dim3(D_MODEL / 32, 4 * D_MODEL / 32), 256, 0, stream>>>(
            Wm1 + (size_t)l * D_MODEL * 4 * D_MODEL, wth, wtl, D_MODEL, 4 * D_MODEL);
        gemm_bf3<1><<<dim3(4 * D_MODEL / 128, ROWS / 128), 256, 0, stream>>>(
            xnh, xnl, wth, wtl, nullptr, midh, midl, nullptr,
            ROWS, 4 * D_MODEL, D_MODEL,
            nullptr, nullptr, nullptr, nullptr, nullptr, nullptr);
        transpose_split<<<dim3(4 * D_MODEL / 32, D_MODEL / 32), 256, 0, stream>>>(
            Wm2 + (size_t)l * 4 * D_MODEL * D_MODEL, wth, wtl, 4 * D_MODEL, D_MODEL);
        gemm_bf3<2><<<dim3(D_MODEL / 128, ROWS / 128), 256, 0, stream>>>(
            midh, midl, wth, wtl, partial_w, nullptr, nullptr,
            mscale + (size_t)l * D_MODEL, ROWS, D_MODEL, 4 * D_MODEL,
            nullptr, nullptr, nullptr, nullptr, nullptr, nullptr);
    }
}

// Round 5
// 5830.099 us; speedup vs baseline: 3.4305x; 1.2129x over previous
//
#include <hip/hip_runtime.h>
#include <hip/hip_bf16.h>
#include <math.h>
#include <stdint.h>

#define D_MODEL 768
#define T_SEQ   1024
#define B_BATCH 8
#define NHEAD   12
#define HDIM    64
#define NLAYER  8

typedef unsigned short u16;
typedef __attribute__((ext_vector_type(8))) short bf16x8;
typedef __attribute__((ext_vector_type(4))) float f32x4;
typedef __attribute__((ext_vector_type(4))) uint32_t u32x4;

static constexpr size_t BTD  = (size_t)B_BATCH * T_SEQ * D_MODEL;  // 6291456
static constexpr int    ROWS = B_BATCH * T_SEQ;                    // 8192
static constexpr float  EPSF = 1.1920928955078125e-07f;            // FLT_EPSILON

// ---------------------------------------------------------------- helpers

__device__ __forceinline__ u16 f2bf(float x) {
    __hip_bfloat16 h = __float2bfloat16(x);
    return __builtin_bit_cast(u16, h);
}
__device__ __forceinline__ float bf2f(u16 u) {
    __hip_bfloat16 h = __builtin_bit_cast(__hip_bfloat16, u);
    return __bfloat162float(h);
}
__device__ __forceinline__ void split_bf(float x, u16& hi, u16& lo) {
    hi = f2bf(x);
    lo = f2bf(x - bf2f(hi));
}
__device__ __forceinline__ uint32_t cvt_pk_bf16(float a, float b) {
    uint32_t r;
    asm("v_cvt_pk_bf16_f32 %0, %1, %2" : "=v"(r) : "v"(a), "v"(b));
    return r;
}
__device__ __forceinline__ f32x4 mfma16(bf16x8 a, bf16x8 b, f32x4 c) {
    return __builtin_amdgcn_mfma_f32_16x16x32_bf16(a, b, c, 0, 0, 0);
}

// async global->LDS, 16B/lane; LDS dest wave-uniform base (HW adds lane*16)
__device__ __forceinline__ void gl_lds16(const void* g, void* l) {
    auto gp = reinterpret_cast<const __attribute__((address_space(1))) char*>(
        reinterpret_cast<uintptr_t>(g));
    auto lp = reinterpret_cast<__attribute__((address_space(3))) char*>(
        static_cast<uint32_t>(reinterpret_cast<uintptr_t>(l)));
    __builtin_amdgcn_global_load_lds(gp, lp, 16, 0, 0);
}

__global__ __launch_bounds__(256) void fill_zero4(float4* __restrict__ p, int n4) {
    int i = blockIdx.x * 256 + threadIdx.x;
    if (i < n4) p[i] = make_float4(0.f, 0.f, 0.f, 0.f);
}

__device__ __forceinline__ float block_reduce_sum(float v, float* sbuf) {
    #pragma unroll
    for (int off = 32; off > 0; off >>= 1) v += __shfl_down(v, off);
    __syncthreads();
    if ((threadIdx.x & 63) == 0) sbuf[threadIdx.x >> 6] = v;
    __syncthreads();
    return sbuf[0] + sbuf[1] + sbuf[2] + sbuf[3];
}

__device__ __forceinline__ float gelu_tanh(float x) {
    float x3 = x * x * x;
    float t  = tanhf(0.7978845608028654f * (x + 0.044715f * x3));
    return 0.5f * x * (1.f + t);
}

// ------------------------------------------------- aggregate + rmsnorm fuse
template<int N>
__global__ __launch_bounds__(256)
void agg_norm_kernel(const float* __restrict__ v0, const float* __restrict__ v1,
                     const float* __restrict__ v2, const float* __restrict__ v3,
                     const float* __restrict__ v4, const float* __restrict__ v5,
                     const float* __restrict__ q,  const float* __restrict__ lns,
                     u16* __restrict__ xh, u16* __restrict__ xl) {
    __shared__ float sbuf[4];
    const float* V[6] = {v0, v1, v2, v3, v4, v5};
    const size_t row = blockIdx.x;
    const int tid = threadIdx.x;

    float qv[3];
    #pragma unroll
    for (int j = 0; j < 3; ++j) qv[j] = q[tid + j * 256];

    float vv[N][3];
    float logits[N];
    #pragma unroll
    for (int i = 0; i < N; ++i) {
        const float* vr = V[i] + row * D_MODEL;
        float ssq = 0.f, qd = 0.f;
        #pragma unroll
        for (int j = 0; j < 3; ++j) {
            float x = vr[tid + j * 256];
            vv[i][j] = x;
            ssq = fmaf(x, x, ssq);
            qd  = fmaf(qv[j], x, qd);
        }
        float S  = block_reduce_sum(ssq, sbuf);
        float Qd = block_reduce_sum(qd,  sbuf);
        logits[i] = Qd * rsqrtf(S * (1.f / 768.f) + EPSF);
    }
    float mx = logits[0];
    #pragma unroll
    for (int i = 1; i < N; ++i) mx = fmaxf(mx, logits[i]);
    float w[N];
    float wsum = 0.f;
    #pragma unroll
    for (int i = 0; i < N; ++i) { w[i] = __expf(logits[i] - mx); wsum += w[i]; }
    float inv = 1.f / wsum;

    float outv[3] = {0.f, 0.f, 0.f};
    #pragma unroll
    for (int i = 0; i < N; ++i) {
        float wi = w[i] * inv;
        #pragma unroll
        for (int j = 0; j < 3; ++j) outv[j] = fmaf(wi, vv[i][j], outv[j]);
    }
    float ssq = 0.f;
    #pragma unroll
    for (int j = 0; j < 3; ++j) ssq = fmaf(outv[j], outv[j], ssq);
    float S2 = block_reduce_sum(ssq, sbuf);
    float scale = lns[0] * rsqrtf(S2 * (1.f / 768.f) + EPSF);
    #pragma unroll
    for (int j = 0; j < 3; ++j) {
        float x = outv[j] * scale;
        u16 hi, lo;
        split_bf(x, hi, lo);
        size_t idx = row * D_MODEL + tid + j * 256;
        xh[idx] = hi;
        xl[idx] = lo;
    }
}

// ---------------------------------------------- weight transpose + bf split
__global__ __launch_bounds__(256)
void transpose_split(const float* __restrict__ W, u16* __restrict__ Th,
                     u16* __restrict__ Tl, int K, int N) {
    __shared__ float t[32][33];
    const int bk = blockIdx.x * 32, bn = blockIdx.y * 32;
    const int r = threadIdx.x >> 3, c4 = (threadIdx.x & 7) * 4;
    float4 v = *(const float4*)&W[(size_t)(bk + r) * N + bn + c4];
    t[r][c4 + 0] = v.x; t[r][c4 + 1] = v.y; t[r][c4 + 2] = v.z; t[r][c4 + 3] = v.w;
    __syncthreads();
    u16 h[4], lo[4];
    #pragma unroll
    for (int j = 0; j < 4; ++j) split_bf(t[c4 + j][r], h[j], lo[j]);
    size_t o = (size_t)(bn + r) * K + bk + c4;
    *(uint2*)&Th[o] = make_uint2((uint32_t)h[0]  | ((uint32_t)h[1]  << 16),
                                 (uint32_t)h[2]  | ((uint32_t)h[3]  << 16));
    *(uint2*)&Tl[o] = make_uint2((uint32_t)lo[0] | ((uint32_t)lo[1] << 16),
                                 (uint32_t)lo[2] | ((uint32_t)lo[3] << 16));
}

// ---------------------------------------------- V transpose (head-major)
// in  vh/vl [bh][1024][64] -> out vth/vtl [bh][64][1024]
__global__ __launch_bounds__(256)
void vt_transpose(const u16* __restrict__ vh, const u16* __restrict__ vl,
                  u16* __restrict__ vth, u16* __restrict__ vtl) {
    __shared__ u16 th[32][36];
    __shared__ u16 tl[32][36];
    const int bh = blockIdx.z;
    const int t0 = blockIdx.x * 32, d0 = blockIdx.y * 32;
    const int r = threadIdx.x >> 3, c = (threadIdx.x & 7) * 4;
    const size_t ib = ((size_t)(bh << 10) + t0 + r) * 64 + d0 + c;
    *(uint2*)&th[r][c] = *(const uint2*)&vh[ib];
    *(uint2*)&tl[r][c] = *(const uint2*)&vl[ib];
    __syncthreads();
    const size_t ob = ((size_t)(bh << 6) + d0 + r) * 1024 + t0 + c;
    u16 a0 = th[c + 0][r], a1 = th[c + 1][r], a2 = th[c + 2][r], a3 = th[c + 3][r];
    *(uint2*)&vth[ob] = make_uint2((uint32_t)a0 | ((uint32_t)a1 << 16),
                                   (uint32_t)a2 | ((uint32_t)a3 << 16));
    u16 b0 = tl[c + 0][r], b1 = tl[c + 1][r], b2 = tl[c + 2][r], b3 = tl[c + 3][r];
    *(uint2*)&vtl[ob] = make_uint2((uint32_t)b0 | ((uint32_t)b1 << 16),
                                   (uint32_t)b2 | ((uint32_t)b3 << 16));
}

// ------------------------------------------------- split-bf16 MFMA GEMM
// C[M,N] = (Ah+Al)[M,K] @ (Bh+Bl)^T  (B given as [N][K]); 3-term product.
// EPI: 1 = gelu -> bf16 hi/lo, 2 = Cf += scale[n]*acc,
//      3 = scatter qkv (q*0.125) into head-major split buffers
template<int EPI>
__global__ __launch_bounds__(256)
void gemm_bf3(const u16* __restrict__ Ah, const u16* __restrict__ Al,
              const u16* __restrict__ Bh, const u16* __restrict__ Bl,
              float* __restrict__ Cf, u16* __restrict__ Ch, u16* __restrict__ Cl,
              const float* __restrict__ scale, int M, int N, int K,
              u16* __restrict__ Qh, u16* __restrict__ Ql,
              u16* __restrict__ Kh, u16* __restrict__ Kl,
              u16* __restrict__ Vh, u16* __restrict__ Vl) {
    __shared__ u16 smem[16384];
    const int tid = threadIdx.x;
    const int bm = blockIdx.y << 7, bn = blockIdx.x << 7;
    const int w = tid >> 6, l = tid & 63;
    const int wr = w >> 1, wc = w & 1;

    const size_t aoff0 = (size_t)(bm + (tid >> 2)) * K + ((tid & 3) << 3);
    const size_t boff0 = (size_t)(bn + (tid >> 2)) * K + ((tid & 3) << 3);
    const size_t s64 = (size_t)64 * K;
    char* sb = (char*)smem;
    const uint32_t wq = (uint32_t)w << 10;

    f32x4 acc[4][4] = {};

    for (int k0 = 0; k0 < K; k0 += 32) {
        __syncthreads();
        gl_lds16(Ah + aoff0 + k0,       sb + 0     + wq);
        gl_lds16(Ah + aoff0 + s64 + k0, sb + 4096  + wq);
        gl_lds16(Al + aoff0 + k0,       sb + 8192  + wq);
        gl_lds16(Al + aoff0 + s64 + k0, sb + 12288 + wq);
        gl_lds16(Bh + boff0 + k0,       sb + 16384 + wq);
        gl_lds16(Bh + boff0 + s64 + k0, sb + 20480 + wq);
        gl_lds16(Bl + boff0 + k0,       sb + 24576 + wq);
        gl_lds16(Bl + boff0 + s64 + k0, sb + 28672 + wq);
        __syncthreads();

        const int koff = (l >> 4) << 3;
        const int arow = wr * 64 + (l & 15);
        const int brow = wc * 64 + (l & 15);
        bf16x8 ah[4], al4[4], bh4[4], bl4[4];
        #pragma unroll
        for (int i = 0; i < 4; ++i) {
            ah[i]  = *(const bf16x8*)&smem[(arow + i * 16) * 32 + koff];
            al4[i] = *(const bf16x8*)&smem[4096  + (arow + i * 16) * 32 + koff];
            bh4[i] = *(const bf16x8*)&smem[8192  + (brow + i * 16) * 32 + koff];
            bl4[i] = *(const bf16x8*)&smem[12288 + (brow + i * 16) * 32 + koff];
        }
        #pragma unroll
        for (int i = 0; i < 4; ++i) {
            #pragma unroll
            for (int j = 0; j < 4; ++j) {
                acc[i][j] = __builtin_amdgcn_mfma_f32_16x16x32_bf16(ah[i],  bh4[j], acc[i][j], 0, 0, 0);
                acc[i][j] = __builtin_amdgcn_mfma_f32_16x16x32_bf16(ah[i],  bl4[j], acc[i][j], 0, 0, 0);
                acc[i][j] = __builtin_amdgcn_mfma_f32_16x16x32_bf16(al4[i], bh4[j], acc[i][j], 0, 0, 0);
            }
        }
    }

    // C/D frag: col = lane&15, row = (lane>>4)*4 + reg
    const int crow0 = bm + wr * 64 + ((l >> 4) << 2);
    const int ccol0 = bn + wc * 64 + (l & 15);
    #pragma unroll
    for (int i = 0; i < 4; ++i) {
        #pragma unroll
        for (int j = 0; j < 4; ++j) {
            const int col = ccol0 + j * 16;
            #pragma unroll
            for (int r = 0; r < 4; ++r) {
                const int row = crow0 + i * 16 + r;
                const size_t o = (size_t)row * N + col;
                float v = acc[i][j][r];
                if (EPI == 1) {
                    float g = gelu_tanh(v);
                    u16 hi, lo;
                    split_bf(g, hi, lo);
                    Ch[o] = hi; Cl[o] = lo;
                } else if (EPI == 2) {
                    Cf[o] += scale[col] * v;
                } else if (EPI == 3) {
                    const int which = (col >= 1536) ? 2 : ((col >= 768) ? 1 : 0);
                    const int hcol = col - which * 768;
                    const size_t dst = ((size_t)((row >> 10) * NHEAD + (hcol >> 6)) * 1024
                                        + (row & 1023)) * 64 + (hcol & 63);
                    if (which == 0) v *= 0.125f;
                    u16 hi, lo;
                    split_bf(v, hi, lo);
                    if (which == 0)      { Qh[dst] = hi; Ql[dst] = lo; }
                    else if (which == 1) { Kh[dst] = hi; Kl[dst] = lo; }
                    else                 { Vh[dst] = hi; Vl[dst] = lo; }
                }
            }
        }
    }
}

// --------------------------------------------------- MFMA flash attention
// 16x16x32 fragment conventions (proven by gemm_bf3 / r4 flash16).
// Pairing: block handles q-tiles {p, 15-p}, shared K/V fragment stream.
// P redistribution via register shuffles (no LDS, no fences).
// Grid: 768 blocks 1D; decode keeps all pairs of one head on one XCD.
__global__ __launch_bounds__(256)
void flash16(const u16* __restrict__ qh, const u16* __restrict__ ql,
             const u16* __restrict__ kh, const u16* __restrict__ kl,
             const u16* __restrict__ vth, const u16* __restrict__ vtl,
             u16* __restrict__ ch, u16* __restrict__ cl) {
    const int id = blockIdx.x;
    const int r8 = id & 7, s = id >> 3;
    const int bh = r8 + 8 * (s >> 3);       // same-head blocks -> same XCD slot
    const int p  = s & 7;                   // pair index: q-tiles {p, 15-p}
    const int hh = bh % NHEAD, bb = bh / NHEAD;
    const int tid = threadIdx.x, w = tid >> 6, l = tid & 63;
    const int lq = l & 15, lg = l >> 4;
    const size_t hb = (size_t)bh << 16;     // bh * 1024 * 64

    const int wqA = p * 64 + w * 16;        // low q-subtile base
    const int wqB = (15 - p) * 64 + w * 16; // high q-subtile base
    const int qA = wqA + lq, qB = wqB + lq;

    // Q B-frags: B[col=q][k=lg*8+e]; hi/lo interleave as in r4
    bf16x8 qA00, qA01, qA10, qA11, qB00, qB01, qB10, qB11;
    {
        const size_t qa = hb + ((size_t)qA << 6) + lg * 8;
        qA00 = *(const bf16x8*)(qh + qa);       qA01 = *(const bf16x8*)(ql + qa);
        qA10 = *(const bf16x8*)(qh + qa + 32);  qA11 = *(const bf16x8*)(ql + qa + 32);
        const size_t qb = hb + ((size_t)qB << 6) + lg * 8;
        qB00 = *(const bf16x8*)(qh + qb);       qB01 = *(const bf16x8*)(ql + qb);
        qB10 = *(const bf16x8*)(qh + qb + 32);  qB11 = *(const bf16x8*)(ql + qb + 32);
    }

    f32x4 oA[4] = {}, oB[4] = {};
    float mA = -30000.f, lsA = 0.f, mB = -30000.f, lsB = 0.f;
    const int ntiles = 32 - 2 * p;
    const int src0 = 32 * (lg & 1) + lq, src1 = src0 + 16;
    const bool hiHalf = lg >= 2;

    for (int kt = 0; kt < ntiles; ++kt) {
        const int k0 = kt * 32;
        // ---- shared K fragments (A-operand rows = keys)
        const size_t kb0 = hb + (size_t)(k0 + lq) * 64 + lg * 8;
        const size_t kb1 = kb0 + 16 * 64;
        bf16x8 ka0 = *(const bf16x8*)(kh + kb0);
        bf16x8 ka1 = *(const bf16x8*)(kh + kb0 + 32);
        bf16x8 kc0 = *(const bf16x8*)(kl + kb0);
        bf16x8 kc1 = *(const bf16x8*)(kl + kb0 + 32);
        bf16x8 kd0 = *(const bf16x8*)(kh + kb1);
        bf16x8 kd1 = *(const bf16x8*)(kh + kb1 + 32);
        bf16x8 ke0 = *(const bf16x8*)(kl + kb1);
        bf16x8 ke1 = *(const bf16x8*)(kl + kb1 + 32);
        // ---- shared V fragments (issued early; used after softmax)
        bf16x8 vfh[4], vfl[4];
        #pragma unroll
        for (int dt = 0; dt < 4; ++dt) {
            const size_t vb = hb + (size_t)(dt * 16 + lq) * 1024 + k0 + lg * 8;
            vfh[dt] = *(const bf16x8*)(vth + vb);
            vfl[dt] = *(const bf16x8*)(vtl + vb);
        }
        const bool actA = (k0 <= wqA + 31);

        // ---- S^T for B (always) and A (while in range), 3-term split
        f32x4 s0B = {}, s1B = {}, s0A = {}, s1A = {};
        s0B = mfma16(ka0, qB00, s0B); s0B = mfma16(ka0, qB01, s0B);
        s0B = mfma16(kc0, qB00, s0B); s0B = mfma16(ka1, qB10, s0B);
        s0B = mfma16(ka1, qB11, s0B); s0B = mfma16(kc1, qB10, s0B);
        s1B = mfma16(kd0, qB00, s1B); s1B = mfma16(kd0, qB01, s1B);
        s1B = mfma16(ke0, qB00, s1B); s1B = mfma16(kd1, qB10, s1B);
        s1B = mfma16(kd1, qB11, s1B); s1B = mfma16(ke1, qB10, s1B);
        if (actA) {
            s0A = mfma16(ka0, qA00, s0A); s0A = mfma16(ka0, qA01, s0A);
            s0A = mfma16(kc0, qA00, s0A); s0A = mfma16(ka1, qA10, s0A);
            s0A = mfma16(ka1, qA11, s0A); s0A = mfma16(kc1, qA10, s0A);
            s1A = mfma16(kd0, qA00, s1A); s1A = mfma16(kd0, qA01, s1A);
            s1A = mfma16(ke0, qA00, s1A); s1A = mfma16(kd1, qA10, s1A);
            s1A = mfma16(kd1, qA11, s1A); s1A = mfma16(ke1, qA10, s1A);
        }

        // ================= B path =================
        if (k0 + 31 > wqB) {
            #pragma unroll
            for (int r = 0; r < 4; ++r) {
                if (k0 + 4 * lg + r > qB)      s0B[r] = -30000.f;
                if (k0 + 16 + 4 * lg + r > qB) s1B[r] = -30000.f;
            }
        }
        {
            float tm = fmaxf(fmaxf(fmaxf(s0B[0], s0B[1]), fmaxf(s0B[2], s0B[3])),
                             fmaxf(fmaxf(s1B[0], s1B[1]), fmaxf(s1B[2], s1B[3])));
            tm = fmaxf(tm, __shfl_xor(tm, 16));
            tm = fmaxf(tm, __shfl_xor(tm, 32));
            const float mnew = fmaxf(mB, tm);
            const float fac = __expf(mB - mnew);
            mB = mnew;
            lsB *= fac;
            #pragma unroll
            for (int dt = 0; dt < 4; ++dt) {
                oB[dt][0] *= fac; oB[dt][1] *= fac; oB[dt][2] *= fac; oB[dt][3] *= fac;
            }
            float ps = 0.f;
            #pragma unroll
            for (int r = 0; r < 4; ++r) {
                s0B[r] = __expf(s0B[r] - mB); ps += s0B[r];
                s1B[r] = __expf(s1B[r] - mB); ps += s1B[r];
            }
            lsB += ps;
            const uint32_t wA0 = cvt_pk_bf16(s0B[0], s0B[1]);
            const uint32_t wA1 = cvt_pk_bf16(s0B[2], s0B[3]);
            const uint32_t wB0 = cvt_pk_bf16(s1B[0], s1B[1]);
            const uint32_t wB1 = cvt_pk_bf16(s1B[2], s1B[3]);
            const uint32_t a0 = (uint32_t)__shfl((int)wA0, src0);
            const uint32_t b0 = (uint32_t)__shfl((int)wB0, src0);
            const uint32_t a1 = (uint32_t)__shfl((int)wA1, src0);
            const uint32_t b1 = (uint32_t)__shfl((int)wB1, src0);
            const uint32_t a2 = (uint32_t)__shfl((int)wA0, src1);
            const uint32_t b2 = (uint32_t)__shfl((int)wB0, src1);
            const uint32_t a3 = (uint32_t)__shfl((int)wA1, src1);
            const uint32_t b3 = (uint32_t)__shfl((int)wB1, src1);
            u32x4 pw = { hiHalf ? b0 : a0, hiHalf ? b1 : a1,
                         hiHalf ? b2 : a2, hiHalf ? b3 : a3 };
            const bf16x8 pb = __builtin_bit_cast(bf16x8, pw);
            #pragma unroll
            for (int dt = 0; dt < 4; ++dt) {
                oB[dt] = mfma16(vfh[dt], pb, oB[dt]);
                oB[dt] = mfma16(vfl[dt], pb, oB[dt]);
            }
        }

        // ================= A path =================
        if (actA) {
            if (k0 + 31 > wqA) {
                #pragma unroll
                for (int r = 0; r < 4; ++r) {
                    if (k0 + 4 * lg + r > qA)      s0A[r] = -30000.f;
                    if (k0 + 16 + 4 * lg + r > qA) s1A[r] = -30000.f;
                }
            }
            float tm = fmaxf(fmaxf(fmaxf(s0A[0], s0A[1]), fmaxf(s0A[2], s0A[3])),
                             fmaxf(fmaxf(s1A[0], s1A[1]), fmaxf(s1A[2], s1A[3])));
            tm = fmaxf(tm, __shfl_xor(tm, 16));
            tm = fmaxf(tm, __shfl_xor(tm, 32));
            const float mnew = fmaxf(mA, tm);
            const float fac = __expf(mA - mnew);
            mA = mnew;
            lsA *= fac;
            #pragma unroll
            for (int dt = 0; dt < 4; ++dt) {
                oA[dt][0] *= fac; oA[dt][1] *= fac; oA[dt][2] *= fac; oA[dt][3] *= fac;
            }
            float ps = 0.f;
            #pragma unroll
            for (int r = 0; r < 4; ++r) {
                s0A[r] = __expf(s0A[r] - mA); ps += s0A[r];
                s1A[r] = __expf(s1A[r] - mA); ps += s1A[r];
            }
            lsA += ps;
            const uint32_t wA0 = cvt_pk_bf16(s0A[0], s0A[1]);
            const uint32_t wA1 = cvt_pk_bf16(s0A[2], s0A[3]);
            const uint32_t wB0 = cvt_pk_bf16(s1A[0], s1A[1]);
            const uint32_t wB1 = cvt_pk_bf16(s1A[2], s1A[3]);
            const uint32_t a0 = (uint32_t)__shfl((int)wA0, src0);
            const uint32_t b0 = (uint32_t)__shfl((int)wB0, src0);
            const uint32_t a1 = (uint32_t)__shfl((int)wA1, src0);
            const uint32_t b1 = (uint32_t)__shfl((int)wB1, src0);
            const uint32_t a2 = (uint32_t)__shfl((int)wA0, src1);
            const uint32_t b2 = (uint32_t)__shfl((int)wB0, src1);
            const uint32_t a3 = (uint32_t)__shfl((int)wA1, src1);
            const uint32_t b3 = (uint32_t)__shfl((int)wB1, src1);
            u32x4 pw = { hiHalf ? b0 : a0, hiHalf ? b1 : a1,
                         hiHalf ? b2 : a2, hiHalf ? b3 : a3 };
            const bf16x8 pb = __builtin_bit_cast(bf16x8, pw);
            #pragma unroll
            for (int dt = 0; dt < 4; ++dt) {
                oA[dt] = mfma16(vfh[dt], pb, oA[dt]);
                oA[dt] = mfma16(vfl[dt], pb, oA[dt]);
            }
        }
    }

    // ---- normalize + write both q-tiles
    lsA += __shfl_xor(lsA, 16); lsA += __shfl_xor(lsA, 32);
    lsB += __shfl_xor(lsB, 16); lsB += __shfl_xor(lsB, 32);
    const float invA = 1.f / lsA, invB = 1.f / lsB;
    const size_t cbA = ((size_t)(bb * 1024 + qA)) * 768 + hh * 64;
    const size_t cbB = ((size_t)(bb * 1024 + qB)) * 768 + hh * 64;
    #pragma unroll
    for (int dt = 0; dt < 4; ++dt) {
        u16 h4[4], l4[4];
        #pragma unroll
        for (int r = 0; r < 4; ++r) split_bf(oA[dt][r] * invA, h4[r], l4[r]);
        size_t co = cbA + dt * 16 + 4 * lg;
        *(uint2*)&ch[co] = make_uint2((uint32_t)h4[0] | ((uint32_t)h4[1] << 16),
                                      (uint32_t)h4[2] | ((uint32_t)h4[3] << 16));
        *(uint2*)&cl[co] = make_uint2((uint32_t)l4[0] | ((uint32_t)l4[1] << 16),
                                      (uint32_t)l4[2] | ((uint32_t)l4[3] << 16));
        #pragma unroll
        for (int r = 0; r < 4; ++r) split_bf(oB[dt][r] * invB, h4[r], l4[r]);
        co = cbB + dt * 16 + 4 * lg;
        *(uint2*)&ch[co] = make_uint2((uint32_t)h4[0] | ((uint32_t)h4[1] << 16),
                                      (uint32_t)h4[2] | ((uint32_t)h4[3] << 16));
        *(uint2*)&cl[co] = make_uint2((uint32_t)l4[0] | ((uint32_t)l4[1] << 16),
                                      (uint32_t)l4[2] | ((uint32_t)l4[3] << 16));
    }
}

// ------------------------------------------------------------------- host

extern "C" void kernel_launch(void* const* d_in, const int* in_sizes, int n_in,
                              void* d_out, int out_size, void* d_ws, size_t ws_size,
                              hipStream_t stream) {
    const float* x0     = (const float*)d_in[0];
    const float* aproj  = (const float*)d_in[1];
    const float* mproj  = (const float*)d_in[2];
    const float* Wqkv   = (const float*)d_in[3];
    const float* Wo     = (const float*)d_in[4];
    const float* Wm1    = (const float*)d_in[5];
    const float* Wm2    = (const float*)d_in[6];
    const float* ascale = (const float*)d_in[7];
    const float* mscale = (const float*)d_in[8];
    const float* lns    = (const float*)d_in[9];
    float* out = (float*)d_out;
    char*  base = (char*)d_ws;

    // layout (bytes): p1..p3 (12 BTD) | xn hi/lo (4 BTD) | wt (9.44MB) | qkv family (16 BTD)
    float* p1  = (float*)base;
    float* p2  = p1 + BTD;
    float* p3  = p2 + BTD;
    u16*   xnh = (u16*)(base + 12 * BTD);
    u16*   xnl = xnh + BTD;
    u16*   wth = (u16*)(base + 16 * BTD);
    u16*   wtl = wth + (size_t)3072 * 768;
    char*  QB  = base + 16 * BTD + (size_t)2 * 2 * 3072 * 768;
    u16* qh  = (u16*)QB;
    u16* ql  = qh + BTD;
    u16* kh  = ql + BTD;
    u16* kl  = kh + BTD;
    u16* vh  = kl + BTD;
    u16* vl  = vh + BTD;
    u16* vth = vl + BTD;
    u16* vtl = vth + BTD;
    u16* midh = qh;   // [8192,3072] hi: spans qh..kl (dead then)
    u16* midl = vh;   // lo: spans vh..vtl (dead then)
    u16* ctxh = vh;   // flash out aliases normal-layout V (dead after vt pass)
    u16* ctxl = vl;

    float* pb[3] = {p1, p2, p3};
    const float* hist[6];
    int nh = 1;
    hist[0] = x0;
    const float* partial_c = x0;
    float* partial_w = nullptr;
    int pidx = 0;

    auto launch_agg = [&](int n, const float* Vl6[6], const float* qvec,
                          const float* lnsl) {
        switch (n) {
        case 2: agg_norm_kernel<2><<<dim3(ROWS), 256, 0, stream>>>(Vl6[0], Vl6[1], Vl6[2], Vl6[3], Vl6[4], Vl6[5], qvec, lnsl, xnh, xnl); break;
        case 3: agg_norm_kernel<3><<<dim3(ROWS), 256, 0, stream>>>(Vl6[0], Vl6[1], Vl6[2], Vl6[3], Vl6[4], Vl6[5], qvec, lnsl, xnh, xnl); break;
        case 4: agg_norm_kernel<4><<<dim3(ROWS), 256, 0, stream>>>(Vl6[0], Vl6[1], Vl6[2], Vl6[3], Vl6[4], Vl6[5], qvec, lnsl, xnh, xnl); break;
        case 5: agg_norm_kernel<5><<<dim3(ROWS), 256, 0, stream>>>(Vl6[0], Vl6[1], Vl6[2], Vl6[3], Vl6[4], Vl6[5], qvec, lnsl, xnh, xnl); break;
        default: agg_norm_kernel<6><<<dim3(ROWS), 256, 0, stream>>>(Vl6[0], Vl6[1], Vl6[2], Vl6[3], Vl6[4], Vl6[5], qvec, lnsl, xnh, xnl); break;
        }
    };

    for (int l = 0; l < NLAYER; ++l) {
        // ---- attention-path aggregate (reads OLD partial) -> xn hi/lo
        const float* Vl6[6] = {nullptr, nullptr, nullptr, nullptr, nullptr, nullptr};
        for (int i = 0; i < nh; ++i) Vl6[i] = hist[i];
        Vl6[nh] = partial_c;
        launch_agg(nh + 1, Vl6, aproj + (size_t)l * D_MODEL, lns + l);

        // ---- block boundary
        if ((l & 1) == 0) {
            hist[nh++] = partial_c;
            float* np = (pidx < 3) ? pb[pidx] : out;
            ++pidx;
            fill_zero4<<<dim3((int)(BTD / 4 / 256)), 256, 0, stream>>>((float4*)np, (int)(BTD / 4));
            partial_w = np;
            partial_c = np;
        }

        // ---- QKV GEMM -> head-major split q/k/v
        transpose_split<<<dim3(D_MODEL / 32, 3 * D_MODEL / 32), 256, 0, stream>>>(
            Wqkv + (size_t)l * D_MODEL * 3 * D_MODEL, wth, wtl, D_MODEL, 3 * D_MODEL);
        gemm_bf3<3><<<dim3(3 * D_MODEL / 128, ROWS / 128), 256, 0, stream>>>(
            xnh, xnl, wth, wtl, nullptr, nullptr, nullptr, nullptr,
            ROWS, 3 * D_MODEL, D_MODEL, qh, ql, kh, kl, vh, vl);

        // ---- V transpose -> vt
        vt_transpose<<<dim3(T_SEQ / 32, HDIM / 32, B_BATCH * NHEAD), 256, 0, stream>>>(
            vh, vl, vth, vtl);

        // ---- flash attention -> ctx (aliases vh/vl; flash reads vth/vtl only)
        flash16<<<dim3(768), 256, 0, stream>>>(
            qh, ql, kh, kl, vth, vtl, ctxh, ctxl);

        // ---- Wo GEMM: partial += attn_scale * (ctx @ Wo)
        transpose_split<<<dim3(D_MODEL / 32, D_MODEL / 32), 256, 0, stream>>>(
            Wo + (size_t)l * D_MODEL * D_MODEL, wth, wtl, D_MODEL, D_MODEL);
        gemm_bf3<2><<<dim3(D_MODEL / 128, ROWS / 128), 256, 0, stream>>>(
            ctxh, ctxl, wth, wtl, partial_w, nullptr, nullptr,
            ascale + (size_t)l * D_MODEL, ROWS, D_MODEL, D_MODEL,
            nullptr, nullptr, nullptr, nullptr, nullptr, nullptr);

        // ---- mlp-path aggregate (reads NEW partial) -> xn hi/lo
        const float* V26[6] = {nullptr, nullptr, nullptr, nullptr, nullptr, nullptr};
        for (int i = 0; i < nh; ++i) V26[i] = hist[i];
        V26[nh] = partial_c;
        launch_agg(nh + 1, V26, mproj + (size_t)l * D_MODEL, lns + l);

        // ---- MLP
        transpose_split<<<dim3(D_MODEL / 32, 4 * D_MODEL / 32), 256, 0, stream>>>(
            Wm1 + (size_t)l * D_MODEL * 4 * D_MODEL, wth, wtl, D_MODEL, 4 * D_MODEL);
        gemm_bf3<1><<<dim3(4 * D_MODEL / 128, ROWS / 128), 256, 0, stream>>>(
            xnh, xnl, wth, wtl, nullptr, midh, midl, nullptr,
            ROWS, 4 * D_MODEL, D_MODEL,
            nullptr, nullptr, nullptr, nullptr, nullptr, nullptr);
        transpose_split<<<dim3(4 * D_MODEL / 32, D_MODEL / 32), 256, 0, stream>>>(
            Wm2 + (size_t)l * 4 * D_MODEL * D_MODEL, wth, wtl, 4 * D_MODEL, D_MODEL);
        gemm_bf3<2><<<dim3(D_MODEL / 128, ROWS / 128), 256, 0, stream>>>(
            midh, midl, wth, wtl, partial_w, nullptr, nullptr,
            mscale + (size_t)l * D_MODEL, ROWS, D_MODEL, 4 * D_MODEL,
            nullptr, nullptr, nullptr, nullptr, nullptr, nullptr);
    }
}

// Round 6
// 5470.176 us; speedup vs baseline: 3.6562x; 1.0658x over previous
//
#include <hip/hip_runtime.h>
#include <hip/hip_bf16.h>
#include <math.h>
#include <stdint.h>

#define D_MODEL 768
#define T_SEQ   1024
#define B_BATCH 8
#define NHEAD   12
#define HDIM    64
#define NLAYER  8

typedef unsigned short u16;
typedef __attribute__((ext_vector_type(8))) short bf16x8;
typedef __attribute__((ext_vector_type(4))) float f32x4;
typedef __attribute__((ext_vector_type(4))) uint32_t u32x4;

static constexpr size_t BTD  = (size_t)B_BATCH * T_SEQ * D_MODEL;  // 6291456
static constexpr int    ROWS = B_BATCH * T_SEQ;                    // 8192
static constexpr float  EPSF = 1.1920928955078125e-07f;            // FLT_EPSILON

// ---------------------------------------------------------------- helpers

__device__ __forceinline__ u16 f2bf(float x) {
    __hip_bfloat16 h = __float2bfloat16(x);
    return __builtin_bit_cast(u16, h);
}
__device__ __forceinline__ float bf2f(u16 u) {
    __hip_bfloat16 h = __builtin_bit_cast(__hip_bfloat16, u);
    return __bfloat162float(h);
}
__device__ __forceinline__ void split_bf(float x, u16& hi, u16& lo) {
    hi = f2bf(x);
    lo = f2bf(x - bf2f(hi));
}
__device__ __forceinline__ uint32_t cvt_pk_bf16(float a, float b) {
    uint32_t r;
    asm("v_cvt_pk_bf16_f32 %0, %1, %2" : "=v"(r) : "v"(a), "v"(b));
    return r;
}
__device__ __forceinline__ f32x4 mfma16(bf16x8 a, bf16x8 b, f32x4 c) {
    return __builtin_amdgcn_mfma_f32_16x16x32_bf16(a, b, c, 0, 0, 0);
}

// async global->LDS, 16B/lane; LDS dest wave-uniform base (HW adds lane*16)
__device__ __forceinline__ void gl_lds16(const void* g, void* l) {
    auto gp = reinterpret_cast<const __attribute__((address_space(1))) char*>(
        reinterpret_cast<uintptr_t>(g));
    auto lp = reinterpret_cast<__attribute__((address_space(3))) char*>(
        static_cast<uint32_t>(reinterpret_cast<uintptr_t>(l)));
    __builtin_amdgcn_global_load_lds(gp, lp, 16, 0, 0);
}

__global__ __launch_bounds__(256) void fill_zero4(float4* __restrict__ p, int n4) {
    int i = blockIdx.x * 256 + threadIdx.x;
    if (i < n4) p[i] = make_float4(0.f, 0.f, 0.f, 0.f);
}

__device__ __forceinline__ float block_reduce_sum(float v, float* sbuf) {
    #pragma unroll
    for (int off = 32; off > 0; off >>= 1) v += __shfl_down(v, off);
    __syncthreads();
    if ((threadIdx.x & 63) == 0) sbuf[threadIdx.x >> 6] = v;
    __syncthreads();
    return sbuf[0] + sbuf[1] + sbuf[2] + sbuf[3];
}

// tanh-gelu via exp: 0.5x(1+tanh(z)) = x - x/(exp(2z)+1); exact at +-inf
__device__ __forceinline__ float gelu_fast(float x) {
    float z = 0.7978845608028654f * (x + 0.044715f * x * x * x);
    float e = __expf(2.f * z);
    return x - x / (e + 1.f);
}

// ------------------------------------------------- aggregate + rmsnorm fuse
template<int N>
__global__ __launch_bounds__(256)
void agg_norm_kernel(const float* __restrict__ v0, const float* __restrict__ v1,
                     const float* __restrict__ v2, const float* __restrict__ v3,
                     const float* __restrict__ v4, const float* __restrict__ v5,
                     const float* __restrict__ q,  const float* __restrict__ lns,
                     u16* __restrict__ xh, u16* __restrict__ xl) {
    __shared__ float sbuf[4];
    const float* V[6] = {v0, v1, v2, v3, v4, v5};
    const size_t row = blockIdx.x;
    const int tid = threadIdx.x;

    float qv[3];
    #pragma unroll
    for (int j = 0; j < 3; ++j) qv[j] = q[tid + j * 256];

    float vv[N][3];
    float logits[N];
    #pragma unroll
    for (int i = 0; i < N; ++i) {
        const float* vr = V[i] + row * D_MODEL;
        float ssq = 0.f, qd = 0.f;
        #pragma unroll
        for (int j = 0; j < 3; ++j) {
            float x = vr[tid + j * 256];
            vv[i][j] = x;
            ssq = fmaf(x, x, ssq);
            qd  = fmaf(qv[j], x, qd);
        }
        float S  = block_reduce_sum(ssq, sbuf);
        float Qd = block_reduce_sum(qd,  sbuf);
        logits[i] = Qd * rsqrtf(S * (1.f / 768.f) + EPSF);
    }
    float mx = logits[0];
    #pragma unroll
    for (int i = 1; i < N; ++i) mx = fmaxf(mx, logits[i]);
    float w[N];
    float wsum = 0.f;
    #pragma unroll
    for (int i = 0; i < N; ++i) { w[i] = __expf(logits[i] - mx); wsum += w[i]; }
    float inv = 1.f / wsum;

    float outv[3] = {0.f, 0.f, 0.f};
    #pragma unroll
    for (int i = 0; i < N; ++i) {
        float wi = w[i] * inv;
        #pragma unroll
        for (int j = 0; j < 3; ++j) outv[j] = fmaf(wi, vv[i][j], outv[j]);
    }
    float ssq = 0.f;
    #pragma unroll
    for (int j = 0; j < 3; ++j) ssq = fmaf(outv[j], outv[j], ssq);
    float S2 = block_reduce_sum(ssq, sbuf);
    float scale = lns[0] * rsqrtf(S2 * (1.f / 768.f) + EPSF);
    #pragma unroll
    for (int j = 0; j < 3; ++j) {
        float x = outv[j] * scale;
        u16 hi, lo;
        split_bf(x, hi, lo);
        size_t idx = row * D_MODEL + tid + j * 256;
        xh[idx] = hi;
        xl[idx] = lo;
    }
}

// ---------------------------------------------- weight transpose + bf split
__global__ __launch_bounds__(256)
void transpose_split(const float* __restrict__ W, u16* __restrict__ Th,
                     u16* __restrict__ Tl, int K, int N) {
    __shared__ float t[32][33];
    const int bk = blockIdx.x * 32, bn = blockIdx.y * 32;
    const int r = threadIdx.x >> 3, c4 = (threadIdx.x & 7) * 4;
    float4 v = *(const float4*)&W[(size_t)(bk + r) * N + bn + c4];
    t[r][c4 + 0] = v.x; t[r][c4 + 1] = v.y; t[r][c4 + 2] = v.z; t[r][c4 + 3] = v.w;
    __syncthreads();
    u16 h[4], lo[4];
    #pragma unroll
    for (int j = 0; j < 4; ++j) split_bf(t[c4 + j][r], h[j], lo[j]);
    size_t o = (size_t)(bn + r) * K + bk + c4;
    *(uint2*)&Th[o] = make_uint2((uint32_t)h[0]  | ((uint32_t)h[1]  << 16),
                                 (uint32_t)h[2]  | ((uint32_t)h[3]  << 16));
    *(uint2*)&Tl[o] = make_uint2((uint32_t)lo[0] | ((uint32_t)lo[1] << 16),
                                 (uint32_t)lo[2] | ((uint32_t)lo[3] << 16));
}

// ---------------------------------------------- V transpose (head-major)
// in  vh/vl [bh][1024][64] -> out vth/vtl [bh][64][1024]
__global__ __launch_bounds__(256)
void vt_transpose(const u16* __restrict__ vh, const u16* __restrict__ vl,
                  u16* __restrict__ vth, u16* __restrict__ vtl) {
    __shared__ u16 th[32][36];
    __shared__ u16 tl[32][36];
    const int bh = blockIdx.z;
    const int t0 = blockIdx.x * 32, d0 = blockIdx.y * 32;
    const int r = threadIdx.x >> 3, c = (threadIdx.x & 7) * 4;
    const size_t ib = ((size_t)(bh << 10) + t0 + r) * 64 + d0 + c;
    *(uint2*)&th[r][c] = *(const uint2*)&vh[ib];
    *(uint2*)&tl[r][c] = *(const uint2*)&vl[ib];
    __syncthreads();
    const size_t ob = ((size_t)(bh << 6) + d0 + r) * 1024 + t0 + c;
    u16 a0 = th[c + 0][r], a1 = th[c + 1][r], a2 = th[c + 2][r], a3 = th[c + 3][r];
    *(uint2*)&vth[ob] = make_uint2((uint32_t)a0 | ((uint32_t)a1 << 16),
                                   (uint32_t)a2 | ((uint32_t)a3 << 16));
    u16 b0 = tl[c + 0][r], b1 = tl[c + 1][r], b2 = tl[c + 2][r], b3 = tl[c + 3][r];
    *(uint2*)&vtl[ob] = make_uint2((uint32_t)b0 | ((uint32_t)b1 << 16),
                                   (uint32_t)b2 | ((uint32_t)b3 << 16));
}

// ------------------------------------------------- split-bf16 MFMA GEMM
// C[M,N] = (Ah+Al)[M,K] @ (Bh+Bl)^T  (B given as [N][K]); 3-term product.
// Tile: 128 x BN (BN = 128 or 64), BK=32. LDS XOR-swizzled (source-side +
// read-side per rule #21): stage granule gsrc = slot ^ ((row>>1)&3);
// read granule = lg ^ ((row>>1)&3). XCD-contiguous block remap.
// EPI: 1 = gelu -> bf16 hi/lo, 2 = Cf += scale[n]*acc,
//      3 = scatter qkv (q*0.125) into head-major split buffers
template<int EPI, int BN>
__global__ __launch_bounds__(256)
void gemm_bf3(const u16* __restrict__ Ah, const u16* __restrict__ Al,
              const u16* __restrict__ Bh, const u16* __restrict__ Bl,
              float* __restrict__ Cf, u16* __restrict__ Ch, u16* __restrict__ Cl,
              const float* __restrict__ scale, int M, int N, int K,
              u16* __restrict__ Qh, u16* __restrict__ Ql,
              u16* __restrict__ Kh, u16* __restrict__ Kl,
              u16* __restrict__ Vh, u16* __restrict__ Vl) {
    constexpr int NJ = BN / 32;              // 16-col MFMA tiles per wave
    __shared__ u16 smem[8192 + BN * 64];     // A hi|lo then B hi|lo
    constexpr int AL_OFF = 4096;             // u16 offsets
    constexpr int BH_OFF = 8192;
    constexpr int BL_OFF = 8192 + BN * 32;

    // XCD-contiguous remap (n = gridDim.x*64, always % 8 == 0)
    const int nwg = gridDim.x * gridDim.y;
    const int lin = blockIdx.y * gridDim.x + blockIdx.x;
    const int wg  = (lin & 7) * (nwg >> 3) + (lin >> 3);
    const int bm  = (wg / gridDim.x) << 7;
    const int bn  = (wg % gridDim.x) * BN;

    const int tid = threadIdx.x;
    const int w = tid >> 6, l = tid & 63;
    const int wr = w >> 1, wc = w & 1;

    // staging: row = tid>>2, source granule pre-swizzled
    const int grow = tid >> 2;
    const int gcol = (((tid & 3) ^ ((tid >> 3) & 3)) << 3);
    const size_t aoff0 = (size_t)(bm + grow) * K + gcol;
    const size_t boff0 = (size_t)(bn + grow) * K + gcol;
    const size_t s64 = (size_t)64 * K;
    char* sb = (char*)smem;
    const uint32_t wq = (uint32_t)w << 10;

    f32x4 acc[4][NJ] = {};

    const int key8 = (((l & 15) >> 1) & 3) << 3;   // read-side XOR key (u16 units)
    const int koff = (l >> 4) << 3;
    const int kswz = koff ^ key8;

    for (int k0 = 0; k0 < K; k0 += 32) {
        __syncthreads();
        gl_lds16(Ah + aoff0 + k0,       sb + 0     + wq);
        gl_lds16(Ah + aoff0 + s64 + k0, sb + 4096  + wq);
        gl_lds16(Al + aoff0 + k0,       sb + 8192  + wq);
        gl_lds16(Al + aoff0 + s64 + k0, sb + 12288 + wq);
        gl_lds16(Bh + boff0 + k0,       sb + 16384 + wq);
        if constexpr (BN == 128)
            gl_lds16(Bh + boff0 + s64 + k0, sb + 20480 + wq);
        gl_lds16(Bl + boff0 + k0,       sb + 2 * BL_OFF + wq);
        if constexpr (BN == 128)
            gl_lds16(Bl + boff0 + s64 + k0, sb + 2 * BL_OFF + 4096 + wq);
        __syncthreads();

        const int arow = wr * 64 + (l & 15);
        const int brow = wc * (BN / 2) + (l & 15);
        bf16x8 ah[4], al4[4], bh4[NJ], bl4[NJ];
        #pragma unroll
        for (int i = 0; i < 4; ++i) {
            ah[i]  = *(const bf16x8*)&smem[(arow + i * 16) * 32 + kswz];
            al4[i] = *(const bf16x8*)&smem[AL_OFF + (arow + i * 16) * 32 + kswz];
        }
        #pragma unroll
        for (int j = 0; j < NJ; ++j) {
            bh4[j] = *(const bf16x8*)&smem[BH_OFF + (brow + j * 16) * 32 + kswz];
            bl4[j] = *(const bf16x8*)&smem[BL_OFF + (brow + j * 16) * 32 + kswz];
        }
        #pragma unroll
        for (int i = 0; i < 4; ++i) {
            #pragma unroll
            for (int j = 0; j < NJ; ++j) {
                acc[i][j] = mfma16(ah[i],  bh4[j], acc[i][j]);
                acc[i][j] = mfma16(ah[i],  bl4[j], acc[i][j]);
                acc[i][j] = mfma16(al4[i], bh4[j], acc[i][j]);
            }
        }
    }

    // C/D frag: col = lane&15, row = (lane>>4)*4 + reg
    const int crow0 = bm + wr * 64 + ((l >> 4) << 2);
    const int ccol0 = bn + wc * (BN / 2) + (l & 15);
    #pragma unroll
    for (int i = 0; i < 4; ++i) {
        #pragma unroll
        for (int j = 0; j < NJ; ++j) {
            const int col = ccol0 + j * 16;
            #pragma unroll
            for (int r = 0; r < 4; ++r) {
                const int row = crow0 + i * 16 + r;
                const size_t o = (size_t)row * N + col;
                float v = acc[i][j][r];
                if (EPI == 1) {
                    float g = gelu_fast(v);
                    u16 hi, lo;
                    split_bf(g, hi, lo);
                    Ch[o] = hi; Cl[o] = lo;
                } else if (EPI == 2) {
                    Cf[o] += scale[col] * v;
                } else if (EPI == 3) {
                    const int which = (col >= 1536) ? 2 : ((col >= 768) ? 1 : 0);
                    const int hcol = col - which * 768;
                    const size_t dst = ((size_t)((row >> 10) * NHEAD + (hcol >> 6)) * 1024
                                        + (row & 1023)) * 64 + (hcol & 63);
                    if (which == 0) v *= 0.125f;
                    u16 hi, lo;
                    split_bf(v, hi, lo);
                    if (which == 0)      { Qh[dst] = hi; Ql[dst] = lo; }
                    else if (which == 1) { Kh[dst] = hi; Kl[dst] = lo; }
                    else                 { Vh[dst] = hi; Vl[dst] = lo; }
                }
            }
        }
    }
}

// --------------------------------------------------- MFMA flash attention
// 16x16x32 fragment conventions. Paired q-tiles {p, 15-p} share one K/V
// fragment stream; P redistribution via register shuffles (no LDS).
// Grid: 768 blocks 1D; decode keeps all pairs of one head on one XCD.
__global__ __launch_bounds__(256)
void flash16(const u16* __restrict__ qh, const u16* __restrict__ ql,
             const u16* __restrict__ kh, const u16* __restrict__ kl,
             const u16* __restrict__ vth, const u16* __restrict__ vtl,
             u16* __restrict__ ch, u16* __restrict__ cl) {
    const int id = blockIdx.x;
    const int r8 = id & 7, s = id >> 3;
    const int bh = r8 + 8 * (s >> 3);
    const int p  = s & 7;
    const int hh = bh % NHEAD, bb = bh / NHEAD;
    const int tid = threadIdx.x, w = tid >> 6, l = tid & 63;
    const int lq = l & 15, lg = l >> 4;
    const size_t hb = (size_t)bh << 16;

    const int wqA = p * 64 + w * 16;
    const int wqB = (15 - p) * 64 + w * 16;
    const int qA = wqA + lq, qB = wqB + lq;

    bf16x8 qA00, qA01, qA10, qA11, qB00, qB01, qB10, qB11;
    {
        const size_t qa = hb + ((size_t)qA << 6) + lg * 8;
        qA00 = *(const bf16x8*)(qh + qa);       qA01 = *(const bf16x8*)(ql + qa);
        qA10 = *(const bf16x8*)(qh + qa + 32);  qA11 = *(const bf16x8*)(ql + qa + 32);
        const size_t qb = hb + ((size_t)qB << 6) + lg * 8;
        qB00 = *(const bf16x8*)(qh + qb);       qB01 = *(const bf16x8*)(ql + qb);
        qB10 = *(const bf16x8*)(qh + qb + 32);  qB11 = *(const bf16x8*)(ql + qb + 32);
    }

    f32x4 oA[4] = {}, oB[4] = {};
    float mA = -30000.f, lsA = 0.f, mB = -30000.f, lsB = 0.f;
    const int ntiles = 32 - 2 * p;
    const int src0 = 32 * (lg & 1) + lq, src1 = src0 + 16;
    const bool hiHalf = lg >= 2;

    for (int kt = 0; kt < ntiles; ++kt) {
        const int k0 = kt * 32;
        const size_t kb0 = hb + (size_t)(k0 + lq) * 64 + lg * 8;
        const size_t kb1 = kb0 + 16 * 64;
        bf16x8 ka0 = *(const bf16x8*)(kh + kb0);
        bf16x8 ka1 = *(const bf16x8*)(kh + kb0 + 32);
        bf16x8 kc0 = *(const bf16x8*)(kl + kb0);
        bf16x8 kc1 = *(const bf16x8*)(kl + kb0 + 32);
        bf16x8 kd0 = *(const bf16x8*)(kh + kb1);
        bf16x8 kd1 = *(const bf16x8*)(kh + kb1 + 32);
        bf16x8 ke0 = *(const bf16x8*)(kl + kb1);
        bf16x8 ke1 = *(const bf16x8*)(kl + kb1 + 32);
        bf16x8 vfh[4], vfl[4];
        #pragma unroll
        for (int dt = 0; dt < 4; ++dt) {
            const size_t vb = hb + (size_t)(dt * 16 + lq) * 1024 + k0 + lg * 8;
            vfh[dt] = *(const bf16x8*)(vth + vb);
            vfl[dt] = *(const bf16x8*)(vtl + vb);
        }
        const bool actA = (k0 <= wqA + 31);

        f32x4 s0B = {}, s1B = {}, s0A = {}, s1A = {};
        s0B = mfma16(ka0, qB00, s0B); s0B = mfma16(ka0, qB01, s0B);
        s0B = mfma16(kc0, qB00, s0B); s0B = mfma16(ka1, qB10, s0B);
        s0B = mfma16(ka1, qB11, s0B); s0B = mfma16(kc1, qB10, s0B);
        s1B = mfma16(kd0, qB00, s1B); s1B = mfma16(kd0, qB01, s1B);
        s1B = mfma16(ke0, qB00, s1B); s1B = mfma16(kd1, qB10, s1B);
        s1B = mfma16(kd1, qB11, s1B); s1B = mfma16(ke1, qB10, s1B);
        if (actA) {
            s0A = mfma16(ka0, qA00, s0A); s0A = mfma16(ka0, qA01, s0A);
            s0A = mfma16(kc0, qA00, s0A); s0A = mfma16(ka1, qA10, s0A);
            s0A = mfma16(ka1, qA11, s0A); s0A = mfma16(kc1, qA10, s0A);
            s1A = mfma16(kd0, qA00, s1A); s1A = mfma16(kd0, qA01, s1A);
            s1A = mfma16(ke0, qA00, s1A); s1A = mfma16(kd1, qA10, s1A);
            s1A = mfma16(kd1, qA11, s1A); s1A = mfma16(ke1, qA10, s1A);
        }

        // ================= B path =================
        if (k0 + 31 > wqB) {
            #pragma unroll
            for (int r = 0; r < 4; ++r) {
                if (k0 + 4 * lg + r > qB)      s0B[r] = -30000.f;
                if (k0 + 16 + 4 * lg + r > qB) s1B[r] = -30000.f;
            }
        }
        {
            float tm = fmaxf(fmaxf(fmaxf(s0B[0], s0B[1]), fmaxf(s0B[2], s0B[3])),
                             fmaxf(fmaxf(s1B[0], s1B[1]), fmaxf(s1B[2], s1B[3])));
            tm = fmaxf(tm, __shfl_xor(tm, 16));
            tm = fmaxf(tm, __shfl_xor(tm, 32));
            const float mnew = fmaxf(mB, tm);
            const float fac = __expf(mB - mnew);
            mB = mnew;
            lsB *= fac;
            #pragma unroll
            for (int dt = 0; dt < 4; ++dt) {
                oB[dt][0] *= fac; oB[dt][1] *= fac; oB[dt][2] *= fac; oB[dt][3] *= fac;
            }
            float ps = 0.f;
            #pragma unroll
            for (int r = 0; r < 4; ++r) {
                s0B[r] = __expf(s0B[r] - mB); ps += s0B[r];
                s1B[r] = __expf(s1B[r] - mB); ps += s1B[r];
            }
            lsB += ps;
            const uint32_t wA0 = cvt_pk_bf16(s0B[0], s0B[1]);
            const uint32_t wA1 = cvt_pk_bf16(s0B[2], s0B[3]);
            const uint32_t wB0 = cvt_pk_bf16(s1B[0], s1B[1]);
            const uint32_t wB1 = cvt_pk_bf16(s1B[2], s1B[3]);
            const uint32_t a0 = (uint32_t)__shfl((int)wA0, src0);
            const uint32_t b0 = (uint32_t)__shfl((int)wB0, src0);
            const uint32_t a1 = (uint32_t)__shfl((int)wA1, src0);
            const uint32_t b1 = (uint32_t)__shfl((int)wB1, src0);
            const uint32_t a2 = (uint32_t)__shfl((int)wA0, src1);
            const uint32_t b2 = (uint32_t)__shfl((int)wB0, src1);
            const uint32_t a3 = (uint32_t)__shfl((int)wA1, src1);
            const uint32_t b3 = (uint32_t)__shfl((int)wB1, src1);
            u32x4 pw = { hiHalf ? b0 : a0, hiHalf ? b1 : a1,
                         hiHalf ? b2 : a2, hiHalf ? b3 : a3 };
            const bf16x8 pb = __builtin_bit_cast(bf16x8, pw);
            #pragma unroll
            for (int dt = 0; dt < 4; ++dt) {
                oB[dt] = mfma16(vfh[dt], pb, oB[dt]);
                oB[dt] = mfma16(vfl[dt], pb, oB[dt]);
            }
        }

        // ================= A path =================
        if (actA) {
            if (k0 + 31 > wqA) {
                #pragma unroll
                for (int r = 0; r < 4; ++r) {
                    if (k0 + 4 * lg + r > qA)      s0A[r] = -30000.f;
                    if (k0 + 16 + 4 * lg + r > qA) s1A[r] = -30000.f;
                }
            }
            float tm = fmaxf(fmaxf(fmaxf(s0A[0], s0A[1]), fmaxf(s0A[2], s0A[3])),
                             fmaxf(fmaxf(s1A[0], s1A[1]), fmaxf(s1A[2], s1A[3])));
            tm = fmaxf(tm, __shfl_xor(tm, 16));
            tm = fmaxf(tm, __shfl_xor(tm, 32));
            const float mnew = fmaxf(mA, tm);
            const float fac = __expf(mA - mnew);
            mA = mnew;
            lsA *= fac;
            #pragma unroll
            for (int dt = 0; dt < 4; ++dt) {
                oA[dt][0] *= fac; oA[dt][1] *= fac; oA[dt][2] *= fac; oA[dt][3] *= fac;
            }
            float ps = 0.f;
            #pragma unroll
            for (int r = 0; r < 4; ++r) {
                s0A[r] = __expf(s0A[r] - mA); ps += s0A[r];
                s1A[r] = __expf(s1A[r] - mA); ps += s1A[r];
            }
            lsA += ps;
            const uint32_t wA0 = cvt_pk_bf16(s0A[0], s0A[1]);
            const uint32_t wA1 = cvt_pk_bf16(s0A[2], s0A[3]);
            const uint32_t wB0 = cvt_pk_bf16(s1A[0], s1A[1]);
            const uint32_t wB1 = cvt_pk_bf16(s1A[2], s1A[3]);
            const uint32_t a0 = (uint32_t)__shfl((int)wA0, src0);
            const uint32_t b0 = (uint32_t)__shfl((int)wB0, src0);
            const uint32_t a1 = (uint32_t)__shfl((int)wA1, src0);
            const uint32_t b1 = (uint32_t)__shfl((int)wB1, src0);
            const uint32_t a2 = (uint32_t)__shfl((int)wA0, src1);
            const uint32_t b2 = (uint32_t)__shfl((int)wB0, src1);
            const uint32_t a3 = (uint32_t)__shfl((int)wA1, src1);
            const uint32_t b3 = (uint32_t)__shfl((int)wB1, src1);
            u32x4 pw = { hiHalf ? b0 : a0, hiHalf ? b1 : a1,
                         hiHalf ? b2 : a2, hiHalf ? b3 : a3 };
            const bf16x8 pb = __builtin_bit_cast(bf16x8, pw);
            #pragma unroll
            for (int dt = 0; dt < 4; ++dt) {
                oA[dt] = mfma16(vfh[dt], pb, oA[dt]);
                oA[dt] = mfma16(vfl[dt], pb, oA[dt]);
            }
        }
    }

    lsA += __shfl_xor(lsA, 16); lsA += __shfl_xor(lsA, 32);
    lsB += __shfl_xor(lsB, 16); lsB += __shfl_xor(lsB, 32);
    const float invA = 1.f / lsA, invB = 1.f / lsB;
    const size_t cbA = ((size_t)(bb * 1024 + qA)) * 768 + hh * 64;
    const size_t cbB = ((size_t)(bb * 1024 + qB)) * 768 + hh * 64;
    #pragma unroll
    for (int dt = 0; dt < 4; ++dt) {
        u16 h4[4], l4[4];
        #pragma unroll
        for (int r = 0; r < 4; ++r) split_bf(oA[dt][r] * invA, h4[r], l4[r]);
        size_t co = cbA + dt * 16 + 4 * lg;
        *(uint2*)&ch[co] = make_uint2((uint32_t)h4[0] | ((uint32_t)h4[1] << 16),
                                      (uint32_t)h4[2] | ((uint32_t)h4[3] << 16));
        *(uint2*)&cl[co] = make_uint2((uint32_t)l4[0] | ((uint32_t)l4[1] << 16),
                                      (uint32_t)l4[2] | ((uint32_t)l4[3] << 16));
        #pragma unroll
        for (int r = 0; r < 4; ++r) split_bf(oB[dt][r] * invB, h4[r], l4[r]);
        co = cbB + dt * 16 + 4 * lg;
        *(uint2*)&ch[co] = make_uint2((uint32_t)h4[0] | ((uint32_t)h4[1] << 16),
                                      (uint32_t)h4[2] | ((uint32_t)h4[3] << 16));
        *(uint2*)&cl[co] = make_uint2((uint32_t)l4[0] | ((uint32_t)l4[1] << 16),
                                      (uint32_t)l4[2] | ((uint32_t)l4[3] << 16));
    }
}

// ------------------------------------------------------------------- host

extern "C" void kernel_launch(void* const* d_in, const int* in_sizes, int n_in,
                              void* d_out, int out_size, void* d_ws, size_t ws_size,
                              hipStream_t stream) {
    const float* x0     = (const float*)d_in[0];
    const float* aproj  = (const float*)d_in[1];
    const float* mproj  = (const float*)d_in[2];
    const float* Wqkv   = (const float*)d_in[3];
    const float* Wo     = (const float*)d_in[4];
    const float* Wm1    = (const float*)d_in[5];
    const float* Wm2    = (const float*)d_in[6];
    const float* ascale = (const float*)d_in[7];
    const float* mscale = (const float*)d_in[8];
    const float* lns    = (const float*)d_in[9];
    float* out = (float*)d_out;
    char*  base = (char*)d_ws;

    float* p1  = (float*)base;
    float* p2  = p1 + BTD;
    float* p3  = p2 + BTD;
    u16*   xnh = (u16*)(base + 12 * BTD);
    u16*   xnl = xnh + BTD;
    u16*   wth = (u16*)(base + 16 * BTD);
    u16*   wtl = wth + (size_t)3072 * 768;
    char*  QB  = base + 16 * BTD + (size_t)2 * 2 * 3072 * 768;
    u16* qh  = (u16*)QB;
    u16* ql  = qh + BTD;
    u16* kh  = ql + BTD;
    u16* kl  = kh + BTD;
    u16* vh  = kl + BTD;
    u16* vl  = vh + BTD;
    u16* vth = vl + BTD;
    u16* vtl = vth + BTD;
    u16* midh = qh;
    u16* midl = vh;
    u16* ctxh = vh;
    u16* ctxl = vl;

    float* pb[3] = {p1, p2, p3};
    const float* hist[6];
    int nh = 1;
    hist[0] = x0;
    const float* partial_c = x0;
    float* partial_w = nullptr;
    int pidx = 0;

    auto launch_agg = [&](int n, const float* Vl6[6], const float* qvec,
                          const float* lnsl) {
        switch (n) {
        case 2: agg_norm_kernel<2><<<dim3(ROWS), 256, 0, stream>>>(Vl6[0], Vl6[1], Vl6[2], Vl6[3], Vl6[4], Vl6[5], qvec, lnsl, xnh, xnl); break;
        case 3: agg_norm_kernel<3><<<dim3(ROWS), 256, 0, stream>>>(Vl6[0], Vl6[1], Vl6[2], Vl6[3], Vl6[4], Vl6[5], qvec, lnsl, xnh, xnl); break;
        case 4: agg_norm_kernel<4><<<dim3(ROWS), 256, 0, stream>>>(Vl6[0], Vl6[1], Vl6[2], Vl6[3], Vl6[4], Vl6[5], qvec, lnsl, xnh, xnl); break;
        case 5: agg_norm_kernel<5><<<dim3(ROWS), 256, 0, stream>>>(Vl6[0], Vl6[1], Vl6[2], Vl6[3], Vl6[4], Vl6[5], qvec, lnsl, xnh, xnl); break;
        default: agg_norm_kernel<6><<<dim3(ROWS), 256, 0, stream>>>(Vl6[0], Vl6[1], Vl6[2], Vl6[3], Vl6[4], Vl6[5], qvec, lnsl, xnh, xnl); break;
        }
    };

    for (int l = 0; l < NLAYER; ++l) {
        // ---- attention-path aggregate (reads OLD partial) -> xn hi/lo
        const float* Vl6[6] = {nullptr, nullptr, nullptr, nullptr, nullptr, nullptr};
        for (int i = 0; i < nh; ++i) Vl6[i] = hist[i];
        Vl6[nh] = partial_c;
        launch_agg(nh + 1, Vl6, aproj + (size_t)l * D_MODEL, lns + l);

        // ---- block boundary
        if ((l & 1) == 0) {
            hist[nh++] = partial_c;
            float* np = (pidx < 3) ? pb[pidx] : out;
            ++pidx;
            fill_zero4<<<dim3((int)(BTD / 4 / 256)), 256, 0, stream>>>((float4*)np, (int)(BTD / 4));
            partial_w = np;
            partial_c = np;
        }

        // ---- QKV GEMM -> head-major split q/k/v
        transpose_split<<<dim3(D_MODEL / 32, 3 * D_MODEL / 32), 256, 0, stream>>>(
            Wqkv + (size_t)l * D_MODEL * 3 * D_MODEL, wth, wtl, D_MODEL, 3 * D_MODEL);
        gemm_bf3<3, 128><<<dim3(3 * D_MODEL / 128, ROWS / 128), 256, 0, stream>>>(
            xnh, xnl, wth, wtl, nullptr, nullptr, nullptr, nullptr,
            ROWS, 3 * D_MODEL, D_MODEL, qh, ql, kh, kl, vh, vl);

        // ---- V transpose -> vt
        vt_transpose<<<dim3(T_SEQ / 32, HDIM / 32, B_BATCH * NHEAD), 256, 0, stream>>>(
            vh, vl, vth, vtl);

        // ---- flash attention -> ctx (aliases vh/vl; flash reads vth/vtl only)
        flash16<<<dim3(768), 256, 0, stream>>>(
            qh, ql, kh, kl, vth, vtl, ctxh, ctxl);

        // ---- Wo GEMM: partial += attn_scale * (ctx @ Wo)  [BN=64: 768 blocks]
        transpose_split<<<dim3(D_MODEL / 32, D_MODEL / 32), 256, 0, stream>>>(
            Wo + (size_t)l * D_MODEL * D_MODEL, wth, wtl, D_MODEL, D_MODEL);
        gemm_bf3<2, 64><<<dim3(D_MODEL / 64, ROWS / 128), 256, 0, stream>>>(
            ctxh, ctxl, wth, wtl, partial_w, nullptr, nullptr,
            ascale + (size_t)l * D_MODEL, ROWS, D_MODEL, D_MODEL,
            nullptr, nullptr, nullptr, nullptr, nullptr, nullptr);

        // ---- mlp-path aggregate (reads NEW partial) -> xn hi/lo
        const float* V26[6] = {nullptr, nullptr, nullptr, nullptr, nullptr, nullptr};
        for (int i = 0; i < nh; ++i) V26[i] = hist[i];
        V26[nh] = partial_c;
        launch_agg(nh + 1, V26, mproj + (size_t)l * D_MODEL, lns + l);

        // ---- MLP
        transpose_split<<<dim3(D_MODEL / 32, 4 * D_MODEL / 32), 256, 0, stream>>>(
            Wm1 + (size_t)l * D_MODEL * 4 * D_MODEL, wth, wtl, D_MODEL, 4 * D_MODEL);
        gemm_bf3<1, 128><<<dim3(4 * D_MODEL / 128, ROWS / 128), 256, 0, stream>>>(
            xnh, xnl, wth, wtl, nullptr, midh, midl, nullptr,
            ROWS, 4 * D_MODEL, D_MODEL,
            nullptr, nullptr, nullptr, nullptr, nullptr, nullptr);
        transpose_split<<<dim3(4 * D_MODEL / 32, D_MODEL / 32), 256, 0, stream>>>(
            Wm2 + (size_t)l * 4 * D_MODEL * D_MODEL, wth, wtl, 4 * D_MODEL, D_MODEL);
        gemm_bf3<2, 64><<<dim3(D_MODEL / 64, ROWS / 128), 256, 0, stream>>>(
            midh, midl, wth, wtl, partial_w, nullptr, nullptr,
            mscale + (size_t)l * D_MODEL, ROWS, D_MODEL, 4 * D_MODEL,
            nullptr, nullptr, nullptr, nullptr, nullptr, nullptr);
    }
}

// Round 7
// 5169.463 us; speedup vs baseline: 3.8689x; 1.0582x over previous
//
#include <hip/hip_runtime.h>
#include <hip/hip_bf16.h>
#include <math.h>
#include <stdint.h>

#define D_MODEL 768
#define T_SEQ   1024
#define B_BATCH 8
#define NHEAD   12
#define HDIM    64
#define NLAYER  8

typedef unsigned short u16;
typedef __attribute__((ext_vector_type(8))) short bf16x8;
typedef __attribute__((ext_vector_type(4))) float f32x4;
typedef __attribute__((ext_vector_type(4))) uint32_t u32x4;

static constexpr size_t BTD  = (size_t)B_BATCH * T_SEQ * D_MODEL;  // 6291456
static constexpr int    ROWS = B_BATCH * T_SEQ;                    // 8192
static constexpr float  EPSF = 1.1920928955078125e-07f;            // FLT_EPSILON

// ---------------------------------------------------------------- helpers

__device__ __forceinline__ u16 f2bf(float x) {
    __hip_bfloat16 h = __float2bfloat16(x);
    return __builtin_bit_cast(u16, h);
}
__device__ __forceinline__ float bf2f(u16 u) {
    __hip_bfloat16 h = __builtin_bit_cast(__hip_bfloat16, u);
    return __bfloat162float(h);
}
__device__ __forceinline__ void split_bf(float x, u16& hi, u16& lo) {
    hi = f2bf(x);
    lo = f2bf(x - bf2f(hi));
}
__device__ __forceinline__ uint32_t cvt_pk_bf16(float a, float b) {
    uint32_t r;
    asm("v_cvt_pk_bf16_f32 %0, %1, %2" : "=v"(r) : "v"(a), "v"(b));
    return r;
}
__device__ __forceinline__ f32x4 mfma16(bf16x8 a, bf16x8 b, f32x4 c) {
    return __builtin_amdgcn_mfma_f32_16x16x32_bf16(a, b, c, 0, 0, 0);
}

// async global->LDS, 16B/lane; LDS dest wave-uniform base (HW adds lane*16)
__device__ __forceinline__ void gl_lds16(const void* g, void* l) {
    auto gp = reinterpret_cast<const __attribute__((address_space(1))) char*>(
        reinterpret_cast<uintptr_t>(g));
    auto lp = reinterpret_cast<__attribute__((address_space(3))) char*>(
        static_cast<uint32_t>(reinterpret_cast<uintptr_t>(l)));
    __builtin_amdgcn_global_load_lds(gp, lp, 16, 0, 0);
}

__global__ __launch_bounds__(256) void fill_zero4(float4* __restrict__ p, int n4) {
    int i = blockIdx.x * 256 + threadIdx.x;
    if (i < n4) p[i] = make_float4(0.f, 0.f, 0.f, 0.f);
}

__device__ __forceinline__ float block_reduce_sum(float v, float* sbuf) {
    #pragma unroll
    for (int off = 32; off > 0; off >>= 1) v += __shfl_down(v, off);
    __syncthreads();
    if ((threadIdx.x & 63) == 0) sbuf[threadIdx.x >> 6] = v;
    __syncthreads();
    return sbuf[0] + sbuf[1] + sbuf[2] + sbuf[3];
}

// tanh-gelu via exp: 0.5x(1+tanh(z)) = x - x/(exp(2z)+1); exact at +-inf
__device__ __forceinline__ float gelu_fast(float x) {
    float z = 0.7978845608028654f * (x + 0.044715f * x * x * x);
    float e = __expf(2.f * z);
    return x - x / (e + 1.f);
}

// ------------------------------------------------- aggregate + rmsnorm fuse
template<int N>
__global__ __launch_bounds__(256)
void agg_norm_kernel(const float* __restrict__ v0, const float* __restrict__ v1,
                     const float* __restrict__ v2, const float* __restrict__ v3,
                     const float* __restrict__ v4, const float* __restrict__ v5,
                     const float* __restrict__ q,  const float* __restrict__ lns,
                     u16* __restrict__ xh, u16* __restrict__ xl) {
    __shared__ float sbuf[4];
    const float* V[6] = {v0, v1, v2, v3, v4, v5};
    const size_t row = blockIdx.x;
    const int tid = threadIdx.x;

    float qv[3];
    #pragma unroll
    for (int j = 0; j < 3; ++j) qv[j] = q[tid + j * 256];

    float vv[N][3];
    float logits[N];
    #pragma unroll
    for (int i = 0; i < N; ++i) {
        const float* vr = V[i] + row * D_MODEL;
        float ssq = 0.f, qd = 0.f;
        #pragma unroll
        for (int j = 0; j < 3; ++j) {
            float x = vr[tid + j * 256];
            vv[i][j] = x;
            ssq = fmaf(x, x, ssq);
            qd  = fmaf(qv[j], x, qd);
        }
        float S  = block_reduce_sum(ssq, sbuf);
        float Qd = block_reduce_sum(qd,  sbuf);
        logits[i] = Qd * rsqrtf(S * (1.f / 768.f) + EPSF);
    }
    float mx = logits[0];
    #pragma unroll
    for (int i = 1; i < N; ++i) mx = fmaxf(mx, logits[i]);
    float w[N];
    float wsum = 0.f;
    #pragma unroll
    for (int i = 0; i < N; ++i) { w[i] = __expf(logits[i] - mx); wsum += w[i]; }
    float inv = 1.f / wsum;

    float outv[3] = {0.f, 0.f, 0.f};
    #pragma unroll
    for (int i = 0; i < N; ++i) {
        float wi = w[i] * inv;
        #pragma unroll
        for (int j = 0; j < 3; ++j) outv[j] = fmaf(wi, vv[i][j], outv[j]);
    }
    float ssq = 0.f;
    #pragma unroll
    for (int j = 0; j < 3; ++j) ssq = fmaf(outv[j], outv[j], ssq);
    float S2 = block_reduce_sum(ssq, sbuf);
    float scale = lns[0] * rsqrtf(S2 * (1.f / 768.f) + EPSF);
    #pragma unroll
    for (int j = 0; j < 3; ++j) {
        float x = outv[j] * scale;
        u16 hi, lo;
        split_bf(x, hi, lo);
        size_t idx = row * D_MODEL + tid + j * 256;
        xh[idx] = hi;
        xl[idx] = lo;
    }
}

// ---------------------------------------------- weight transpose + bf split
__global__ __launch_bounds__(256)
void transpose_split(const float* __restrict__ W, u16* __restrict__ Th,
                     u16* __restrict__ Tl, int K, int N) {
    __shared__ float t[32][33];
    const int bk = blockIdx.x * 32, bn = blockIdx.y * 32;
    const int r = threadIdx.x >> 3, c4 = (threadIdx.x & 7) * 4;
    float4 v = *(const float4*)&W[(size_t)(bk + r) * N + bn + c4];
    t[r][c4 + 0] = v.x; t[r][c4 + 1] = v.y; t[r][c4 + 2] = v.z; t[r][c4 + 3] = v.w;
    __syncthreads();
    u16 h[4], lo[4];
    #pragma unroll
    for (int j = 0; j < 4; ++j) split_bf(t[c4 + j][r], h[j], lo[j]);
    size_t o = (size_t)(bn + r) * K + bk + c4;
    *(uint2*)&Th[o] = make_uint2((uint32_t)h[0]  | ((uint32_t)h[1]  << 16),
                                 (uint32_t)h[2]  | ((uint32_t)h[3]  << 16));
    *(uint2*)&Tl[o] = make_uint2((uint32_t)lo[0] | ((uint32_t)lo[1] << 16),
                                 (uint32_t)lo[2] | ((uint32_t)lo[3] << 16));
}

// ---------------------------------------------- V transpose (head-major, hi only)
// in  vh [bh][1024][64] -> out vth [bh][64][1024]
__global__ __launch_bounds__(256)
void vt_transpose(const u16* __restrict__ vh, u16* __restrict__ vth) {
    __shared__ u16 th[32][36];
    const int bh = blockIdx.z;
    const int t0 = blockIdx.x * 32, d0 = blockIdx.y * 32;
    const int r = threadIdx.x >> 3, c = (threadIdx.x & 7) * 4;
    const size_t ib = ((size_t)(bh << 10) + t0 + r) * 64 + d0 + c;
    *(uint2*)&th[r][c] = *(const uint2*)&vh[ib];
    __syncthreads();
    const size_t ob = ((size_t)(bh << 6) + d0 + r) * 1024 + t0 + c;
    u16 a0 = th[c + 0][r], a1 = th[c + 1][r], a2 = th[c + 2][r], a3 = th[c + 3][r];
    *(uint2*)&vth[ob] = make_uint2((uint32_t)a0 | ((uint32_t)a1 << 16),
                                   (uint32_t)a2 | ((uint32_t)a3 << 16));
}

// ------------------------------------------------- split-bf16 MFMA GEMM
// C[M,N] = (Ah+Al)[M,K] @ (Bh+Bl)^T  (B given as [N][K]); 3-term product.
// Tile: 128 x BN (BN = 128 or 64), BK=32. LDS XOR-swizzled both sides.
// EPI: 1 = gelu -> bf16 hi/lo, 2 = Cf += scale[n]*acc,
//      3 = scatter qkv (q*0.125) into head-major split buffers (V hi only)
template<int EPI, int BN>
__global__ __launch_bounds__(256)
void gemm_bf3(const u16* __restrict__ Ah, const u16* __restrict__ Al,
              const u16* __restrict__ Bh, const u16* __restrict__ Bl,
              float* __restrict__ Cf, u16* __restrict__ Ch, u16* __restrict__ Cl,
              const float* __restrict__ scale, int M, int N, int K,
              u16* __restrict__ Qh, u16* __restrict__ Ql,
              u16* __restrict__ Kh, u16* __restrict__ Kl,
              u16* __restrict__ Vh) {
    constexpr int NJ = BN / 32;
    __shared__ u16 smem[8192 + BN * 64];
    constexpr int AL_OFF = 4096;
    constexpr int BH_OFF = 8192;
    constexpr int BL_OFF = 8192 + BN * 32;

    const int nwg = gridDim.x * gridDim.y;
    const int lin = blockIdx.y * gridDim.x + blockIdx.x;
    const int wg  = (lin & 7) * (nwg >> 3) + (lin >> 3);
    const int bm  = (wg / gridDim.x) << 7;
    const int bn  = (wg % gridDim.x) * BN;

    const int tid = threadIdx.x;
    const int w = tid >> 6, l = tid & 63;
    const int wr = w >> 1, wc = w & 1;

    const int grow = tid >> 2;
    const int gcol = (((tid & 3) ^ ((tid >> 3) & 3)) << 3);
    const size_t aoff0 = (size_t)(bm + grow) * K + gcol;
    const size_t boff0 = (size_t)(bn + grow) * K + gcol;
    const size_t s64 = (size_t)64 * K;
    char* sb = (char*)smem;
    const uint32_t wq = (uint32_t)w << 10;

    f32x4 acc[4][NJ] = {};

    const int key8 = (((l & 15) >> 1) & 3) << 3;
    const int koff = (l >> 4) << 3;
    const int kswz = koff ^ key8;

    for (int k0 = 0; k0 < K; k0 += 32) {
        __syncthreads();
        gl_lds16(Ah + aoff0 + k0,       sb + 0     + wq);
        gl_lds16(Ah + aoff0 + s64 + k0, sb + 4096  + wq);
        gl_lds16(Al + aoff0 + k0,       sb + 8192  + wq);
        gl_lds16(Al + aoff0 + s64 + k0, sb + 12288 + wq);
        gl_lds16(Bh + boff0 + k0,       sb + 16384 + wq);
        if constexpr (BN == 128)
            gl_lds16(Bh + boff0 + s64 + k0, sb + 20480 + wq);
        gl_lds16(Bl + boff0 + k0,       sb + 2 * BL_OFF + wq);
        if constexpr (BN == 128)
            gl_lds16(Bl + boff0 + s64 + k0, sb + 2 * BL_OFF + 4096 + wq);
        __syncthreads();

        const int arow = wr * 64 + (l & 15);
        const int brow = wc * (BN / 2) + (l & 15);
        bf16x8 ah[4], al4[4], bh4[NJ], bl4[NJ];
        #pragma unroll
        for (int i = 0; i < 4; ++i) {
            ah[i]  = *(const bf16x8*)&smem[(arow + i * 16) * 32 + kswz];
            al4[i] = *(const bf16x8*)&smem[AL_OFF + (arow + i * 16) * 32 + kswz];
        }
        #pragma unroll
        for (int j = 0; j < NJ; ++j) {
            bh4[j] = *(const bf16x8*)&smem[BH_OFF + (brow + j * 16) * 32 + kswz];
            bl4[j] = *(const bf16x8*)&smem[BL_OFF + (brow + j * 16) * 32 + kswz];
        }
        #pragma unroll
        for (int i = 0; i < 4; ++i) {
            #pragma unroll
            for (int j = 0; j < NJ; ++j) {
                acc[i][j] = mfma16(ah[i],  bh4[j], acc[i][j]);
                acc[i][j] = mfma16(ah[i],  bl4[j], acc[i][j]);
                acc[i][j] = mfma16(al4[i], bh4[j], acc[i][j]);
            }
        }
    }

    const int crow0 = bm + wr * 64 + ((l >> 4) << 2);
    const int ccol0 = bn + wc * (BN / 2) + (l & 15);
    #pragma unroll
    for (int i = 0; i < 4; ++i) {
        #pragma unroll
        for (int j = 0; j < NJ; ++j) {
            const int col = ccol0 + j * 16;
            #pragma unroll
            for (int r = 0; r < 4; ++r) {
                const int row = crow0 + i * 16 + r;
                const size_t o = (size_t)row * N + col;
                float v = acc[i][j][r];
                if (EPI == 1) {
                    float g = gelu_fast(v);
                    u16 hi, lo;
                    split_bf(g, hi, lo);
                    Ch[o] = hi; Cl[o] = lo;
                } else if (EPI == 2) {
                    Cf[o] += scale[col] * v;
                } else if (EPI == 3) {
                    const int which = (col >= 1536) ? 2 : ((col >= 768) ? 1 : 0);
                    const int hcol = col - which * 768;
                    const size_t dst = ((size_t)((row >> 10) * NHEAD + (hcol >> 6)) * 1024
                                        + (row & 1023)) * 64 + (hcol & 63);
                    if (which == 0) v *= 0.125f;
                    u16 hi, lo;
                    split_bf(v, hi, lo);
                    if (which == 0)      { Qh[dst] = hi; Ql[dst] = lo; }
                    else if (which == 1) { Kh[dst] = hi; Kl[dst] = lo; }
                    else                 { Vh[dst] = hi; }
                }
            }
        }
    }
}

// --------------------------------------------------- MFMA flash attention
// Paired q-tiles {p, 15-p} share one K/V fragment stream. K register
// double-buffer (prefetch tile kt+1 under compute), defer-max (THR=8),
// PV with V hi only. P redistribution via register shuffles (no LDS).
__global__ __launch_bounds__(256, 3)
void flash16(const u16* __restrict__ qh, const u16* __restrict__ ql,
             const u16* __restrict__ kh, const u16* __restrict__ kl,
             const u16* __restrict__ vth,
             u16* __restrict__ ch, u16* __restrict__ cl) {
    const int id = blockIdx.x;
    const int r8 = id & 7, s = id >> 3;
    const int bh = r8 + 8 * (s >> 3);
    const int p  = s & 7;
    const int hh = bh % NHEAD, bb = bh / NHEAD;
    const int tid = threadIdx.x, w = tid >> 6, l = tid & 63;
    const int lq = l & 15, lg = l >> 4;
    const size_t hb = (size_t)bh << 16;

    const int wqA = p * 64 + w * 16;
    const int wqB = (15 - p) * 64 + w * 16;
    const int qA = wqA + lq, qB = wqB + lq;

    bf16x8 qA0, qA1, qA2, qA3, qB0, qB1, qB2, qB3;
    {
        const size_t qa = hb + ((size_t)qA << 6) + lg * 8;
        qA0 = *(const bf16x8*)(qh + qa);       qA1 = *(const bf16x8*)(ql + qa);
        qA2 = *(const bf16x8*)(qh + qa + 32);  qA3 = *(const bf16x8*)(ql + qa + 32);
        const size_t qb = hb + ((size_t)qB << 6) + lg * 8;
        qB0 = *(const bf16x8*)(qh + qb);       qB1 = *(const bf16x8*)(ql + qb);
        qB2 = *(const bf16x8*)(qh + qb + 32);  qB3 = *(const bf16x8*)(ql + qb + 32);
    }

    f32x4 oA[4] = {}, oB[4] = {};
    float mA = -30000.f, lsA = 0.f, mB = -30000.f, lsB = 0.f;
    const int ntiles = 32 - 2 * p;              // always even
    const int src0 = 32 * (lg & 1) + lq, src1 = src0 + 16;
    const bool hiHalf = lg >= 2;

    bf16x8 KA[8], KB[8];
    auto loadK = [&](bf16x8 (&K)[8], int k0) {
        const size_t kb0 = hb + (size_t)(k0 + lq) * 64 + lg * 8;
        const size_t kb1 = kb0 + 16 * 64;
        K[0] = *(const bf16x8*)(kh + kb0);
        K[1] = *(const bf16x8*)(kh + kb0 + 32);
        K[2] = *(const bf16x8*)(kl + kb0);
        K[3] = *(const bf16x8*)(kl + kb0 + 32);
        K[4] = *(const bf16x8*)(kh + kb1);
        K[5] = *(const bf16x8*)(kh + kb1 + 32);
        K[6] = *(const bf16x8*)(kl + kb1);
        K[7] = *(const bf16x8*)(kl + kb1 + 32);
    };

    auto path = [&](bf16x8 (&Kc)[8], bf16x8 (&vf)[4], int k0, int wqX, int qX,
                    bf16x8 q0, bf16x8 q1, bf16x8 q2, bf16x8 q3,
                    float& mX, float& lsX, f32x4 (&oX)[4]) {
        f32x4 s0 = {}, s1 = {};
        s0 = mfma16(Kc[0], q0, s0); s0 = mfma16(Kc[0], q1, s0);
        s0 = mfma16(Kc[2], q0, s0); s0 = mfma16(Kc[1], q2, s0);
        s0 = mfma16(Kc[1], q3, s0); s0 = mfma16(Kc[3], q2, s0);
        s1 = mfma16(Kc[4], q0, s1); s1 = mfma16(Kc[4], q1, s1);
        s1 = mfma16(Kc[6], q0, s1); s1 = mfma16(Kc[5], q2, s1);
        s1 = mfma16(Kc[5], q3, s1); s1 = mfma16(Kc[7], q2, s1);
        if (k0 + 31 > wqX) {
            #pragma unroll
            for (int r = 0; r < 4; ++r) {
                if (k0 + 4 * lg + r > qX)      s0[r] = -30000.f;
                if (k0 + 16 + 4 * lg + r > qX) s1[r] = -30000.f;
            }
        }
        float tmloc = fmaxf(fmaxf(fmaxf(s0[0], s0[1]), fmaxf(s0[2], s0[3])),
                            fmaxf(fmaxf(s1[0], s1[1]), fmaxf(s1[2], s1[3])));
        if (__any(tmloc > mX + 8.f)) {
            float tm = fmaxf(tmloc, __shfl_xor(tmloc, 16));
            tm = fmaxf(tm, __shfl_xor(tm, 32));
            const float mnew = fmaxf(mX, tm);
            const float fac = __expf(mX - mnew);
            mX = mnew;
            lsX *= fac;
            #pragma unroll
            for (int dt = 0; dt < 4; ++dt) {
                oX[dt][0] *= fac; oX[dt][1] *= fac;
                oX[dt][2] *= fac; oX[dt][3] *= fac;
            }
        }
        float ps = 0.f;
        #pragma unroll
        for (int r = 0; r < 4; ++r) {
            s0[r] = __expf(s0[r] - mX); ps += s0[r];
            s1[r] = __expf(s1[r] - mX); ps += s1[r];
        }
        lsX += ps;
        const uint32_t wA0 = cvt_pk_bf16(s0[0], s0[1]);
        const uint32_t wA1 = cvt_pk_bf16(s0[2], s0[3]);
        const uint32_t wB0 = cvt_pk_bf16(s1[0], s1[1]);
        const uint32_t wB1 = cvt_pk_bf16(s1[2], s1[3]);
        const uint32_t a0 = (uint32_t)__shfl((int)wA0, src0);
        const uint32_t b0 = (uint32_t)__shfl((int)wB0, src0);
        const uint32_t a1 = (uint32_t)__shfl((int)wA1, src0);
        const uint32_t b1 = (uint32_t)__shfl((int)wB1, src0);
        const uint32_t a2 = (uint32_t)__shfl((int)wA0, src1);
        const uint32_t b2 = (uint32_t)__shfl((int)wB0, src1);
        const uint32_t a3 = (uint32_t)__shfl((int)wA1, src1);
        const uint32_t b3 = (uint32_t)__shfl((int)wB1, src1);
        u32x4 pw = { hiHalf ? b0 : a0, hiHalf ? b1 : a1,
                     hiHalf ? b2 : a2, hiHalf ? b3 : a3 };
        const bf16x8 pb = __builtin_bit_cast(bf16x8, pw);
        #pragma unroll
        for (int dt = 0; dt < 4; ++dt)
            oX[dt] = mfma16(vf[dt], pb, oX[dt]);
    };

    auto step = [&](bf16x8 (&Kc)[8], bf16x8 (&Kn)[8], int kt) {
        const int k0 = kt * 32;
        bf16x8 vf[4];
        #pragma unroll
        for (int dt = 0; dt < 4; ++dt) {
            const size_t vb = hb + (size_t)(dt * 16 + lq) * 1024 + k0 + lg * 8;
            vf[dt] = *(const bf16x8*)(vth + vb);
        }
        const int ktn = (kt + 1 < ntiles) ? kt + 1 : kt;   // clamp (last unused)
        loadK(Kn, ktn * 32);
        if (k0 <= wqB + 15)
            path(Kc, vf, k0, wqB, qB, qB0, qB1, qB2, qB3, mB, lsB, oB);
        if (k0 <= wqA + 15)
            path(Kc, vf, k0, wqA, qA, qA0, qA1, qA2, qA3, mA, lsA, oA);
    };

    loadK(KA, 0);
    for (int kt = 0; kt < ntiles; kt += 2) {
        step(KA, KB, kt);
        step(KB, KA, kt + 1);
    }

    lsA += __shfl_xor(lsA, 16); lsA += __shfl_xor(lsA, 32);
    lsB += __shfl_xor(lsB, 16); lsB += __shfl_xor(lsB, 32);
    const float invA = 1.f / lsA, invB = 1.f / lsB;
    const size_t cbA = ((size_t)(bb * 1024 + qA)) * 768 + hh * 64;
    const size_t cbB = ((size_t)(bb * 1024 + qB)) * 768 + hh * 64;
    #pragma unroll
    for (int dt = 0; dt < 4; ++dt) {
        u16 h4[4], l4[4];
        #pragma unroll
        for (int r = 0; r < 4; ++r) split_bf(oA[dt][r] * invA, h4[r], l4[r]);
        size_t co = cbA + dt * 16 + 4 * lg;
        *(uint2*)&ch[co] = make_uint2((uint32_t)h4[0] | ((uint32_t)h4[1] << 16),
                                      (uint32_t)h4[2] | ((uint32_t)h4[3] << 16));
        *(uint2*)&cl[co] = make_uint2((uint32_t)l4[0] | ((uint32_t)l4[1] << 16),
                                      (uint32_t)l4[2] | ((uint32_t)l4[3] << 16));
        #pragma unroll
        for (int r = 0; r < 4; ++r) split_bf(oB[dt][r] * invB, h4[r], l4[r]);
        co = cbB + dt * 16 + 4 * lg;
        *(uint2*)&ch[co] = make_uint2((uint32_t)h4[0] | ((uint32_t)h4[1] << 16),
                                      (uint32_t)h4[2] | ((uint32_t)h4[3] << 16));
        *(uint2*)&cl[co] = make_uint2((uint32_t)l4[0] | ((uint32_t)l4[1] << 16),
                                      (uint32_t)l4[2] | ((uint32_t)l4[3] << 16));
    }
}

// ------------------------------------------------------------------- host

extern "C" void kernel_launch(void* const* d_in, const int* in_sizes, int n_in,
                              void* d_out, int out_size, void* d_ws, size_t ws_size,
                              hipStream_t stream) {
    const float* x0     = (const float*)d_in[0];
    const float* aproj  = (const float*)d_in[1];
    const float* mproj  = (const float*)d_in[2];
    const float* Wqkv   = (const float*)d_in[3];
    const float* Wo     = (const float*)d_in[4];
    const float* Wm1    = (const float*)d_in[5];
    const float* Wm2    = (const float*)d_in[6];
    const float* ascale = (const float*)d_in[7];
    const float* mscale = (const float*)d_in[8];
    const float* lns    = (const float*)d_in[9];
    float* out = (float*)d_out;
    char*  base = (char*)d_ws;

    float* p1  = (float*)base;
    float* p2  = p1 + BTD;
    float* p3  = p2 + BTD;
    u16*   xnh = (u16*)(base + 12 * BTD);
    u16*   xnl = xnh + BTD;
    u16*   wth = (u16*)(base + 16 * BTD);
    u16*   wtl = wth + (size_t)3072 * 768;
    char*  QB  = base + 16 * BTD + (size_t)2 * 2 * 3072 * 768;
    u16* qh  = (u16*)QB;
    u16* ql  = qh + BTD;
    u16* kh  = ql + BTD;
    u16* kl  = kh + BTD;
    u16* vh  = kl + BTD;
    u16* vl  = vh + BTD;
    u16* vth = vl + BTD;
    u16* midh = qh;
    u16* midl = vh;
    u16* ctxh = vh;
    u16* ctxl = vl;

    float* pb[3] = {p1, p2, p3};
    const float* hist[6];
    int nh = 1;
    hist[0] = x0;
    const float* partial_c = x0;
    float* partial_w = nullptr;
    int pidx = 0;

    auto launch_agg = [&](int n, const float* Vl6[6], const float* qvec,
                          const float* lnsl) {
        switch (n) {
        case 2: agg_norm_kernel<2><<<dim3(ROWS), 256, 0, stream>>>(Vl6[0], Vl6[1], Vl6[2], Vl6[3], Vl6[4], Vl6[5], qvec, lnsl, xnh, xnl); break;
        case 3: agg_norm_kernel<3><<<dim3(ROWS), 256, 0, stream>>>(Vl6[0], Vl6[1], Vl6[2], Vl6[3], Vl6[4], Vl6[5], qvec, lnsl, xnh, xnl); break;
        case 4: agg_norm_kernel<4><<<dim3(ROWS), 256, 0, stream>>>(Vl6[0], Vl6[1], Vl6[2], Vl6[3], Vl6[4], Vl6[5], qvec, lnsl, xnh, xnl); break;
        case 5: agg_norm_kernel<5><<<dim3(ROWS), 256, 0, stream>>>(Vl6[0], Vl6[1], Vl6[2], Vl6[3], Vl6[4], Vl6[5], qvec, lnsl, xnh, xnl); break;
        default: agg_norm_kernel<6><<<dim3(ROWS), 256, 0, stream>>>(Vl6[0], Vl6[1], Vl6[2], Vl6[3], Vl6[4], Vl6[5], qvec, lnsl, xnh, xnl); break;
        }
    };

    for (int l = 0; l < NLAYER; ++l) {
        // ---- attention-path aggregate (reads OLD partial) -> xn hi/lo
        const float* Vl6[6] = {nullptr, nullptr, nullptr, nullptr, nullptr, nullptr};
        for (int i = 0; i < nh; ++i) Vl6[i] = hist[i];
        Vl6[nh] = partial_c;
        launch_agg(nh + 1, Vl6, aproj + (size_t)l * D_MODEL, lns + l);

        // ---- block boundary
        if ((l & 1) == 0) {
            hist[nh++] = partial_c;
            float* np = (pidx < 3) ? pb[pidx] : out;
            ++pidx;
            fill_zero4<<<dim3((int)(BTD / 4 / 256)), 256, 0, stream>>>((float4*)np, (int)(BTD / 4));
            partial_w = np;
            partial_c = np;
        }

        // ---- QKV GEMM -> head-major split q/k/v (V hi only)
        transpose_split<<<dim3(D_MODEL / 32, 3 * D_MODEL / 32), 256, 0, stream>>>(
            Wqkv + (size_t)l * D_MODEL * 3 * D_MODEL, wth, wtl, D_MODEL, 3 * D_MODEL);
        gemm_bf3<3, 128><<<dim3(3 * D_MODEL / 128, ROWS / 128), 256, 0, stream>>>(
            xnh, xnl, wth, wtl, nullptr, nullptr, nullptr, nullptr,
            ROWS, 3 * D_MODEL, D_MODEL, qh, ql, kh, kl, vh);

        // ---- V transpose (hi only) -> vth
        vt_transpose<<<dim3(T_SEQ / 32, HDIM / 32, B_BATCH * NHEAD), 256, 0, stream>>>(
            vh, vth);

        // ---- flash attention -> ctx (aliases vh/vl; flash reads vth only)
        flash16<<<dim3(768), 256, 0, stream>>>(
            qh, ql, kh, kl, vth, ctxh, ctxl);

        // ---- Wo GEMM: partial += attn_scale * (ctx @ Wo)  [BN=64: 768 blocks]
        transpose_split<<<dim3(D_MODEL / 32, D_MODEL / 32), 256, 0, stream>>>(
            Wo + (size_t)l * D_MODEL * D_MODEL, wth, wtl, D_MODEL, D_MODEL);
        gemm_bf3<2, 64><<<dim3(D_MODEL / 64, ROWS / 128), 256, 0, stream>>>(
            ctxh, ctxl, wth, wtl, partial_w, nullptr, nullptr,
            ascale + (size_t)l * D_MODEL, ROWS, D_MODEL, D_MODEL,
            nullptr, nullptr, nullptr, nullptr, nullptr);

        // ---- mlp-path aggregate (reads NEW partial) -> xn hi/lo
        const float* V26[6] = {nullptr, nullptr, nullptr, nullptr, nullptr, nullptr};
        for (int i = 0; i < nh; ++i) V26[i] = hist[i];
        V26[nh] = partial_c;
        launch_agg(nh + 1, V26, mproj + (size_t)l * D_MODEL, lns + l);

        // ---- MLP
        transpose_split<<<dim3(D_MODEL / 32, 4 * D_MODEL / 32), 256, 0, stream>>>(
            Wm1 + (size_t)l * D_MODEL * 4 * D_MODEL, wth, wtl, D_MODEL, 4 * D_MODEL);
        gemm_bf3<1, 128><<<dim3(4 * D_MODEL / 128, ROWS / 128), 256, 0, stream>>>(
            xnh, xnl, wth, wtl, nullptr, midh, midl, nullptr,
            ROWS, 4 * D_MODEL, D_MODEL,
            nullptr, nullptr, nullptr, nullptr, nullptr);
        transpose_split<<<dim3(4 * D_MODEL / 32, D_MODEL / 32), 256, 0, stream>>>(
            Wm2 + (size_t)l * 4 * D_MODEL * D_MODEL, wth, wtl, 4 * D_MODEL, D_MODEL);
        gemm_bf3<2, 64><<<dim3(D_MODEL / 64, ROWS / 128), 256, 0, stream>>>(
            midh, midl, wth, wtl, partial_w, nullptr, nullptr,
            mscale + (size_t)l * D_MODEL, ROWS, D_MODEL, 4 * D_MODEL,
            nullptr, nullptr, nullptr, nullptr, nullptr);
    }
}

// Round 8
// 4232.021 us; speedup vs baseline: 4.7259x; 1.2215x over previous
//
#include <hip/hip_runtime.h>
#include <hip/hip_bf16.h>
#include <math.h>
#include <stdint.h>

#define D_MODEL 768
#define T_SEQ   1024
#define B_BATCH 8
#define NHEAD   12
#define HDIM    64
#define NLAYER  8

typedef unsigned short u16;
typedef __attribute__((ext_vector_type(8))) short bf16x8;
typedef __attribute__((ext_vector_type(4))) float f32x4;
typedef __attribute__((ext_vector_type(4))) uint32_t u32x4;

static constexpr size_t BTD  = (size_t)B_BATCH * T_SEQ * D_MODEL;  // 6291456
static constexpr int    ROWS = B_BATCH * T_SEQ;                    // 8192
static constexpr float  EPSF = 1.1920928955078125e-07f;            // FLT_EPSILON

// ---------------------------------------------------------------- helpers

__device__ __forceinline__ u16 f2bf(float x) {
    __hip_bfloat16 h = __float2bfloat16(x);
    return __builtin_bit_cast(u16, h);
}
__device__ __forceinline__ float bf2f(u16 u) {
    __hip_bfloat16 h = __builtin_bit_cast(__hip_bfloat16, u);
    return __bfloat162float(h);
}
__device__ __forceinline__ void split_bf(float x, u16& hi, u16& lo) {
    hi = f2bf(x);
    lo = f2bf(x - bf2f(hi));
}
__device__ __forceinline__ uint32_t cvt_pk_bf16(float a, float b) {
    uint32_t r;
    asm("v_cvt_pk_bf16_f32 %0, %1, %2" : "=v"(r) : "v"(a), "v"(b));
    return r;
}
__device__ __forceinline__ f32x4 mfma16(bf16x8 a, bf16x8 b, f32x4 c) {
    return __builtin_amdgcn_mfma_f32_16x16x32_bf16(a, b, c, 0, 0, 0);
}

// async global->LDS, 16B/lane; LDS dest wave-uniform base (HW adds lane*16)
__device__ __forceinline__ void gl_lds16(const void* g, void* l) {
    auto gp = reinterpret_cast<const __attribute__((address_space(1))) char*>(
        reinterpret_cast<uintptr_t>(g));
    auto lp = reinterpret_cast<__attribute__((address_space(3))) char*>(
        static_cast<uint32_t>(reinterpret_cast<uintptr_t>(l)));
    __builtin_amdgcn_global_load_lds(gp, lp, 16, 0, 0);
}

__global__ __launch_bounds__(256) void fill_zero4(float4* __restrict__ p, int n4) {
    int i = blockIdx.x * 256 + threadIdx.x;
    if (i < n4) p[i] = make_float4(0.f, 0.f, 0.f, 0.f);
}

__device__ __forceinline__ float block_reduce_sum(float v, float* sbuf) {
    #pragma unroll
    for (int off = 32; off > 0; off >>= 1) v += __shfl_down(v, off);
    __syncthreads();
    if ((threadIdx.x & 63) == 0) sbuf[threadIdx.x >> 6] = v;
    __syncthreads();
    return sbuf[0] + sbuf[1] + sbuf[2] + sbuf[3];
}

// tanh-gelu via exp: 0.5x(1+tanh(z)) = x - x/(exp(2z)+1); exact at +-inf
__device__ __forceinline__ float gelu_fast(float x) {
    float z = 0.7978845608028654f * (x + 0.044715f * x * x * x);
    float e = __expf(2.f * z);
    return x - x / (e + 1.f);
}

// ------------------------------------------------- aggregate + rmsnorm fuse
template<int N>
__global__ __launch_bounds__(256)
void agg_norm_kernel(const float* __restrict__ v0, const float* __restrict__ v1,
                     const float* __restrict__ v2, const float* __restrict__ v3,
                     const float* __restrict__ v4, const float* __restrict__ v5,
                     const float* __restrict__ q,  const float* __restrict__ lns,
                     u16* __restrict__ xh, u16* __restrict__ xl) {
    __shared__ float sbuf[4];
    const float* V[6] = {v0, v1, v2, v3, v4, v5};
    const size_t row = blockIdx.x;
    const int tid = threadIdx.x;

    float qv[3];
    #pragma unroll
    for (int j = 0; j < 3; ++j) qv[j] = q[tid + j * 256];

    float vv[N][3];
    float logits[N];
    #pragma unroll
    for (int i = 0; i < N; ++i) {
        const float* vr = V[i] + row * D_MODEL;
        float ssq = 0.f, qd = 0.f;
        #pragma unroll
        for (int j = 0; j < 3; ++j) {
            float x = vr[tid + j * 256];
            vv[i][j] = x;
            ssq = fmaf(x, x, ssq);
            qd  = fmaf(qv[j], x, qd);
        }
        float S  = block_reduce_sum(ssq, sbuf);
        float Qd = block_reduce_sum(qd,  sbuf);
        logits[i] = Qd * rsqrtf(S * (1.f / 768.f) + EPSF);
    }
    float mx = logits[0];
    #pragma unroll
    for (int i = 1; i < N; ++i) mx = fmaxf(mx, logits[i]);
    float w[N];
    float wsum = 0.f;
    #pragma unroll
    for (int i = 0; i < N; ++i) { w[i] = __expf(logits[i] - mx); wsum += w[i]; }
    float inv = 1.f / wsum;

    float outv[3] = {0.f, 0.f, 0.f};
    #pragma unroll
    for (int i = 0; i < N; ++i) {
        float wi = w[i] * inv;
        #pragma unroll
        for (int j = 0; j < 3; ++j) outv[j] = fmaf(wi, vv[i][j], outv[j]);
    }
    float ssq = 0.f;
    #pragma unroll
    for (int j = 0; j < 3; ++j) ssq = fmaf(outv[j], outv[j], ssq);
    float S2 = block_reduce_sum(ssq, sbuf);
    float scale = lns[0] * rsqrtf(S2 * (1.f / 768.f) + EPSF);
    #pragma unroll
    for (int j = 0; j < 3; ++j) {
        float x = outv[j] * scale;
        u16 hi, lo;
        split_bf(x, hi, lo);
        size_t idx = row * D_MODEL + tid + j * 256;
        xh[idx] = hi;
        xl[idx] = lo;
    }
}

// ---------------------------------------------- weight transpose (hi only)
// W[K][N] fp32 -> Th[N][K] bf16
__global__ __launch_bounds__(256)
void transpose_split(const float* __restrict__ W, u16* __restrict__ Th,
                     int K, int N) {
    __shared__ float t[32][33];
    const int bk = blockIdx.x * 32, bn = blockIdx.y * 32;
    const int r = threadIdx.x >> 3, c4 = (threadIdx.x & 7) * 4;
    float4 v = *(const float4*)&W[(size_t)(bk + r) * N + bn + c4];
    t[r][c4 + 0] = v.x; t[r][c4 + 1] = v.y; t[r][c4 + 2] = v.z; t[r][c4 + 3] = v.w;
    __syncthreads();
    u16 h[4];
    #pragma unroll
    for (int j = 0; j < 4; ++j) h[j] = f2bf(t[c4 + j][r]);
    size_t o = (size_t)(bn + r) * K + bk + c4;
    *(uint2*)&Th[o] = make_uint2((uint32_t)h[0] | ((uint32_t)h[1] << 16),
                                 (uint32_t)h[2] | ((uint32_t)h[3] << 16));
}

// ---------------------------------------------- V transpose (head-major, hi only)
__global__ __launch_bounds__(256)
void vt_transpose(const u16* __restrict__ vh, u16* __restrict__ vth) {
    __shared__ u16 th[32][36];
    const int bh = blockIdx.z;
    const int t0 = blockIdx.x * 32, d0 = blockIdx.y * 32;
    const int r = threadIdx.x >> 3, c = (threadIdx.x & 7) * 4;
    const size_t ib = ((size_t)(bh << 10) + t0 + r) * 64 + d0 + c;
    *(uint2*)&th[r][c] = *(const uint2*)&vh[ib];
    __syncthreads();
    const size_t ob = ((size_t)(bh << 6) + d0 + r) * 1024 + t0 + c;
    u16 a0 = th[c + 0][r], a1 = th[c + 1][r], a2 = th[c + 2][r], a3 = th[c + 3][r];
    *(uint2*)&vth[ob] = make_uint2((uint32_t)a0 | ((uint32_t)a1 << 16),
                                   (uint32_t)a2 | ((uint32_t)a3 << 16));
}

// ------------------------------------------------- split-A x bf16-W MFMA GEMM
// C[M,N] = (Ah+Al)[M,K] @ Bh^T  (B given as [N][K]); 2-term product.
// Prefetch-pipelined: LDS double-buffer, counted vmcnt + raw barriers.
// EPI: 1 = gelu -> bf16 hi/lo, 2 = Cf += scale[n]*acc,
//      3 = scatter qkv (q*0.125) into head-major split buffers (V hi only)
template<int EPI, int BN>
__global__ __launch_bounds__(256)
void gemm_bf2(const u16* __restrict__ Ah, const u16* __restrict__ Al,
              const u16* __restrict__ Bh,
              float* __restrict__ Cf, u16* __restrict__ Ch, u16* __restrict__ Cl,
              const float* __restrict__ scale, int M, int N, int K,
              u16* __restrict__ Qh, u16* __restrict__ Ql,
              u16* __restrict__ Kh, u16* __restrict__ Kl,
              u16* __restrict__ Vh) {
    constexpr int NJ = BN / 32;
    constexpr int BUFB = 16384 + BN * 64;       // bytes per buffer
    __shared__ u16 smem[2 * (8192 + BN * 32)];

    // XCD-contiguous remap (nwg always % 8 == 0)
    const int nwg = gridDim.x * gridDim.y;
    const int lin = blockIdx.y * gridDim.x + blockIdx.x;
    const int wg  = (lin & 7) * (nwg >> 3) + (lin >> 3);
    const int bm  = (wg / gridDim.x) << 7;
    const int bn  = (wg % gridDim.x) * BN;

    const int tid = threadIdx.x;
    const int w = tid >> 6, l = tid & 63;
    const int wr = w >> 1, wc = w & 1;

    // staging: row = tid>>2, source granule pre-swizzled (both-sides swizzle)
    const int grow = tid >> 2;
    const int gcol = (((tid & 3) ^ ((tid >> 3) & 3)) << 3);
    const size_t aoff0 = (size_t)(bm + grow) * K + gcol;
    const size_t boff0 = (size_t)(bn + grow) * K + gcol;
    const size_t s64 = (size_t)64 * K;
    char* sb0 = (char*)smem;
    char* sb1 = (char*)smem + BUFB;
    const uint32_t wq = (uint32_t)w << 10;

    auto stage = [&](char* sbuf, int k0) {
        gl_lds16(Ah + aoff0 + k0,       sbuf + 0     + wq);
        gl_lds16(Ah + aoff0 + s64 + k0, sbuf + 4096  + wq);
        gl_lds16(Al + aoff0 + k0,       sbuf + 8192  + wq);
        gl_lds16(Al + aoff0 + s64 + k0, sbuf + 12288 + wq);
        gl_lds16(Bh + boff0 + k0,       sbuf + 16384 + wq);
        if constexpr (BN == 128)
            gl_lds16(Bh + boff0 + s64 + k0, sbuf + 20480 + wq);
    };

    f32x4 acc[4][NJ] = {};

    const int key8 = (((l & 15) >> 1) & 3) << 3;   // read-side XOR key (u16)
    const int kswz = ((l >> 4) << 3) ^ key8;
    const int arow = wr * 64 + (l & 15);
    const int brow = wc * (BN / 2) + (l & 15);
    const int nk = K >> 5;

    stage(sb0, 0);
    for (int kt = 0; kt < nk; ++kt) {
        char* cur = (kt & 1) ? sb1 : sb0;
        char* nxt = (kt & 1) ? sb0 : sb1;
        if (kt + 1 < nk) {
            stage(nxt, (kt + 1) << 5);
            if constexpr (BN == 128)
                asm volatile("s_waitcnt vmcnt(6)\n\ts_barrier" ::: "memory");
            else
                asm volatile("s_waitcnt vmcnt(5)\n\ts_barrier" ::: "memory");
        } else {
            asm volatile("s_waitcnt vmcnt(0)\n\ts_barrier" ::: "memory");
        }
        __builtin_amdgcn_sched_barrier(0);

        const u16* bu = (const u16*)cur;
        bf16x8 ah[4], al4[4], bh4[NJ];
        #pragma unroll
        for (int i = 0; i < 4; ++i) {
            ah[i]  = *(const bf16x8*)&bu[(arow + i * 16) * 32 + kswz];
            al4[i] = *(const bf16x8*)&bu[4096 + (arow + i * 16) * 32 + kswz];
        }
        #pragma unroll
        for (int j = 0; j < NJ; ++j)
            bh4[j] = *(const bf16x8*)&bu[8192 + (brow + j * 16) * 32 + kswz];
        asm volatile("s_waitcnt lgkmcnt(0)" ::: "memory");
        __builtin_amdgcn_sched_barrier(0);
        asm volatile("s_barrier" ::: "memory");   // all waves done reading cur

        #pragma unroll
        for (int i = 0; i < 4; ++i) {
            #pragma unroll
            for (int j = 0; j < NJ; ++j) {
                acc[i][j] = mfma16(ah[i],  bh4[j], acc[i][j]);
                acc[i][j] = mfma16(al4[i], bh4[j], acc[i][j]);
            }
        }
    }

    // C/D frag: col = lane&15, row = (lane>>4)*4 + reg
    const int crow0 = bm + wr * 64 + ((l >> 4) << 2);
    const int ccol0 = bn + wc * (BN / 2) + (l & 15);
    #pragma unroll
    for (int i = 0; i < 4; ++i) {
        #pragma unroll
        for (int j = 0; j < NJ; ++j) {
            const int col = ccol0 + j * 16;
            #pragma unroll
            for (int r = 0; r < 4; ++r) {
                const int row = crow0 + i * 16 + r;
                const size_t o = (size_t)row * N + col;
                float v = acc[i][j][r];
                if (EPI == 1) {
                    float g = gelu_fast(v);
                    u16 hi, lo;
                    split_bf(g, hi, lo);
                    Ch[o] = hi; Cl[o] = lo;
                } else if (EPI == 2) {
                    Cf[o] += scale[col] * v;
                } else if (EPI == 3) {
                    const int which = (col >= 1536) ? 2 : ((col >= 768) ? 1 : 0);
                    const int hcol = col - which * 768;
                    const size_t dst = ((size_t)((row >> 10) * NHEAD + (hcol >> 6)) * 1024
                                        + (row & 1023)) * 64 + (hcol & 63);
                    if (which == 0) v *= 0.125f;
                    u16 hi, lo;
                    split_bf(v, hi, lo);
                    if (which == 0)      { Qh[dst] = hi; Ql[dst] = lo; }
                    else if (which == 1) { Kh[dst] = hi; Kl[dst] = lo; }
                    else                 { Vh[dst] = hi; }
                }
            }
        }
    }
}

// --------------------------------------------------- MFMA flash attention
// Paired q-tiles {p, 15-p} share one K/V fragment stream. K register
// double-buffer, defer-max (THR=8), PV with V hi only. P redistribution
// via register shuffles (no LDS, no barriers).
__global__ __launch_bounds__(256, 3)
void flash16(const u16* __restrict__ qh, const u16* __restrict__ ql,
             const u16* __restrict__ kh, const u16* __restrict__ kl,
             const u16* __restrict__ vth,
             u16* __restrict__ ch, u16* __restrict__ cl) {
    const int id = blockIdx.x;
    const int r8 = id & 7, s = id >> 3;
    const int bh = r8 + 8 * (s >> 3);
    const int p  = s & 7;
    const int hh = bh % NHEAD, bb = bh / NHEAD;
    const int tid = threadIdx.x, w = tid >> 6, l = tid & 63;
    const int lq = l & 15, lg = l >> 4;
    const size_t hb = (size_t)bh << 16;

    const int wqA = p * 64 + w * 16;
    const int wqB = (15 - p) * 64 + w * 16;
    const int qA = wqA + lq, qB = wqB + lq;

    bf16x8 qA0, qA1, qA2, qA3, qB0, qB1, qB2, qB3;
    {
        const size_t qa = hb + ((size_t)qA << 6) + lg * 8;
        qA0 = *(const bf16x8*)(qh + qa);       qA1 = *(const bf16x8*)(ql + qa);
        qA2 = *(const bf16x8*)(qh + qa + 32);  qA3 = *(const bf16x8*)(ql + qa + 32);
        const size_t qb = hb + ((size_t)qB << 6) + lg * 8;
        qB0 = *(const bf16x8*)(qh + qb);       qB1 = *(const bf16x8*)(ql + qb);
        qB2 = *(const bf16x8*)(qh + qb + 32);  qB3 = *(const bf16x8*)(ql + qb + 32);
    }

    f32x4 oA[4] = {}, oB[4] = {};
    float mA = -30000.f, lsA = 0.f, mB = -30000.f, lsB = 0.f;
    const int ntiles = 32 - 2 * p;              // always even
    const int src0 = 32 * (lg & 1) + lq, src1 = src0 + 16;
    const bool hiHalf = lg >= 2;

    bf16x8 KA[8], KB[8];
    auto loadK = [&](bf16x8 (&K)[8], int k0) {
        const size_t kb0 = hb + (size_t)(k0 + lq) * 64 + lg * 8;
        const size_t kb1 = kb0 + 16 * 64;
        K[0] = *(const bf16x8*)(kh + kb0);
        K[1] = *(const bf16x8*)(kh + kb0 + 32);
        K[2] = *(const bf16x8*)(kl + kb0);
        K[3] = *(const bf16x8*)(kl + kb0 + 32);
        K[4] = *(const bf16x8*)(kh + kb1);
        K[5] = *(const bf16x8*)(kh + kb1 + 32);
        K[6] = *(const bf16x8*)(kl + kb1);
        K[7] = *(const bf16x8*)(kl + kb1 + 32);
    };

    auto path = [&](bf16x8 (&Kc)[8], bf16x8 (&vf)[4], int k0, int wqX, int qX,
                    bf16x8 q0, bf16x8 q1, bf16x8 q2, bf16x8 q3,
                    float& mX, float& lsX, f32x4 (&oX)[4]) {
        f32x4 s0 = {}, s1 = {};
        s0 = mfma16(Kc[0], q0, s0); s0 = mfma16(Kc[0], q1, s0);
        s0 = mfma16(Kc[2], q0, s0); s0 = mfma16(Kc[1], q2, s0);
        s0 = mfma16(Kc[1], q3, s0); s0 = mfma16(Kc[3], q2, s0);
        s1 = mfma16(Kc[4], q0, s1); s1 = mfma16(Kc[4], q1, s1);
        s1 = mfma16(Kc[6], q0, s1); s1 = mfma16(Kc[5], q2, s1);
        s1 = mfma16(Kc[5], q3, s1); s1 = mfma16(Kc[7], q2, s1);
        if (k0 + 31 > wqX) {
            #pragma unroll
            for (int r = 0; r < 4; ++r) {
                if (k0 + 4 * lg + r > qX)      s0[r] = -30000.f;
                if (k0 + 16 + 4 * lg + r > qX) s1[r] = -30000.f;
            }
        }
        float tmloc = fmaxf(fmaxf(fmaxf(s0[0], s0[1]), fmaxf(s0[2], s0[3])),
                            fmaxf(fmaxf(s1[0], s1[1]), fmaxf(s1[2], s1[3])));
        if (__any(tmloc > mX + 8.f)) {
            float tm = fmaxf(tmloc, __shfl_xor(tmloc, 16));
            tm = fmaxf(tm, __shfl_xor(tm, 32));
            const float mnew = fmaxf(mX, tm);
            const float fac = __expf(mX - mnew);
            mX = mnew;
            lsX *= fac;
            #pragma unroll
            for (int dt = 0; dt < 4; ++dt) {
                oX[dt][0] *= fac; oX[dt][1] *= fac;
                oX[dt][2] *= fac; oX[dt][3] *= fac;
            }
        }
        float ps = 0.f;
        #pragma unroll
        for (int r = 0; r < 4; ++r) {
            s0[r] = __expf(s0[r] - mX); ps += s0[r];
            s1[r] = __expf(s1[r] - mX); ps += s1[r];
        }
        lsX += ps;
        const uint32_t wA0 = cvt_pk_bf16(s0[0], s0[1]);
        const uint32_t wA1 = cvt_pk_bf16(s0[2], s0[3]);
        const uint32_t wB0 = cvt_pk_bf16(s1[0], s1[1]);
        const uint32_t wB1 = cvt_pk_bf16(s1[2], s1[3]);
        const uint32_t a0 = (uint32_t)__shfl((int)wA0, src0);
        const uint32_t b0 = (uint32_t)__shfl((int)wB0, src0);
        const uint32_t a1 = (uint32_t)__shfl((int)wA1, src0);
        const uint32_t b1 = (uint32_t)__shfl((int)wB1, src0);
        const uint32_t a2 = (uint32_t)__shfl((int)wA0, src1);
        const uint32_t b2 = (uint32_t)__shfl((int)wB0, src1);
        const uint32_t a3 = (uint32_t)__shfl((int)wA1, src1);
        const uint32_t b3 = (uint32_t)__shfl((int)wB1, src1);
        u32x4 pw = { hiHalf ? b0 : a0, hiHalf ? b1 : a1,
                     hiHalf ? b2 : a2, hiHalf ? b3 : a3 };
        const bf16x8 pb = __builtin_bit_cast(bf16x8, pw);
        #pragma unroll
        for (int dt = 0; dt < 4; ++dt)
            oX[dt] = mfma16(vf[dt], pb, oX[dt]);
    };

    auto step = [&](bf16x8 (&Kc)[8], bf16x8 (&Kn)[8], int kt) {
        const int k0 = kt * 32;
        bf16x8 vf[4];
        #pragma unroll
        for (int dt = 0; dt < 4; ++dt) {
            const size_t vb = hb + (size_t)(dt * 16 + lq) * 1024 + k0 + lg * 8;
            vf[dt] = *(const bf16x8*)(vth + vb);
        }
        const int ktn = (kt + 1 < ntiles) ? kt + 1 : kt;
        loadK(Kn, ktn * 32);
        if (k0 <= wqB + 15)
            path(Kc, vf, k0, wqB, qB, qB0, qB1, qB2, qB3, mB, lsB, oB);
        if (k0 <= wqA + 15)
            path(Kc, vf, k0, wqA, qA, qA0, qA1, qA2, qA3, mA, lsA, oA);
    };

    loadK(KA, 0);
    for (int kt = 0; kt < ntiles; kt += 2) {
        step(KA, KB, kt);
        step(KB, KA, kt + 1);
    }

    lsA += __shfl_xor(lsA, 16); lsA += __shfl_xor(lsA, 32);
    lsB += __shfl_xor(lsB, 16); lsB += __shfl_xor(lsB, 32);
    const float invA = 1.f / lsA, invB = 1.f / lsB;
    const size_t cbA = ((size_t)(bb * 1024 + qA)) * 768 + hh * 64;
    const size_t cbB = ((size_t)(bb * 1024 + qB)) * 768 + hh * 64;
    #pragma unroll
    for (int dt = 0; dt < 4; ++dt) {
        u16 h4[4], l4[4];
        #pragma unroll
        for (int r = 0; r < 4; ++r) split_bf(oA[dt][r] * invA, h4[r], l4[r]);
        size_t co = cbA + dt * 16 + 4 * lg;
        *(uint2*)&ch[co] = make_uint2((uint32_t)h4[0] | ((uint32_t)h4[1] << 16),
                                      (uint32_t)h4[2] | ((uint32_t)h4[3] << 16));
        *(uint2*)&cl[co] = make_uint2((uint32_t)l4[0] | ((uint32_t)l4[1] << 16),
                                      (uint32_t)l4[2] | ((uint32_t)l4[3] << 16));
        #pragma unroll
        for (int r = 0; r < 4; ++r) split_bf(oB[dt][r] * invB, h4[r], l4[r]);
        co = cbB + dt * 16 + 4 * lg;
        *(uint2*)&ch[co] = make_uint2((uint32_t)h4[0] | ((uint32_t)h4[1] << 16),
                                      (uint32_t)h4[2] | ((uint32_t)h4[3] << 16));
        *(uint2*)&cl[co] = make_uint2((uint32_t)l4[0] | ((uint32_t)l4[1] << 16),
                                      (uint32_t)l4[2] | ((uint32_t)l4[3] << 16));
    }
}

// ------------------------------------------------------------------- host

extern "C" void kernel_launch(void* const* d_in, const int* in_sizes, int n_in,
                              void* d_out, int out_size, void* d_ws, size_t ws_size,
                              hipStream_t stream) {
    const float* x0     = (const float*)d_in[0];
    const float* aproj  = (const float*)d_in[1];
    const float* mproj  = (const float*)d_in[2];
    const float* Wqkv   = (const float*)d_in[3];
    const float* Wo     = (const float*)d_in[4];
    const float* Wm1    = (const float*)d_in[5];
    const float* Wm2    = (const float*)d_in[6];
    const float* ascale = (const float*)d_in[7];
    const float* mscale = (const float*)d_in[8];
    const float* lns    = (const float*)d_in[9];
    float* out = (float*)d_out;
    char*  base = (char*)d_ws;

    float* p1  = (float*)base;
    float* p2  = p1 + BTD;
    float* p3  = p2 + BTD;
    u16*   xnh = (u16*)(base + 12 * BTD);
    u16*   xnl = xnh + BTD;
    u16*   wth = (u16*)(base + 16 * BTD);
    char*  QB  = base + 16 * BTD + (size_t)2 * 2 * 3072 * 768;
    u16* qh  = (u16*)QB;
    u16* ql  = qh + BTD;
    u16* kh  = ql + BTD;
    u16* kl  = kh + BTD;
    u16* vh  = kl + BTD;
    u16* vl  = vh + BTD;
    u16* vth = vl + BTD;
    u16* midh = qh;
    u16* midl = vh;
    u16* ctxh = vh;
    u16* ctxl = vl;

    float* pb[3] = {p1, p2, p3};
    const float* hist[6];
    int nh = 1;
    hist[0] = x0;
    const float* partial_c = x0;
    float* partial_w = nullptr;
    int pidx = 0;

    auto launch_agg = [&](int n, const float* Vl6[6], const float* qvec,
                          const float* lnsl) {
        switch (n) {
        case 2: agg_norm_kernel<2><<<dim3(ROWS), 256, 0, stream>>>(Vl6[0], Vl6[1], Vl6[2], Vl6[3], Vl6[4], Vl6[5], qvec, lnsl, xnh, xnl); break;
        case 3: agg_norm_kernel<3><<<dim3(ROWS), 256, 0, stream>>>(Vl6[0], Vl6[1], Vl6[2], Vl6[3], Vl6[4], Vl6[5], qvec, lnsl, xnh, xnl); break;
        case 4: agg_norm_kernel<4><<<dim3(ROWS), 256, 0, stream>>>(Vl6[0], Vl6[1], Vl6[2], Vl6[3], Vl6[4], Vl6[5], qvec, lnsl, xnh, xnl); break;
        case 5: agg_norm_kernel<5><<<dim3(ROWS), 256, 0, stream>>>(Vl6[0], Vl6[1], Vl6[2], Vl6[3], Vl6[4], Vl6[5], qvec, lnsl, xnh, xnl); break;
        default: agg_norm_kernel<6><<<dim3(ROWS), 256, 0, stream>>>(Vl6[0], Vl6[1], Vl6[2], Vl6[3], Vl6[4], Vl6[5], qvec, lnsl, xnh, xnl); break;
        }
    };

    for (int l = 0; l < NLAYER; ++l) {
        // ---- attention-path aggregate (reads OLD partial) -> xn hi/lo
        const float* Vl6[6] = {nullptr, nullptr, nullptr, nullptr, nullptr, nullptr};
        for (int i = 0; i < nh; ++i) Vl6[i] = hist[i];
        Vl6[nh] = partial_c;
        launch_agg(nh + 1, Vl6, aproj + (size_t)l * D_MODEL, lns + l);

        // ---- block boundary
        if ((l & 1) == 0) {
            hist[nh++] = partial_c;
            float* np = (pidx < 3) ? pb[pidx] : out;
            ++pidx;
            fill_zero4<<<dim3((int)(BTD / 4 / 256)), 256, 0, stream>>>((float4*)np, (int)(BTD / 4));
            partial_w = np;
            partial_c = np;
        }

        // ---- QKV GEMM -> head-major split q/k/v (V hi only)
        transpose_split<<<dim3(D_MODEL / 32, 3 * D_MODEL / 32), 256, 0, stream>>>(
            Wqkv + (size_t)l * D_MODEL * 3 * D_MODEL, wth, D_MODEL, 3 * D_MODEL);
        gemm_bf2<3, 128><<<dim3(3 * D_MODEL / 128, ROWS / 128), 256, 0, stream>>>(
            xnh, xnl, wth, nullptr, nullptr, nullptr, nullptr,
            ROWS, 3 * D_MODEL, D_MODEL, qh, ql, kh, kl, vh);

        // ---- V transpose (hi only) -> vth
        vt_transpose<<<dim3(T_SEQ / 32, HDIM / 32, B_BATCH * NHEAD), 256, 0, stream>>>(
            vh, vth);

        // ---- flash attention -> ctx (aliases vh/vl; flash reads vth only)
        flash16<<<dim3(768), 256, 0, stream>>>(
            qh, ql, kh, kl, vth, ctxh, ctxl);

        // ---- Wo GEMM: partial += attn_scale * (ctx @ Wo)  [BN=64: 768 blocks]
        transpose_split<<<dim3(D_MODEL / 32, D_MODEL / 32), 256, 0, stream>>>(
            Wo + (size_t)l * D_MODEL * D_MODEL, wth, D_MODEL, D_MODEL);
        gemm_bf2<2, 64><<<dim3(D_MODEL / 64, ROWS / 128), 256, 0, stream>>>(
            ctxh, ctxl, wth, partial_w, nullptr, nullptr,
            ascale + (size_t)l * D_MODEL, ROWS, D_MODEL, D_MODEL,
            nullptr, nullptr, nullptr, nullptr, nullptr);

        // ---- mlp-path aggregate (reads NEW partial) -> xn hi/lo
        const float* V26[6] = {nullptr, nullptr, nullptr, nullptr, nullptr, nullptr};
        for (int i = 0; i < nh; ++i) V26[i] = hist[i];
        V26[nh] = partial_c;
        launch_agg(nh + 1, V26, mproj + (size_t)l * D_MODEL, lns + l);

        // ---- MLP
        transpose_split<<<dim3(D_MODEL / 32, 4 * D_MODEL / 32), 256, 0, stream>>>(
            Wm1 + (size_t)l * D_MODEL * 4 * D_MODEL, wth, D_MODEL, 4 * D_MODEL);
        gemm_bf2<1, 128><<<dim3(4 * D_MODEL / 128, ROWS / 128), 256, 0, stream>>>(
            xnh, xnl, wth, nullptr, midh, midl, nullptr,
            ROWS, 4 * D_MODEL, D_MODEL,
            nullptr, nullptr, nullptr, nullptr, nullptr);
        transpose_split<<<dim3(4 * D_MODEL / 32, D_MODEL / 32), 256, 0, stream>>>(
            Wm2 + (size_t)l * 4 * D_MODEL * D_MODEL, wth, 4 * D_MODEL, D_MODEL);
        gemm_bf2<2, 64><<<dim3(D_MODEL / 64, ROWS / 128), 256, 0, stream>>>(
            midh, midl, wth, partial_w, nullptr, nullptr,
            mscale + (size_t)l * D_MODEL, ROWS, D_MODEL, 4 * D_MODEL,
            nullptr, nullptr, nullptr, nullptr, nullptr);
    }
}

// Round 9
// 3858.646 us; speedup vs baseline: 5.1832x; 1.0968x over previous
//
#include <hip/hip_runtime.h>
#include <hip/hip_bf16.h>
#include <math.h>
#include <stdint.h>

#define D_MODEL 768
#define T_SEQ   1024
#define B_BATCH 8
#define NHEAD   12
#define HDIM    64
#define NLAYER  8

typedef unsigned short u16;
typedef __attribute__((ext_vector_type(8))) short bf16x8;
typedef __attribute__((ext_vector_type(4))) float f32x4;
typedef __attribute__((ext_vector_type(4))) uint32_t u32x4;

static constexpr size_t BTD  = (size_t)B_BATCH * T_SEQ * D_MODEL;  // 6291456
static constexpr int    ROWS = B_BATCH * T_SEQ;                    // 8192
static constexpr float  EPSF = 1.1920928955078125e-07f;            // FLT_EPSILON

// ---------------------------------------------------------------- helpers

__device__ __forceinline__ u16 f2bf(float x) {
    __hip_bfloat16 h = __float2bfloat16(x);
    return __builtin_bit_cast(u16, h);
}
__device__ __forceinline__ float bf2f(u16 u) {
    __hip_bfloat16 h = __builtin_bit_cast(__hip_bfloat16, u);
    return __bfloat162float(h);
}
__device__ __forceinline__ void split_bf(float x, u16& hi, u16& lo) {
    hi = f2bf(x);
    lo = f2bf(x - bf2f(hi));
}
__device__ __forceinline__ uint32_t cvt_pk_bf16(float a, float b) {
    uint32_t r;
    asm("v_cvt_pk_bf16_f32 %0, %1, %2" : "=v"(r) : "v"(a), "v"(b));
    return r;
}
__device__ __forceinline__ f32x4 mfma16(bf16x8 a, bf16x8 b, f32x4 c) {
    return __builtin_amdgcn_mfma_f32_16x16x32_bf16(a, b, c, 0, 0, 0);
}

// async global->LDS, 16B/lane; LDS dest wave-uniform base (HW adds lane*16)
__device__ __forceinline__ void gl_lds16(const void* g, void* l) {
    auto gp = reinterpret_cast<const __attribute__((address_space(1))) char*>(
        reinterpret_cast<uintptr_t>(g));
    auto lp = reinterpret_cast<__attribute__((address_space(3))) char*>(
        static_cast<uint32_t>(reinterpret_cast<uintptr_t>(l)));
    __builtin_amdgcn_global_load_lds(gp, lp, 16, 0, 0);
}

__global__ __launch_bounds__(256) void fill_zero4(float4* __restrict__ p, int n4) {
    int i = blockIdx.x * 256 + threadIdx.x;
    if (i < n4) p[i] = make_float4(0.f, 0.f, 0.f, 0.f);
}

__device__ __forceinline__ float block_reduce_sum(float v, float* sbuf) {
    #pragma unroll
    for (int off = 32; off > 0; off >>= 1) v += __shfl_down(v, off);
    __syncthreads();
    if ((threadIdx.x & 63) == 0) sbuf[threadIdx.x >> 6] = v;
    __syncthreads();
    return sbuf[0] + sbuf[1] + sbuf[2] + sbuf[3];
}

// tanh-gelu via exp: 0.5x(1+tanh(z)) = x - x/(exp(2z)+1); exact at +-inf
__device__ __forceinline__ float gelu_fast(float x) {
    float z = 0.7978845608028654f * (x + 0.044715f * x * x * x);
    float e = __expf(2.f * z);
    return x - x / (e + 1.f);
}

// ------------------------------------------------- aggregate + rmsnorm fuse
template<int N>
__global__ __launch_bounds__(256)
void agg_norm_kernel(const float* __restrict__ v0, const float* __restrict__ v1,
                     const float* __restrict__ v2, const float* __restrict__ v3,
                     const float* __restrict__ v4, const float* __restrict__ v5,
                     const float* __restrict__ q,  const float* __restrict__ lns,
                     u16* __restrict__ xh, u16* __restrict__ xl) {
    __shared__ float sbuf[4];
    const float* V[6] = {v0, v1, v2, v3, v4, v5};
    const size_t row = blockIdx.x;
    const int tid = threadIdx.x;

    float qv[3];
    #pragma unroll
    for (int j = 0; j < 3; ++j) qv[j] = q[tid + j * 256];

    float vv[N][3];
    float logits[N];
    #pragma unroll
    for (int i = 0; i < N; ++i) {
        const float* vr = V[i] + row * D_MODEL;
        float ssq = 0.f, qd = 0.f;
        #pragma unroll
        for (int j = 0; j < 3; ++j) {
            float x = vr[tid + j * 256];
            vv[i][j] = x;
            ssq = fmaf(x, x, ssq);
            qd  = fmaf(qv[j], x, qd);
        }
        float S  = block_reduce_sum(ssq, sbuf);
        float Qd = block_reduce_sum(qd,  sbuf);
        logits[i] = Qd * rsqrtf(S * (1.f / 768.f) + EPSF);
    }
    float mx = logits[0];
    #pragma unroll
    for (int i = 1; i < N; ++i) mx = fmaxf(mx, logits[i]);
    float w[N];
    float wsum = 0.f;
    #pragma unroll
    for (int i = 0; i < N; ++i) { w[i] = __expf(logits[i] - mx); wsum += w[i]; }
    float inv = 1.f / wsum;

    float outv[3] = {0.f, 0.f, 0.f};
    #pragma unroll
    for (int i = 0; i < N; ++i) {
        float wi = w[i] * inv;
        #pragma unroll
        for (int j = 0; j < 3; ++j) outv[j] = fmaf(wi, vv[i][j], outv[j]);
    }
    float ssq = 0.f;
    #pragma unroll
    for (int j = 0; j < 3; ++j) ssq = fmaf(outv[j], outv[j], ssq);
    float S2 = block_reduce_sum(ssq, sbuf);
    float scale = lns[0] * rsqrtf(S2 * (1.f / 768.f) + EPSF);
    #pragma unroll
    for (int j = 0; j < 3; ++j) {
        float x = outv[j] * scale;
        u16 hi, lo;
        split_bf(x, hi, lo);
        size_t idx = row * D_MODEL + tid + j * 256;
        xh[idx] = hi;
        xl[idx] = lo;
    }
}

// ---------------------------------------------- weight transpose (hi only)
__global__ __launch_bounds__(256)
void transpose_split(const float* __restrict__ W, u16* __restrict__ Th,
                     int K, int N) {
    __shared__ float t[32][33];
    const int bk = blockIdx.x * 32, bn = blockIdx.y * 32;
    const int r = threadIdx.x >> 3, c4 = (threadIdx.x & 7) * 4;
    float4 v = *(const float4*)&W[(size_t)(bk + r) * N + bn + c4];
    t[r][c4 + 0] = v.x; t[r][c4 + 1] = v.y; t[r][c4 + 2] = v.z; t[r][c4 + 3] = v.w;
    __syncthreads();
    u16 h[4];
    #pragma unroll
    for (int j = 0; j < 4; ++j) h[j] = f2bf(t[c4 + j][r]);
    size_t o = (size_t)(bn + r) * K + bk + c4;
    *(uint2*)&Th[o] = make_uint2((uint32_t)h[0] | ((uint32_t)h[1] << 16),
                                 (uint32_t)h[2] | ((uint32_t)h[3] << 16));
}

// ---------------------------------------------- V transpose (head-major, hi only)
__global__ __launch_bounds__(256)
void vt_transpose(const u16* __restrict__ vh, u16* __restrict__ vth) {
    __shared__ u16 th[32][36];
    const int bh = blockIdx.z;
    const int t0 = blockIdx.x * 32, d0 = blockIdx.y * 32;
    const int r = threadIdx.x >> 3, c = (threadIdx.x & 7) * 4;
    const size_t ib = ((size_t)(bh << 10) + t0 + r) * 64 + d0 + c;
    *(uint2*)&th[r][c] = *(const uint2*)&vh[ib];
    __syncthreads();
    const size_t ob = ((size_t)(bh << 6) + d0 + r) * 1024 + t0 + c;
    u16 a0 = th[c + 0][r], a1 = th[c + 1][r], a2 = th[c + 2][r], a3 = th[c + 3][r];
    *(uint2*)&vth[ob] = make_uint2((uint32_t)a0 | ((uint32_t)a1 << 16),
                                   (uint32_t)a2 | ((uint32_t)a3 << 16));
}

// ------------------------------------------------- split-A x bf16-W MFMA GEMM
// C[M,N] = (Ah+Al)[M,K] @ Bh^T  (B given as [N][K]); 2-term product.
// Prefetch-pipelined: LDS double-buffer, counted vmcnt + raw barriers.
// EPI: 1 = gelu -> bf16 hi/lo, 2 = Cf += scale[n]*acc,
//      3 = scatter qkv (q*0.125) into head-major buffers (Q hi/lo, K/V hi)
template<int EPI, int BN>
__global__ __launch_bounds__(256)
void gemm_bf2(const u16* __restrict__ Ah, const u16* __restrict__ Al,
              const u16* __restrict__ Bh,
              float* __restrict__ Cf, u16* __restrict__ Ch, u16* __restrict__ Cl,
              const float* __restrict__ scale, int M, int N, int K,
              u16* __restrict__ Qh, u16* __restrict__ Ql,
              u16* __restrict__ Kh, u16* __restrict__ Vh) {
    constexpr int NJ = BN / 32;
    constexpr int BUFB = 16384 + BN * 64;       // bytes per buffer
    __shared__ u16 smem[2 * (8192 + BN * 32)];

    // XCD-contiguous remap (nwg always % 8 == 0)
    const int nwg = gridDim.x * gridDim.y;
    const int lin = blockIdx.y * gridDim.x + blockIdx.x;
    const int wg  = (lin & 7) * (nwg >> 3) + (lin >> 3);
    const int bm  = (wg / gridDim.x) << 7;
    const int bn  = (wg % gridDim.x) * BN;

    const int tid = threadIdx.x;
    const int w = tid >> 6, l = tid & 63;
    const int wr = w >> 1, wc = w & 1;

    const int grow = tid >> 2;
    const int gcol = (((tid & 3) ^ ((tid >> 3) & 3)) << 3);
    const size_t aoff0 = (size_t)(bm + grow) * K + gcol;
    const size_t boff0 = (size_t)(bn + grow) * K + gcol;
    const size_t s64 = (size_t)64 * K;
    char* sb0 = (char*)smem;
    char* sb1 = (char*)smem + BUFB;
    const uint32_t wq = (uint32_t)w << 10;

    auto stage = [&](char* sbuf, int k0) {
        gl_lds16(Ah + aoff0 + k0,       sbuf + 0     + wq);
        gl_lds16(Ah + aoff0 + s64 + k0, sbuf + 4096  + wq);
        gl_lds16(Al + aoff0 + k0,       sbuf + 8192  + wq);
        gl_lds16(Al + aoff0 + s64 + k0, sbuf + 12288 + wq);
        gl_lds16(Bh + boff0 + k0,       sbuf + 16384 + wq);
        if constexpr (BN == 128)
            gl_lds16(Bh + boff0 + s64 + k0, sbuf + 20480 + wq);
    };

    f32x4 acc[4][NJ] = {};

    const int key8 = (((l & 15) >> 1) & 3) << 3;
    const int kswz = ((l >> 4) << 3) ^ key8;
    const int arow = wr * 64 + (l & 15);
    const int brow = wc * (BN / 2) + (l & 15);
    const int nk = K >> 5;

    stage(sb0, 0);
    for (int kt = 0; kt < nk; ++kt) {
        char* cur = (kt & 1) ? sb1 : sb0;
        char* nxt = (kt & 1) ? sb0 : sb1;
        if (kt + 1 < nk) {
            stage(nxt, (kt + 1) << 5);
            if constexpr (BN == 128)
                asm volatile("s_waitcnt vmcnt(6)\n\ts_barrier" ::: "memory");
            else
                asm volatile("s_waitcnt vmcnt(5)\n\ts_barrier" ::: "memory");
        } else {
            asm volatile("s_waitcnt vmcnt(0)\n\ts_barrier" ::: "memory");
        }
        __builtin_amdgcn_sched_barrier(0);

        const u16* bu = (const u16*)cur;
        bf16x8 ah[4], al4[4], bh4[NJ];
        #pragma unroll
        for (int i = 0; i < 4; ++i) {
            ah[i]  = *(const bf16x8*)&bu[(arow + i * 16) * 32 + kswz];
            al4[i] = *(const bf16x8*)&bu[4096 + (arow + i * 16) * 32 + kswz];
        }
        #pragma unroll
        for (int j = 0; j < NJ; ++j)
            bh4[j] = *(const bf16x8*)&bu[8192 + (brow + j * 16) * 32 + kswz];
        asm volatile("s_waitcnt lgkmcnt(0)" ::: "memory");
        __builtin_amdgcn_sched_barrier(0);
        asm volatile("s_barrier" ::: "memory");   // all waves done reading cur

        #pragma unroll
        for (int i = 0; i < 4; ++i) {
            #pragma unroll
            for (int j = 0; j < NJ; ++j) {
                acc[i][j] = mfma16(ah[i],  bh4[j], acc[i][j]);
                acc[i][j] = mfma16(al4[i], bh4[j], acc[i][j]);
            }
        }
    }

    // C/D frag: col = lane&15, row = (lane>>4)*4 + reg
    const int crow0 = bm + wr * 64 + ((l >> 4) << 2);
    const int ccol0 = bn + wc * (BN / 2) + (l & 15);
    #pragma unroll
    for (int i = 0; i < 4; ++i) {
        #pragma unroll
        for (int j = 0; j < NJ; ++j) {
            const int col = ccol0 + j * 16;
            #pragma unroll
            for (int r = 0; r < 4; ++r) {
                const int row = crow0 + i * 16 + r;
                const size_t o = (size_t)row * N + col;
                float v = acc[i][j][r];
                if (EPI == 1) {
                    float g = gelu_fast(v);
                    u16 hi, lo;
                    split_bf(g, hi, lo);
                    Ch[o] = hi; Cl[o] = lo;
                } else if (EPI == 2) {
                    Cf[o] += scale[col] * v;
                } else if (EPI == 3) {
                    const int which = (col >= 1536) ? 2 : ((col >= 768) ? 1 : 0);
                    const int hcol = col - which * 768;
                    const size_t dst = ((size_t)((row >> 10) * NHEAD + (hcol >> 6)) * 1024
                                        + (row & 1023)) * 64 + (hcol & 63);
                    if (which == 0) {
                        v *= 0.125f;
                        u16 hi, lo;
                        split_bf(v, hi, lo);
                        Qh[dst] = hi; Ql[dst] = lo;
                    } else if (which == 1) {
                        Kh[dst] = f2bf(v);
                    } else {
                        Vh[dst] = f2bf(v);
                    }
                }
            }
        }
    }
}

// --------------------------------------------------- MFMA flash attention
// Paired q-tiles {p, 15-p} share one K/V fragment stream. K hi-only
// (S = Kh*(Qh+Ql)); K AND V register double-buffered (full-step prefetch);
// defer-max (THR=8). P redistribution via register shuffles (no LDS).
__global__ __launch_bounds__(256, 3)
void flash16(const u16* __restrict__ qh, const u16* __restrict__ ql,
             const u16* __restrict__ kh, const u16* __restrict__ vth,
             u16* __restrict__ ch, u16* __restrict__ cl) {
    const int id = blockIdx.x;
    const int r8 = id & 7, s = id >> 3;
    const int bh = r8 + 8 * (s >> 3);
    const int p  = s & 7;
    const int hh = bh % NHEAD, bb = bh / NHEAD;
    const int tid = threadIdx.x, w = tid >> 6, l = tid & 63;
    const int lq = l & 15, lg = l >> 4;
    const size_t hb = (size_t)bh << 16;

    const int wqA = p * 64 + w * 16;
    const int wqB = (15 - p) * 64 + w * 16;
    const int qA = wqA + lq, qB = wqB + lq;

    bf16x8 qA0, qA1, qA2, qA3, qB0, qB1, qB2, qB3;
    {
        const size_t qa = hb + ((size_t)qA << 6) + lg * 8;
        qA0 = *(const bf16x8*)(qh + qa);       qA1 = *(const bf16x8*)(ql + qa);
        qA2 = *(const bf16x8*)(qh + qa + 32);  qA3 = *(const bf16x8*)(ql + qa + 32);
        const size_t qb = hb + ((size_t)qB << 6) + lg * 8;
        qB0 = *(const bf16x8*)(qh + qb);       qB1 = *(const bf16x8*)(ql + qb);
        qB2 = *(const bf16x8*)(qh + qb + 32);  qB3 = *(const bf16x8*)(ql + qb + 32);
    }

    f32x4 oA[4] = {}, oB[4] = {};
    float mA = -30000.f, lsA = 0.f, mB = -30000.f, lsB = 0.f;
    const int ntiles = 32 - 2 * p;              // always even
    const int src0 = 32 * (lg & 1) + lq, src1 = src0 + 16;
    const bool hiHalf = lg >= 2;

    bf16x8 KA[4], KB[4], VA[4], VB[4];
    auto loadK = [&](bf16x8 (&K)[4], int k0) {
        const size_t kb0 = hb + (size_t)(k0 + lq) * 64 + lg * 8;
        const size_t kb1 = kb0 + 16 * 64;
        K[0] = *(const bf16x8*)(kh + kb0);
        K[1] = *(const bf16x8*)(kh + kb0 + 32);
        K[2] = *(const bf16x8*)(kh + kb1);
        K[3] = *(const bf16x8*)(kh + kb1 + 32);
    };
    auto loadV = [&](bf16x8 (&V)[4], int k0) {
        #pragma unroll
        for (int dt = 0; dt < 4; ++dt) {
            const size_t vb = hb + (size_t)(dt * 16 + lq) * 1024 + k0 + lg * 8;
            V[dt] = *(const bf16x8*)(vth + vb);
        }
    };

    auto path = [&](bf16x8 (&Kc)[4], bf16x8 (&vf)[4], int k0, int wqX, int qX,
                    bf16x8 q0, bf16x8 q1, bf16x8 q2, bf16x8 q3,
                    float& mX, float& lsX, f32x4 (&oX)[4]) {
        f32x4 s0 = {}, s1 = {};
        s0 = mfma16(Kc[0], q0, s0); s0 = mfma16(Kc[0], q1, s0);
        s0 = mfma16(Kc[1], q2, s0); s0 = mfma16(Kc[1], q3, s0);
        s1 = mfma16(Kc[2], q0, s1); s1 = mfma16(Kc[2], q1, s1);
        s1 = mfma16(Kc[3], q2, s1); s1 = mfma16(Kc[3], q3, s1);
        if (k0 + 31 > wqX) {
            #pragma unroll
            for (int r = 0; r < 4; ++r) {
                if (k0 + 4 * lg + r > qX)      s0[r] = -30000.f;
                if (k0 + 16 + 4 * lg + r > qX) s1[r] = -30000.f;
            }
        }
        float tmloc = fmaxf(fmaxf(fmaxf(s0[0], s0[1]), fmaxf(s0[2], s0[3])),
                            fmaxf(fmaxf(s1[0], s1[1]), fmaxf(s1[2], s1[3])));
        if (__any(tmloc > mX + 8.f)) {
            float tm = fmaxf(tmloc, __shfl_xor(tmloc, 16));
            tm = fmaxf(tm, __shfl_xor(tm, 32));
            const float mnew = fmaxf(mX, tm);
            const float fac = __expf(mX - mnew);
            mX = mnew;
            lsX *= fac;
            #pragma unroll
            for (int dt = 0; dt < 4; ++dt) {
                oX[dt][0] *= fac; oX[dt][1] *= fac;
                oX[dt][2] *= fac; oX[dt][3] *= fac;
            }
        }
        float ps = 0.f;
        #pragma unroll
        for (int r = 0; r < 4; ++r) {
            s0[r] = __expf(s0[r] - mX); ps += s0[r];
            s1[r] = __expf(s1[r] - mX); ps += s1[r];
        }
        lsX += ps;
        const uint32_t wA0 = cvt_pk_bf16(s0[0], s0[1]);
        const uint32_t wA1 = cvt_pk_bf16(s0[2], s0[3]);
        const uint32_t wB0 = cvt_pk_bf16(s1[0], s1[1]);
        const uint32_t wB1 = cvt_pk_bf16(s1[2], s1[3]);
        const uint32_t a0 = (uint32_t)__shfl((int)wA0, src0);
        const uint32_t b0 = (uint32_t)__shfl((int)wB0, src0);
        const uint32_t a1 = (uint32_t)__shfl((int)wA1, src0);
        const uint32_t b1 = (uint32_t)__shfl((int)wB1, src0);
        const uint32_t a2 = (uint32_t)__shfl((int)wA0, src1);
        const uint32_t b2 = (uint32_t)__shfl((int)wB0, src1);
        const uint32_t a3 = (uint32_t)__shfl((int)wA1, src1);
        const uint32_t b3 = (uint32_t)__shfl((int)wB1, src1);
        u32x4 pw = { hiHalf ? b0 : a0, hiHalf ? b1 : a1,
                     hiHalf ? b2 : a2, hiHalf ? b3 : a3 };
        const bf16x8 pb = __builtin_bit_cast(bf16x8, pw);
        #pragma unroll
        for (int dt = 0; dt < 4; ++dt)
            oX[dt] = mfma16(vf[dt], pb, oX[dt]);
    };

    auto step = [&](bf16x8 (&Kc)[4], bf16x8 (&Vc)[4],
                    bf16x8 (&Kn)[4], bf16x8 (&Vn)[4], int kt) {
        const int k0 = kt * 32;
        const int ktn = (kt + 1 < ntiles) ? kt + 1 : kt;
        loadK(Kn, ktn * 32);
        loadV(Vn, ktn * 32);
        if (k0 <= wqB + 15)
            path(Kc, Vc, k0, wqB, qB, qB0, qB1, qB2, qB3, mB, lsB, oB);
        if (k0 <= wqA + 15)
            path(Kc, Vc, k0, wqA, qA, qA0, qA1, qA2, qA3, mA, lsA, oA);
    };

    loadK(KA, 0);
    loadV(VA, 0);
    for (int kt = 0; kt < ntiles; kt += 2) {
        step(KA, VA, KB, VB, kt);
        step(KB, VB, KA, VA, kt + 1);
    }

    lsA += __shfl_xor(lsA, 16); lsA += __shfl_xor(lsA, 32);
    lsB += __shfl_xor(lsB, 16); lsB += __shfl_xor(lsB, 32);
    const float invA = 1.f / lsA, invB = 1.f / lsB;
    const size_t cbA = ((size_t)(bb * 1024 + qA)) * 768 + hh * 64;
    const size_t cbB = ((size_t)(bb * 1024 + qB)) * 768 + hh * 64;
    #pragma unroll
    for (int dt = 0; dt < 4; ++dt) {
        u16 h4[4], l4[4];
        #pragma unroll
        for (int r = 0; r < 4; ++r) split_bf(oA[dt][r] * invA, h4[r], l4[r]);
        size_t co = cbA + dt * 16 + 4 * lg;
        *(uint2*)&ch[co] = make_uint2((uint32_t)h4[0] | ((uint32_t)h4[1] << 16),
                                      (uint32_t)h4[2] | ((uint32_t)h4[3] << 16));
        *(uint2*)&cl[co] = make_uint2((uint32_t)l4[0] | ((uint32_t)l4[1] << 16),
                                      (uint32_t)l4[2] | ((uint32_t)l4[3] << 16));
        #pragma unroll
        for (int r = 0; r < 4; ++r) split_bf(oB[dt][r] * invB, h4[r], l4[r]);
        co = cbB + dt * 16 + 4 * lg;
        *(uint2*)&ch[co] = make_uint2((uint32_t)h4[0] | ((uint32_t)h4[1] << 16),
                                      (uint32_t)h4[2] | ((uint32_t)h4[3] << 16));
        *(uint2*)&cl[co] = make_uint2((uint32_t)l4[0] | ((uint32_t)l4[1] << 16),
                                      (uint32_t)l4[2] | ((uint32_t)l4[3] << 16));
    }
}

// ------------------------------------------------------------------- host

extern "C" void kernel_launch(void* const* d_in, const int* in_sizes, int n_in,
                              void* d_out, int out_size, void* d_ws, size_t ws_size,
                              hipStream_t stream) {
    const float* x0     = (const float*)d_in[0];
    const float* aproj  = (const float*)d_in[1];
    const float* mproj  = (const float*)d_in[2];
    const float* Wqkv   = (const float*)d_in[3];
    const float* Wo     = (const float*)d_in[4];
    const float* Wm1    = (const float*)d_in[5];
    const float* Wm2    = (const float*)d_in[6];
    const float* ascale = (const float*)d_in[7];
    const float* mscale = (const float*)d_in[8];
    const float* lns    = (const float*)d_in[9];
    float* out = (float*)d_out;
    char*  base = (char*)d_ws;

    float* p1  = (float*)base;
    float* p2  = p1 + BTD;
    float* p3  = p2 + BTD;
    u16*   xnh = (u16*)(base + 12 * BTD);
    u16*   xnl = xnh + BTD;
    u16*   wth = (u16*)(base + 16 * BTD);           // 3072*768 u16 = 4.72 MB
    char*  QB  = base + 16 * BTD + (size_t)2 * 3072 * 768;
    // QB region: 8 consecutive BTD-u16 slots
    u16* qh   = (u16*)QB;        // slot 0
    u16* ql   = qh  + BTD;       // slot 1
    u16* kh   = ql  + BTD;       // slot 2
    u16* vh   = kh  + BTD;       // slot 3
    u16* vth  = vh  + BTD;       // slot 4
    u16* ctxl = vth + BTD;       // slot 5
    //        slots 6,7 reserved for midl span
    u16* ctxh = vh;              // vh dead after vt_transpose
    u16* midh = qh;              // spans slots 0-3 (qkv dead after Wo)
    u16* midl = vth;             // spans slots 4-7 (vth/ctx dead after Wo)

    float* pb[3] = {p1, p2, p3};
    const float* hist[6];
    int nh = 1;
    hist[0] = x0;
    const float* partial_c = x0;
    float* partial_w = nullptr;
    int pidx = 0;

    auto launch_agg = [&](int n, const float* Vl6[6], const float* qvec,
                          const float* lnsl) {
        switch (n) {
        case 2: agg_norm_kernel<2><<<dim3(ROWS), 256, 0, stream>>>(Vl6[0], Vl6[1], Vl6[2], Vl6[3], Vl6[4], Vl6[5], qvec, lnsl, xnh, xnl); break;
        case 3: agg_norm_kernel<3><<<dim3(ROWS), 256, 0, stream>>>(Vl6[0], Vl6[1], Vl6[2], Vl6[3], Vl6[4], Vl6[5], qvec, lnsl, xnh, xnl); break;
        case 4: agg_norm_kernel<4><<<dim3(ROWS), 256, 0, stream>>>(Vl6[0], Vl6[1], Vl6[2], Vl6[3], Vl6[4], Vl6[5], qvec, lnsl, xnh, xnl); break;
        case 5: agg_norm_kernel<5><<<dim3(ROWS), 256, 0, stream>>>(Vl6[0], Vl6[1], Vl6[2], Vl6[3], Vl6[4], Vl6[5], qvec, lnsl, xnh, xnl); break;
        default: agg_norm_kernel<6><<<dim3(ROWS), 256, 0, stream>>>(Vl6[0], Vl6[1], Vl6[2], Vl6[3], Vl6[4], Vl6[5], qvec, lnsl, xnh, xnl); break;
        }
    };

    for (int l = 0; l < NLAYER; ++l) {
        // ---- attention-path aggregate (reads OLD partial) -> xn hi/lo
        const float* Vl6[6] = {nullptr, nullptr, nullptr, nullptr, nullptr, nullptr};
        for (int i = 0; i < nh; ++i) Vl6[i] = hist[i];
        Vl6[nh] = partial_c;
        launch_agg(nh + 1, Vl6, aproj + (size_t)l * D_MODEL, lns + l);

        // ---- block boundary
        if ((l & 1) == 0) {
            hist[nh++] = partial_c;
            float* np = (pidx < 3) ? pb[pidx] : out;
            ++pidx;
            fill_zero4<<<dim3((int)(BTD / 4 / 256)), 256, 0, stream>>>((float4*)np, (int)(BTD / 4));
            partial_w = np;
            partial_c = np;
        }

        // ---- QKV GEMM -> head-major q (hi/lo), k/v (hi)
        transpose_split<<<dim3(D_MODEL / 32, 3 * D_MODEL / 32), 256, 0, stream>>>(
            Wqkv + (size_t)l * D_MODEL * 3 * D_MODEL, wth, D_MODEL, 3 * D_MODEL);
        gemm_bf2<3, 128><<<dim3(3 * D_MODEL / 128, ROWS / 128), 256, 0, stream>>>(
            xnh, xnl, wth, nullptr, nullptr, nullptr, nullptr,
            ROWS, 3 * D_MODEL, D_MODEL, qh, ql, kh, vh);

        // ---- V transpose (hi only) -> vth
        vt_transpose<<<dim3(T_SEQ / 32, HDIM / 32, B_BATCH * NHEAD), 256, 0, stream>>>(
            vh, vth);

        // ---- flash attention -> ctx (ctxh aliases vh, dead)
        flash16<<<dim3(768), 256, 0, stream>>>(
            qh, ql, kh, vth, ctxh, ctxl);

        // ---- Wo GEMM: partial += attn_scale * (ctx @ Wo)  [BN=64: 768 blocks]
        transpose_split<<<dim3(D_MODEL / 32, D_MODEL / 32), 256, 0, stream>>>(
            Wo + (size_t)l * D_MODEL * D_MODEL, wth, D_MODEL, D_MODEL);
        gemm_bf2<2, 64><<<dim3(D_MODEL / 64, ROWS / 128), 256, 0, stream>>>(
            ctxh, ctxl, wth, partial_w, nullptr, nullptr,
            ascale + (size_t)l * D_MODEL, ROWS, D_MODEL, D_MODEL,
            nullptr, nullptr, nullptr, nullptr);

        // ---- mlp-path aggregate (reads NEW partial) -> xn hi/lo
        const float* V26[6] = {nullptr, nullptr, nullptr, nullptr, nullptr, nullptr};
        for (int i = 0; i < nh; ++i) V26[i] = hist[i];
        V26[nh] = partial_c;
        launch_agg(nh + 1, V26, mproj + (size_t)l * D_MODEL, lns + l);

        // ---- MLP
        transpose_split<<<dim3(D_MODEL / 32, 4 * D_MODEL / 32), 256, 0, stream>>>(
            Wm1 + (size_t)l * D_MODEL * 4 * D_MODEL, wth, D_MODEL, 4 * D_MODEL);
        gemm_bf2<1, 128><<<dim3(4 * D_MODEL / 128, ROWS / 128), 256, 0, stream>>>(
            xnh, xnl, wth, nullptr, midh, midl, nullptr,
            ROWS, 4 * D_MODEL, D_MODEL,
            nullptr, nullptr, nullptr, nullptr);
        transpose_split<<<dim3(4 * D_MODEL / 32, D_MODEL / 32), 256, 0, stream>>>(
            Wm2 + (size_t)l * 4 * D_MODEL * D_MODEL, wth, 4 * D_MODEL, D_MODEL);
        gemm_bf2<2, 64><<<dim3(D_MODEL / 64, ROWS / 128), 256, 0, stream>>>(
            midh, midl, wth, partial_w, nullptr, nullptr,
            mscale + (size_t)l * D_MODEL, ROWS, D_MODEL, 4 * D_MODEL,
            nullptr, nullptr, nullptr, nullptr);
    }
}

// Round 10
// 3301.899 us; speedup vs baseline: 6.0572x; 1.1686x over previous
//
#include <hip/hip_runtime.h>
#include <hip/hip_bf16.h>
#include <math.h>
#include <stdint.h>

#define D_MODEL 768
#define T_SEQ   1024
#define B_BATCH 8
#define NHEAD   12
#define HDIM    64
#define NLAYER  8

typedef unsigned short u16;
typedef __attribute__((ext_vector_type(8))) short bf16x8;
typedef __attribute__((ext_vector_type(4))) float f32x4;
typedef __attribute__((ext_vector_type(4))) uint32_t u32x4;

static constexpr size_t BTD  = (size_t)B_BATCH * T_SEQ * D_MODEL;  // 6291456
static constexpr int    ROWS = B_BATCH * T_SEQ;                    // 8192
static constexpr float  EPSF = 1.1920928955078125e-07f;            // FLT_EPSILON

// ---------------------------------------------------------------- helpers

__device__ __forceinline__ u16 f2bf(float x) {
    __hip_bfloat16 h = __float2bfloat16(x);
    return __builtin_bit_cast(u16, h);
}
__device__ __forceinline__ float bf2f(u16 u) {
    __hip_bfloat16 h = __builtin_bit_cast(__hip_bfloat16, u);
    return __bfloat162float(h);
}
__device__ __forceinline__ void split_bf(float x, u16& hi, u16& lo) {
    hi = f2bf(x);
    lo = f2bf(x - bf2f(hi));
}
__device__ __forceinline__ uint32_t cvt_pk_bf16(float a, float b) {
    uint32_t r;
    asm("v_cvt_pk_bf16_f32 %0, %1, %2" : "=v"(r) : "v"(a), "v"(b));
    return r;
}
__device__ __forceinline__ f32x4 mfma16(bf16x8 a, bf16x8 b, f32x4 c) {
    return __builtin_amdgcn_mfma_f32_16x16x32_bf16(a, b, c, 0, 0, 0);
}

// async global->LDS, 16B/lane; LDS dest wave-uniform base (HW adds lane*16)
__device__ __forceinline__ void gl_lds16(const void* g, void* l) {
    auto gp = reinterpret_cast<const __attribute__((address_space(1))) char*>(
        reinterpret_cast<uintptr_t>(g));
    auto lp = reinterpret_cast<__attribute__((address_space(3))) char*>(
        static_cast<uint32_t>(reinterpret_cast<uintptr_t>(l)));
    __builtin_amdgcn_global_load_lds(gp, lp, 16, 0, 0);
}

__device__ __forceinline__ float block_reduce_sum(float v, float* sbuf) {
    #pragma unroll
    for (int off = 32; off > 0; off >>= 1) v += __shfl_down(v, off);
    __syncthreads();
    if ((threadIdx.x & 63) == 0) sbuf[threadIdx.x >> 6] = v;
    __syncthreads();
    return sbuf[0] + sbuf[1] + sbuf[2] + sbuf[3];
}

// tanh-gelu via exp: 0.5x(1+tanh(z)) = x - x/(exp(2z)+1); exact at +-inf
__device__ __forceinline__ float gelu_fast(float x) {
    float z = 0.7978845608028654f * (x + 0.044715f * x * x * x);
    float e = __expf(2.f * z);
    return x - x / (e + 1.f);
}

// ------------------------------------------------- aggregate + rmsnorm fuse
template<int N>
__global__ __launch_bounds__(256)
void agg_norm_kernel(const float* __restrict__ v0, const float* __restrict__ v1,
                     const float* __restrict__ v2, const float* __restrict__ v3,
                     const float* __restrict__ v4, const float* __restrict__ v5,
                     const float* __restrict__ q,  const float* __restrict__ lns,
                     u16* __restrict__ xh, u16* __restrict__ xl) {
    __shared__ float sbuf[4];
    const float* V[6] = {v0, v1, v2, v3, v4, v5};
    const size_t row = blockIdx.x;
    const int tid = threadIdx.x;

    float qv[3];
    #pragma unroll
    for (int j = 0; j < 3; ++j) qv[j] = q[tid + j * 256];

    float vv[N][3];
    float logits[N];
    #pragma unroll
    for (int i = 0; i < N; ++i) {
        const float* vr = V[i] + row * D_MODEL;
        float ssq = 0.f, qd = 0.f;
        #pragma unroll
        for (int j = 0; j < 3; ++j) {
            float x = vr[tid + j * 256];
            vv[i][j] = x;
            ssq = fmaf(x, x, ssq);
            qd  = fmaf(qv[j], x, qd);
        }
        float S  = block_reduce_sum(ssq, sbuf);
        float Qd = block_reduce_sum(qd,  sbuf);
        logits[i] = Qd * rsqrtf(S * (1.f / 768.f) + EPSF);
    }
    float mx = logits[0];
    #pragma unroll
    for (int i = 1; i < N; ++i) mx = fmaxf(mx, logits[i]);
    float w[N];
    float wsum = 0.f;
    #pragma unroll
    for (int i = 0; i < N; ++i) { w[i] = __expf(logits[i] - mx); wsum += w[i]; }
    float inv = 1.f / wsum;

    float outv[3] = {0.f, 0.f, 0.f};
    #pragma unroll
    for (int i = 0; i < N; ++i) {
        float wi = w[i] * inv;
        #pragma unroll
        for (int j = 0; j < 3; ++j) outv[j] = fmaf(wi, vv[i][j], outv[j]);
    }
    float ssq = 0.f;
    #pragma unroll
    for (int j = 0; j < 3; ++j) ssq = fmaf(outv[j], outv[j], ssq);
    float S2 = block_reduce_sum(ssq, sbuf);
    float scale = lns[0] * rsqrtf(S2 * (1.f / 768.f) + EPSF);
    #pragma unroll
    for (int j = 0; j < 3; ++j) {
        float x = outv[j] * scale;
        u16 hi, lo;
        split_bf(x, hi, lo);
        size_t idx = row * D_MODEL + tid + j * 256;
        xh[idx] = hi;
        xl[idx] = lo;
    }
}

// ---------------------------------------------- weight transpose (hi only)
__global__ __launch_bounds__(256)
void transpose_split(const float* __restrict__ W, u16* __restrict__ Th,
                     int K, int N) {
    __shared__ float t[32][33];
    const int bk = blockIdx.x * 32, bn = blockIdx.y * 32;
    const int r = threadIdx.x >> 3, c4 = (threadIdx.x & 7) * 4;
    float4 v = *(const float4*)&W[(size_t)(bk + r) * N + bn + c4];
    t[r][c4 + 0] = v.x; t[r][c4 + 1] = v.y; t[r][c4 + 2] = v.z; t[r][c4 + 3] = v.w;
    __syncthreads();
    u16 h[4];
    #pragma unroll
    for (int j = 0; j < 4; ++j) h[j] = f2bf(t[c4 + j][r]);
    size_t o = (size_t)(bn + r) * K + bk + c4;
    *(uint2*)&Th[o] = make_uint2((uint32_t)h[0] | ((uint32_t)h[1] << 16),
                                 (uint32_t)h[2] | ((uint32_t)h[3] << 16));
}

// ---------------------------------------------- V transpose (head-major, hi only)
__global__ __launch_bounds__(256)
void vt_transpose(const u16* __restrict__ vh, u16* __restrict__ vth) {
    __shared__ u16 th[32][36];
    const int bh = blockIdx.z;
    const int t0 = blockIdx.x * 32, d0 = blockIdx.y * 32;
    const int r = threadIdx.x >> 3, c = (threadIdx.x & 7) * 4;
    const size_t ib = ((size_t)(bh << 10) + t0 + r) * 64 + d0 + c;
    *(uint2*)&th[r][c] = *(const uint2*)&vh[ib];
    __syncthreads();
    const size_t ob = ((size_t)(bh << 6) + d0 + r) * 1024 + t0 + c;
    u16 a0 = th[c + 0][r], a1 = th[c + 1][r], a2 = th[c + 2][r], a3 = th[c + 3][r];
    *(uint2*)&vth[ob] = make_uint2((uint32_t)a0 | ((uint32_t)a1 << 16),
                                   (uint32_t)a2 | ((uint32_t)a3 << 16));
}

// ------------------------------------------------- MFMA GEMM
// C[M,N] = A[M,K] @ Bh^T (B given as [N][K]).
// TWO=true: A = Ah+Al (2-term). TWO=false: A = Ah only (1-term).
// Prefetch-pipelined: LDS double-buffer, counted vmcnt + raw barriers.
// EPI: 1 = gelu -> bf16 (hi only), 2 = Cf += scale[n]*acc,
//      4 = Cf  = scale[n]*acc (init, no read),
//      3 = scatter qkv (q*0.125) into head-major buffers (Q hi/lo, K/V hi)
template<int EPI, int BN, bool TWO>
__global__ __launch_bounds__(256)
void gemm_bf2(const u16* __restrict__ Ah, const u16* __restrict__ Al,
              const u16* __restrict__ Bh,
              float* __restrict__ Cf, u16* __restrict__ Ch,
              const float* __restrict__ scale, int M, int N, int K,
              u16* __restrict__ Qh, u16* __restrict__ Ql,
              u16* __restrict__ Kh, u16* __restrict__ Vh) {
    constexpr int NJ = BN / 32;
    constexpr int A_U16 = TWO ? 8192 : 4096;     // A region per buffer (u16)
    constexpr int BUF_U16 = A_U16 + BN * 32;     // per-buffer size (u16)
    __shared__ u16 smem[2 * BUF_U16];

    // XCD-contiguous remap (nwg always % 8 == 0)
    const int nwg = gridDim.x * gridDim.y;
    const int lin = blockIdx.y * gridDim.x + blockIdx.x;
    const int wg  = (lin & 7) * (nwg >> 3) + (lin >> 3);
    const int bm  = (wg / gridDim.x) << 7;
    const int bn  = (wg % gridDim.x) * BN;

    const int tid = threadIdx.x;
    const int w = tid >> 6, l = tid & 63;
    const int wr = w >> 1, wc = w & 1;

    const int grow = tid >> 2;
    const int gcol = (((tid & 3) ^ ((tid >> 3) & 3)) << 3);
    const size_t aoff0 = (size_t)(bm + grow) * K + gcol;
    const size_t boff0 = (size_t)(bn + grow) * K + gcol;
    const size_t s64 = (size_t)64 * K;
    char* sb0 = (char*)smem;
    char* sb1 = (char*)smem + 2 * BUF_U16;       // bytes = BUF_U16*2
    const uint32_t wq = (uint32_t)w << 10;

    auto stage = [&](char* sbuf, int k0) {
        gl_lds16(Ah + aoff0 + k0,       sbuf + 0    + wq);
        gl_lds16(Ah + aoff0 + s64 + k0, sbuf + 4096 + wq);
        if constexpr (TWO) {
            gl_lds16(Al + aoff0 + k0,       sbuf + 8192  + wq);
            gl_lds16(Al + aoff0 + s64 + k0, sbuf + 12288 + wq);
        }
        gl_lds16(Bh + boff0 + k0, sbuf + 2 * A_U16 + wq);
        if constexpr (BN == 128)
            gl_lds16(Bh + boff0 + s64 + k0, sbuf + 2 * A_U16 + 4096 + wq);
    };

    f32x4 acc[4][NJ] = {};

    const int key8 = (((l & 15) >> 1) & 3) << 3;
    const int kswz = ((l >> 4) << 3) ^ key8;
    const int arow = wr * 64 + (l & 15);
    const int brow = wc * (BN / 2) + (l & 15);
    const int nk = K >> 5;

    stage(sb0, 0);
    for (int kt = 0; kt < nk; ++kt) {
        char* cur = (kt & 1) ? sb1 : sb0;
        char* nxt = (kt & 1) ? sb0 : sb1;
        if (kt + 1 < nk) {
            stage(nxt, (kt + 1) << 5);
            if constexpr (TWO && BN == 128)
                asm volatile("s_waitcnt vmcnt(6)\n\ts_barrier" ::: "memory");
            else if constexpr (TWO)
                asm volatile("s_waitcnt vmcnt(5)\n\ts_barrier" ::: "memory");
            else if constexpr (BN == 128)
                asm volatile("s_waitcnt vmcnt(4)\n\ts_barrier" ::: "memory");
            else
                asm volatile("s_waitcnt vmcnt(3)\n\ts_barrier" ::: "memory");
        } else {
            asm volatile("s_waitcnt vmcnt(0)\n\ts_barrier" ::: "memory");
        }
        __builtin_amdgcn_sched_barrier(0);

        const u16* bu = (const u16*)cur;
        bf16x8 ah[4], al4[TWO ? 4 : 1], bh4[NJ];
        #pragma unroll
        for (int i = 0; i < 4; ++i) {
            ah[i] = *(const bf16x8*)&bu[(arow + i * 16) * 32 + kswz];
            if constexpr (TWO)
                al4[i] = *(const bf16x8*)&bu[4096 + (arow + i * 16) * 32 + kswz];
        }
        #pragma unroll
        for (int j = 0; j < NJ; ++j)
            bh4[j] = *(const bf16x8*)&bu[A_U16 + (brow + j * 16) * 32 + kswz];
        asm volatile("s_waitcnt lgkmcnt(0)" ::: "memory");
        __builtin_amdgcn_sched_barrier(0);
        asm volatile("s_barrier" ::: "memory");   // all waves done reading cur

        #pragma unroll
        for (int i = 0; i < 4; ++i) {
            #pragma unroll
            for (int j = 0; j < NJ; ++j) {
                acc[i][j] = mfma16(ah[i], bh4[j], acc[i][j]);
                if constexpr (TWO)
                    acc[i][j] = mfma16(al4[i], bh4[j], acc[i][j]);
            }
        }
    }

    // C/D frag: col = lane&15, row = (lane>>4)*4 + reg
    const int crow0 = bm + wr * 64 + ((l >> 4) << 2);
    const int ccol0 = bn + wc * (BN / 2) + (l & 15);
    #pragma unroll
    for (int i = 0; i < 4; ++i) {
        #pragma unroll
        for (int j = 0; j < NJ; ++j) {
            const int col = ccol0 + j * 16;
            #pragma unroll
            for (int r = 0; r < 4; ++r) {
                const int row = crow0 + i * 16 + r;
                const size_t o = (size_t)row * N + col;
                float v = acc[i][j][r];
                if (EPI == 1) {
                    Ch[o] = f2bf(gelu_fast(v));
                } else if (EPI == 2) {
                    Cf[o] += scale[col] * v;
                } else if (EPI == 4) {
                    Cf[o] = scale[col] * v;
                } else if (EPI == 3) {
                    const int which = (col >= 1536) ? 2 : ((col >= 768) ? 1 : 0);
                    const int hcol = col - which * 768;
                    const size_t dst = ((size_t)((row >> 10) * NHEAD + (hcol >> 6)) * 1024
                                        + (row & 1023)) * 64 + (hcol & 63);
                    if (which == 0) {
                        v *= 0.125f;
                        u16 hi, lo;
                        split_bf(v, hi, lo);
                        Qh[dst] = hi; Ql[dst] = lo;
                    } else if (which == 1) {
                        Kh[dst] = f2bf(v);
                    } else {
                        Vh[dst] = f2bf(v);
                    }
                }
            }
        }
    }
}

// --------------------------------------------------- MFMA flash attention
// Paired q-tiles {p, 15-p} share one K/V fragment stream. K hi-only
// (S = Kh*(Qh+Ql)); K AND V register double-buffered; defer-max (THR=8).
// ctx written as single bf16. P redistribution via register shuffles.
__global__ __launch_bounds__(256, 3)
void flash16(const u16* __restrict__ qh, const u16* __restrict__ ql,
             const u16* __restrict__ kh, const u16* __restrict__ vth,
             u16* __restrict__ ch) {
    const int id = blockIdx.x;
    const int r8 = id & 7, s = id >> 3;
    const int bh = r8 + 8 * (s >> 3);
    const int p  = s & 7;
    const int hh = bh % NHEAD, bb = bh / NHEAD;
    const int tid = threadIdx.x, w = tid >> 6, l = tid & 63;
    const int lq = l & 15, lg = l >> 4;
    const size_t hb = (size_t)bh << 16;

    const int wqA = p * 64 + w * 16;
    const int wqB = (15 - p) * 64 + w * 16;
    const int qA = wqA + lq, qB = wqB + lq;

    bf16x8 qA0, qA1, qA2, qA3, qB0, qB1, qB2, qB3;
    {
        const size_t qa = hb + ((size_t)qA << 6) + lg * 8;
        qA0 = *(const bf16x8*)(qh + qa);       qA1 = *(const bf16x8*)(ql + qa);
        qA2 = *(const bf16x8*)(qh + qa + 32);  qA3 = *(const bf16x8*)(ql + qa + 32);
        const size_t qb = hb + ((size_t)qB << 6) + lg * 8;
        qB0 = *(const bf16x8*)(qh + qb);       qB1 = *(const bf16x8*)(ql + qb);
        qB2 = *(const bf16x8*)(qh + qb + 32);  qB3 = *(const bf16x8*)(ql + qb + 32);
    }

    f32x4 oA[4] = {}, oB[4] = {};
    float mA = -30000.f, lsA = 0.f, mB = -30000.f, lsB = 0.f;
    const int ntiles = 32 - 2 * p;              // always even
    const int src0 = 32 * (lg & 1) + lq, src1 = src0 + 16;
    const bool hiHalf = lg >= 2;

    bf16x8 KA[4], KB[4], VA[4], VB[4];
    auto loadK = [&](bf16x8 (&K)[4], int k0) {
        const size_t kb0 = hb + (size_t)(k0 + lq) * 64 + lg * 8;
        const size_t kb1 = kb0 + 16 * 64;
        K[0] = *(const bf16x8*)(kh + kb0);
        K[1] = *(const bf16x8*)(kh + kb0 + 32);
        K[2] = *(const bf16x8*)(kh + kb1);
        K[3] = *(const bf16x8*)(kh + kb1 + 32);
    };
    auto loadV = [&](bf16x8 (&V)[4], int k0) {
        #pragma unroll
        for (int dt = 0; dt < 4; ++dt) {
            const size_t vb = hb + (size_t)(dt * 16 + lq) * 1024 + k0 + lg * 8;
            V[dt] = *(const bf16x8*)(vth + vb);
        }
    };

    auto path = [&](bf16x8 (&Kc)[4], bf16x8 (&vf)[4], int k0, int wqX, int qX,
                    bf16x8 q0, bf16x8 q1, bf16x8 q2, bf16x8 q3,
                    float& mX, float& lsX, f32x4 (&oX)[4]) {
        f32x4 s0 = {}, s1 = {};
        s0 = mfma16(Kc[0], q0, s0); s0 = mfma16(Kc[0], q1, s0);
        s0 = mfma16(Kc[1], q2, s0); s0 = mfma16(Kc[1], q3, s0);
        s1 = mfma16(Kc[2], q0, s1); s1 = mfma16(Kc[2], q1, s1);
        s1 = mfma16(Kc[3], q2, s1); s1 = mfma16(Kc[3], q3, s1);
        if (k0 + 31 > wqX) {
            #pragma unroll
            for (int r = 0; r < 4; ++r) {
                if (k0 + 4 * lg + r > qX)      s0[r] = -30000.f;
                if (k0 + 16 + 4 * lg + r > qX) s1[r] = -30000.f;
            }
        }
        float tmloc = fmaxf(fmaxf(fmaxf(s0[0], s0[1]), fmaxf(s0[2], s0[3])),
                            fmaxf(fmaxf(s1[0], s1[1]), fmaxf(s1[2], s1[3])));
        if (__any(tmloc > mX + 8.f)) {
            float tm = fmaxf(tmloc, __shfl_xor(tmloc, 16));
            tm = fmaxf(tm, __shfl_xor(tm, 32));
            const float mnew = fmaxf(mX, tm);
            const float fac = __expf(mX - mnew);
            mX = mnew;
            lsX *= fac;
            #pragma unroll
            for (int dt = 0; dt < 4; ++dt) {
                oX[dt][0] *= fac; oX[dt][1] *= fac;
                oX[dt][2] *= fac; oX[dt][3] *= fac;
            }
        }
        float ps = 0.f;
        #pragma unroll
        for (int r = 0; r < 4; ++r) {
            s0[r] = __expf(s0[r] - mX); ps += s0[r];
            s1[r] = __expf(s1[r] - mX); ps += s1[r];
        }
        lsX += ps;
        const uint32_t wA0 = cvt_pk_bf16(s0[0], s0[1]);
        const uint32_t wA1 = cvt_pk_bf16(s0[2], s0[3]);
        const uint32_t wB0 = cvt_pk_bf16(s1[0], s1[1]);
        const uint32_t wB1 = cvt_pk_bf16(s1[2], s1[3]);
        const uint32_t a0 = (uint32_t)__shfl((int)wA0, src0);
        const uint32_t b0 = (uint32_t)__shfl((int)wB0, src0);
        const uint32_t a1 = (uint32_t)__shfl((int)wA1, src0);
        const uint32_t b1 = (uint32_t)__shfl((int)wB1, src0);
        const uint32_t a2 = (uint32_t)__shfl((int)wA0, src1);
        const uint32_t b2 = (uint32_t)__shfl((int)wB0, src1);
        const uint32_t a3 = (uint32_t)__shfl((int)wA1, src1);
        const uint32_t b3 = (uint32_t)__shfl((int)wB1, src1);
        u32x4 pw = { hiHalf ? b0 : a0, hiHalf ? b1 : a1,
                     hiHalf ? b2 : a2, hiHalf ? b3 : a3 };
        const bf16x8 pb = __builtin_bit_cast(bf16x8, pw);
        #pragma unroll
        for (int dt = 0; dt < 4; ++dt)
            oX[dt] = mfma16(vf[dt], pb, oX[dt]);
    };

    auto step = [&](bf16x8 (&Kc)[4], bf16x8 (&Vc)[4],
                    bf16x8 (&Kn)[4], bf16x8 (&Vn)[4], int kt) {
        const int k0 = kt * 32;
        const int ktn = (kt + 1 < ntiles) ? kt + 1 : kt;
        loadK(Kn, ktn * 32);
        loadV(Vn, ktn * 32);
        if (k0 <= wqB + 15)
            path(Kc, Vc, k0, wqB, qB, qB0, qB1, qB2, qB3, mB, lsB, oB);
        if (k0 <= wqA + 15)
            path(Kc, Vc, k0, wqA, qA, qA0, qA1, qA2, qA3, mA, lsA, oA);
    };

    loadK(KA, 0);
    loadV(VA, 0);
    for (int kt = 0; kt < ntiles; kt += 2) {
        step(KA, VA, KB, VB, kt);
        step(KB, VB, KA, VA, kt + 1);
    }

    lsA += __shfl_xor(lsA, 16); lsA += __shfl_xor(lsA, 32);
    lsB += __shfl_xor(lsB, 16); lsB += __shfl_xor(lsB, 32);
    const float invA = 1.f / lsA, invB = 1.f / lsB;
    const size_t cbA = ((size_t)(bb * 1024 + qA)) * 768 + hh * 64;
    const size_t cbB = ((size_t)(bb * 1024 + qB)) * 768 + hh * 64;
    #pragma unroll
    for (int dt = 0; dt < 4; ++dt) {
        u16 h4[4];
        #pragma unroll
        for (int r = 0; r < 4; ++r) h4[r] = f2bf(oA[dt][r] * invA);
        size_t co = cbA + dt * 16 + 4 * lg;
        *(uint2*)&ch[co] = make_uint2((uint32_t)h4[0] | ((uint32_t)h4[1] << 16),
                                      (uint32_t)h4[2] | ((uint32_t)h4[3] << 16));
        #pragma unroll
        for (int r = 0; r < 4; ++r) h4[r] = f2bf(oB[dt][r] * invB);
        co = cbB + dt * 16 + 4 * lg;
        *(uint2*)&ch[co] = make_uint2((uint32_t)h4[0] | ((uint32_t)h4[1] << 16),
                                      (uint32_t)h4[2] | ((uint32_t)h4[3] << 16));
    }
}

// ------------------------------------------------------------------- host

extern "C" void kernel_launch(void* const* d_in, const int* in_sizes, int n_in,
                              void* d_out, int out_size, void* d_ws, size_t ws_size,
                              hipStream_t stream) {
    const float* x0     = (const float*)d_in[0];
    const float* aproj  = (const float*)d_in[1];
    const float* mproj  = (const float*)d_in[2];
    const float* Wqkv   = (const float*)d_in[3];
    const float* Wo     = (const float*)d_in[4];
    const float* Wm1    = (const float*)d_in[5];
    const float* Wm2    = (const float*)d_in[6];
    const float* ascale = (const float*)d_in[7];
    const float* mscale = (const float*)d_in[8];
    const float* lns    = (const float*)d_in[9];
    float* out = (float*)d_out;
    char*  base = (char*)d_ws;

    float* p1  = (float*)base;
    float* p2  = p1 + BTD;
    float* p3  = p2 + BTD;
    u16*   xnh = (u16*)(base + 12 * BTD);
    u16*   xnl = xnh + BTD;
    u16*   wth = (u16*)(base + 16 * BTD);           // 3072*768 u16 = 4.72 MB
    char*  QB  = base + 16 * BTD + (size_t)2 * 3072 * 768;
    // QB region: 5 consecutive BTD-u16 slots
    u16* qh   = (u16*)QB;        // slot 0
    u16* ql   = qh  + BTD;       // slot 1
    u16* kh   = ql  + BTD;       // slot 2
    u16* vh   = kh  + BTD;       // slot 3
    u16* vth  = vh  + BTD;       // slot 4
    u16* ctxh = vh;              // vh dead after vt_transpose
    u16* midh = qh;              // spans slots 0-3 (q/k/v dead after Wo)

    float* pb[3] = {p1, p2, p3};
    const float* hist[6];
    int nh = 1;
    hist[0] = x0;
    const float* partial_c = x0;
    float* partial_w = nullptr;
    int pidx = 0;

    auto launch_agg = [&](int n, const float* Vl6[6], const float* qvec,
                          const float* lnsl) {
        switch (n) {
        case 2: agg_norm_kernel<2><<<dim3(ROWS), 256, 0, stream>>>(Vl6[0], Vl6[1], Vl6[2], Vl6[3], Vl6[4], Vl6[5], qvec, lnsl, xnh, xnl); break;
        case 3: agg_norm_kernel<3><<<dim3(ROWS), 256, 0, stream>>>(Vl6[0], Vl6[1], Vl6[2], Vl6[3], Vl6[4], Vl6[5], qvec, lnsl, xnh, xnl); break;
        case 4: agg_norm_kernel<4><<<dim3(ROWS), 256, 0, stream>>>(Vl6[0], Vl6[1], Vl6[2], Vl6[3], Vl6[4], Vl6[5], qvec, lnsl, xnh, xnl); break;
        case 5: agg_norm_kernel<5><<<dim3(ROWS), 256, 0, stream>>>(Vl6[0], Vl6[1], Vl6[2], Vl6[3], Vl6[4], Vl6[5], qvec, lnsl, xnh, xnl); break;
        default: agg_norm_kernel<6><<<dim3(ROWS), 256, 0, stream>>>(Vl6[0], Vl6[1], Vl6[2], Vl6[3], Vl6[4], Vl6[5], qvec, lnsl, xnh, xnl); break;
        }
    };

    for (int l = 0; l < NLAYER; ++l) {
        // ---- attention-path aggregate (reads OLD partial) -> xn hi/lo
        const float* Vl6[6] = {nullptr, nullptr, nullptr, nullptr, nullptr, nullptr};
        for (int i = 0; i < nh; ++i) Vl6[i] = hist[i];
        Vl6[nh] = partial_c;
        launch_agg(nh + 1, Vl6, aproj + (size_t)l * D_MODEL, lns + l);

        // ---- block boundary (no fill: Wo EPI=4 initializes the new partial)
        const bool boundary = ((l & 1) == 0);
        if (boundary) {
            hist[nh++] = partial_c;
            float* np = (pidx < 3) ? pb[pidx] : out;
            ++pidx;
            partial_w = np;
            partial_c = np;
        }

        // ---- QKV GEMM -> head-major q (hi/lo), k/v (hi)
        transpose_split<<<dim3(D_MODEL / 32, 3 * D_MODEL / 32), 256, 0, stream>>>(
            Wqkv + (size_t)l * D_MODEL * 3 * D_MODEL, wth, D_MODEL, 3 * D_MODEL);
        gemm_bf2<3, 128, true><<<dim3(3 * D_MODEL / 128, ROWS / 128), 256, 0, stream>>>(
            xnh, xnl, wth, nullptr, nullptr, nullptr,
            ROWS, 3 * D_MODEL, D_MODEL, qh, ql, kh, vh);

        // ---- V transpose (hi only) -> vth
        vt_transpose<<<dim3(T_SEQ / 32, HDIM / 32, B_BATCH * NHEAD), 256, 0, stream>>>(
            vh, vth);

        // ---- flash attention -> ctx (single bf16, aliases vh)
        flash16<<<dim3(768), 256, 0, stream>>>(qh, ql, kh, vth, ctxh);

        // ---- Wo GEMM: partial (=|+=) attn_scale * (ctx @ Wo)
        transpose_split<<<dim3(D_MODEL / 32, D_MODEL / 32), 256, 0, stream>>>(
            Wo + (size_t)l * D_MODEL * D_MODEL, wth, D_MODEL, D_MODEL);
        if (boundary)
            gemm_bf2<4, 64, false><<<dim3(D_MODEL / 64, ROWS / 128), 256, 0, stream>>>(
                ctxh, nullptr, wth, partial_w, nullptr,
                ascale + (size_t)l * D_MODEL, ROWS, D_MODEL, D_MODEL,
                nullptr, nullptr, nullptr, nullptr);
        else
            gemm_bf2<2, 64, false><<<dim3(D_MODEL / 64, ROWS / 128), 256, 0, stream>>>(
                ctxh, nullptr, wth, partial_w, nullptr,
                ascale + (size_t)l * D_MODEL, ROWS, D_MODEL, D_MODEL,
                nullptr, nullptr, nullptr, nullptr);

        // ---- mlp-path aggregate (reads NEW partial) -> xn hi/lo
        const float* V26[6] = {nullptr, nullptr, nullptr, nullptr, nullptr, nullptr};
        for (int i = 0; i < nh; ++i) V26[i] = hist[i];
        V26[nh] = partial_c;
        launch_agg(nh + 1, V26, mproj + (size_t)l * D_MODEL, lns + l);

        // ---- MLP: mid = gelu(xn @ Wm1) single bf16; partial += mscale*(mid @ Wm2)
        transpose_split<<<dim3(D_MODEL / 32, 4 * D_MODEL / 32), 256, 0, stream>>>(
            Wm1 + (size_t)l * D_MODEL * 4 * D_MODEL, wth, D_MODEL, 4 * D_MODEL);
        gemm_bf2<1, 128, true><<<dim3(4 * D_MODEL / 128, ROWS / 128), 256, 0, stream>>>(
            xnh, xnl, wth, nullptr, midh,
            nullptr, ROWS, 4 * D_MODEL, D_MODEL,
            nullptr, nullptr, nullptr, nullptr);
        transpose_split<<<dim3(4 * D_MODEL / 32, D_MODEL / 32), 256, 0, stream>>>(
            Wm2 + (size_t)l * 4 * D_MODEL * D_MODEL, wth, 4 * D_MODEL, D_MODEL);
        gemm_bf2<2, 64, false><<<dim3(D_MODEL / 64, ROWS / 128), 256, 0, stream>>>(
            midh, nullptr, wth, partial_w, nullptr,
            mscale + (size_t)l * D_MODEL, ROWS, D_MODEL, 4 * D_MODEL,
            nullptr, nullptr, nullptr, nullptr);
    }
}

// Round 11
// 2862.467 us; speedup vs baseline: 6.9870x; 1.1535x over previous
//
#include <hip/hip_runtime.h>
#include <hip/hip_bf16.h>
#include <math.h>
#include <stdint.h>

#define D_MODEL 768
#define T_SEQ   1024
#define B_BATCH 8
#define NHEAD   12
#define HDIM    64
#define NLAYER  8

typedef unsigned short u16;
typedef __attribute__((ext_vector_type(8))) short bf16x8;
typedef __attribute__((ext_vector_type(4))) float f32x4;
typedef __attribute__((ext_vector_type(4))) uint32_t u32x4;

static constexpr size_t BTD  = (size_t)B_BATCH * T_SEQ * D_MODEL;  // 6291456
static constexpr int    ROWS = B_BATCH * T_SEQ;                    // 8192
static constexpr float  EPSF = 1.1920928955078125e-07f;            // FLT_EPSILON

// ---------------------------------------------------------------- helpers

__device__ __forceinline__ u16 f2bf(float x) {
    __hip_bfloat16 h = __float2bfloat16(x);
    return __builtin_bit_cast(u16, h);
}
__device__ __forceinline__ float bf2f(u16 u) {
    __hip_bfloat16 h = __builtin_bit_cast(__hip_bfloat16, u);
    return __bfloat162float(h);
}
__device__ __forceinline__ void split_bf(float x, u16& hi, u16& lo) {
    hi = f2bf(x);
    lo = f2bf(x - bf2f(hi));
}
__device__ __forceinline__ uint32_t cvt_pk_bf16(float a, float b) {
    uint32_t r;
    asm("v_cvt_pk_bf16_f32 %0, %1, %2" : "=v"(r) : "v"(a), "v"(b));
    return r;
}
__device__ __forceinline__ f32x4 mfma16(bf16x8 a, bf16x8 b, f32x4 c) {
    return __builtin_amdgcn_mfma_f32_16x16x32_bf16(a, b, c, 0, 0, 0);
}

// async global->LDS, 16B/lane; LDS dest wave-uniform base (HW adds lane*16)
__device__ __forceinline__ void gl_lds16(const void* g, void* l) {
    auto gp = reinterpret_cast<const __attribute__((address_space(1))) char*>(
        reinterpret_cast<uintptr_t>(g));
    auto lp = reinterpret_cast<__attribute__((address_space(3))) char*>(
        static_cast<uint32_t>(reinterpret_cast<uintptr_t>(l)));
    __builtin_amdgcn_global_load_lds(gp, lp, 16, 0, 0);
}

__device__ __forceinline__ float block_reduce_sum(float v, float* sbuf) {
    #pragma unroll
    for (int off = 32; off > 0; off >>= 1) v += __shfl_down(v, off);
    __syncthreads();
    if ((threadIdx.x & 63) == 0) sbuf[threadIdx.x >> 6] = v;
    __syncthreads();
    return sbuf[0] + sbuf[1] + sbuf[2] + sbuf[3];
}

// tanh-gelu via exp: 0.5x(1+tanh(z)) = x - x/(exp(2z)+1); exact at +-inf
__device__ __forceinline__ float gelu_fast(float x) {
    float z = 0.7978845608028654f * (x + 0.044715f * x * x * x);
    float e = __expf(2.f * z);
    return x - x / (e + 1.f);
}

// ------------------------------------------------- aggregate + rmsnorm fuse
template<int N>
__global__ __launch_bounds__(256)
void agg_norm_kernel(const float* __restrict__ v0, const float* __restrict__ v1,
                     const float* __restrict__ v2, const float* __restrict__ v3,
                     const float* __restrict__ v4, const float* __restrict__ v5,
                     const float* __restrict__ q,  const float* __restrict__ lns,
                     u16* __restrict__ xh) {
    __shared__ float sbuf[4];
    const float* V[6] = {v0, v1, v2, v3, v4, v5};
    const size_t row = blockIdx.x;
    const int tid = threadIdx.x;

    float qv[3];
    #pragma unroll
    for (int j = 0; j < 3; ++j) qv[j] = q[tid + j * 256];

    float vv[N][3];
    float logits[N];
    #pragma unroll
    for (int i = 0; i < N; ++i) {
        const float* vr = V[i] + row * D_MODEL;
        float ssq = 0.f, qd = 0.f;
        #pragma unroll
        for (int j = 0; j < 3; ++j) {
            float x = vr[tid + j * 256];
            vv[i][j] = x;
            ssq = fmaf(x, x, ssq);
            qd  = fmaf(qv[j], x, qd);
        }
        float S  = block_reduce_sum(ssq, sbuf);
        float Qd = block_reduce_sum(qd,  sbuf);
        logits[i] = Qd * rsqrtf(S * (1.f / 768.f) + EPSF);
    }
    float mx = logits[0];
    #pragma unroll
    for (int i = 1; i < N; ++i) mx = fmaxf(mx, logits[i]);
    float w[N];
    float wsum = 0.f;
    #pragma unroll
    for (int i = 0; i < N; ++i) { w[i] = __expf(logits[i] - mx); wsum += w[i]; }
    float inv = 1.f / wsum;

    float outv[3] = {0.f, 0.f, 0.f};
    #pragma unroll
    for (int i = 0; i < N; ++i) {
        float wi = w[i] * inv;
        #pragma unroll
        for (int j = 0; j < 3; ++j) outv[j] = fmaf(wi, vv[i][j], outv[j]);
    }
    float ssq = 0.f;
    #pragma unroll
    for (int j = 0; j < 3; ++j) ssq = fmaf(outv[j], outv[j], ssq);
    float S2 = block_reduce_sum(ssq, sbuf);
    float scale = lns[0] * rsqrtf(S2 * (1.f / 768.f) + EPSF);
    #pragma unroll
    for (int j = 0; j < 3; ++j)
        xh[row * D_MODEL + tid + j * 256] = f2bf(outv[j] * scale);
}

// ---------------------------------------------- fused per-layer weight transpose
// 4 matrices W[K][N] fp32 -> Th[N][K] bf16 in one dispatch.
// segments (32x32 tiles): qkv 24x72=1728 | o 24x24=576 | m1 24x96=2304 | m2 96x24=2304
__global__ __launch_bounds__(256)
void transpose_all(const float* __restrict__ Wqkv, const float* __restrict__ Wo,
                   const float* __restrict__ Wm1,  const float* __restrict__ Wm2,
                   u16* __restrict__ T0, u16* __restrict__ T1,
                   u16* __restrict__ T2, u16* __restrict__ T3) {
    const int id = blockIdx.x;
    const float* W; u16* Th; int K, N, t;
    if (id < 1728)      { W = Wqkv; Th = T0; K = 768;  N = 2304; t = id; }
    else if (id < 2304) { W = Wo;   Th = T1; K = 768;  N = 768;  t = id - 1728; }
    else if (id < 4608) { W = Wm1;  Th = T2; K = 768;  N = 3072; t = id - 2304; }
    else                { W = Wm2;  Th = T3; K = 3072; N = 768;  t = id - 4608; }
    const int nk = K >> 5;
    const int bk = (t % nk) * 32, bn = (t / nk) * 32;

    __shared__ float tt[32][33];
    const int r = threadIdx.x >> 3, c4 = (threadIdx.x & 7) * 4;
    float4 v = *(const float4*)&W[(size_t)(bk + r) * N + bn + c4];
    tt[r][c4 + 0] = v.x; tt[r][c4 + 1] = v.y; tt[r][c4 + 2] = v.z; tt[r][c4 + 3] = v.w;
    __syncthreads();
    u16 h[4];
    #pragma unroll
    for (int j = 0; j < 4; ++j) h[j] = f2bf(tt[c4 + j][r]);
    size_t o = (size_t)(bn + r) * K + bk + c4;
    *(uint2*)&Th[o] = make_uint2((uint32_t)h[0] | ((uint32_t)h[1] << 16),
                                 (uint32_t)h[2] | ((uint32_t)h[3] << 16));
}

// ---------------------------------------------- V transpose (head-major, hi only)
__global__ __launch_bounds__(256)
void vt_transpose(const u16* __restrict__ vh, u16* __restrict__ vth) {
    __shared__ u16 th[32][36];
    const int bh = blockIdx.z;
    const int t0 = blockIdx.x * 32, d0 = blockIdx.y * 32;
    const int r = threadIdx.x >> 3, c = (threadIdx.x & 7) * 4;
    const size_t ib = ((size_t)(bh << 10) + t0 + r) * 64 + d0 + c;
    *(uint2*)&th[r][c] = *(const uint2*)&vh[ib];
    __syncthreads();
    const size_t ob = ((size_t)(bh << 6) + d0 + r) * 1024 + t0 + c;
    u16 a0 = th[c + 0][r], a1 = th[c + 1][r], a2 = th[c + 2][r], a3 = th[c + 3][r];
    *(uint2*)&vth[ob] = make_uint2((uint32_t)a0 | ((uint32_t)a1 << 16),
                                   (uint32_t)a2 | ((uint32_t)a3 << 16));
}

// ------------------------------------------------- bf16 MFMA GEMM (1-term)
// C[M,N] = Ah[M,K] @ Bh^T (B given as [N][K]).
// Prefetch-pipelined: LDS double-buffer, counted vmcnt + raw barriers.
// EPI: 1 = gelu -> bf16, 2 = Cf += scale[n]*acc, 4 = Cf = scale[n]*acc,
//      3 = scatter qkv (q*0.125) into head-major buffers (Q hi/lo, K/V hi)
template<int EPI, int BN>
__global__ __launch_bounds__(256)
void gemm_bf1(const u16* __restrict__ Ah, const u16* __restrict__ Bh,
              float* __restrict__ Cf, u16* __restrict__ Ch,
              const float* __restrict__ scale, int M, int N, int K,
              u16* __restrict__ Qh, u16* __restrict__ Ql,
              u16* __restrict__ Kh, u16* __restrict__ Vh) {
    constexpr int NJ = BN / 32;
    constexpr int BUF_U16 = 4096 + BN * 32;      // per-buffer size (u16)
    __shared__ u16 smem[2 * BUF_U16];

    // XCD-contiguous remap (nwg always % 8 == 0)
    const int nwg = gridDim.x * gridDim.y;
    const int lin = blockIdx.y * gridDim.x + blockIdx.x;
    const int wg  = (lin & 7) * (nwg >> 3) + (lin >> 3);
    const int bm  = (wg / gridDim.x) << 7;
    const int bn  = (wg % gridDim.x) * BN;

    const int tid = threadIdx.x;
    const int w = tid >> 6, l = tid & 63;
    const int wr = w >> 1, wc = w & 1;

    const int grow = tid >> 2;
    const int gcol = (((tid & 3) ^ ((tid >> 3) & 3)) << 3);
    const size_t aoff0 = (size_t)(bm + grow) * K + gcol;
    const size_t boff0 = (size_t)(bn + grow) * K + gcol;
    const size_t s64 = (size_t)64 * K;
    char* sb0 = (char*)smem;
    char* sb1 = (char*)smem + 2 * BUF_U16;       // bytes
    const uint32_t wq = (uint32_t)w << 10;

    auto stage = [&](char* sbuf, int k0) {
        gl_lds16(Ah + aoff0 + k0,       sbuf + 0    + wq);
        gl_lds16(Ah + aoff0 + s64 + k0, sbuf + 4096 + wq);
        gl_lds16(Bh + boff0 + k0,       sbuf + 8192 + wq);
        if constexpr (BN == 128)
            gl_lds16(Bh + boff0 + s64 + k0, sbuf + 12288 + wq);
    };

    f32x4 acc[4][NJ] = {};

    const int key8 = (((l & 15) >> 1) & 3) << 3;
    const int kswz = ((l >> 4) << 3) ^ key8;
    const int arow = wr * 64 + (l & 15);
    const int brow = wc * (BN / 2) + (l & 15);
    const int nk = K >> 5;

    stage(sb0, 0);
    for (int kt = 0; kt < nk; ++kt) {
        char* cur = (kt & 1) ? sb1 : sb0;
        char* nxt = (kt & 1) ? sb0 : sb1;
        if (kt + 1 < nk) {
            stage(nxt, (kt + 1) << 5);
            if constexpr (BN == 128)
                asm volatile("s_waitcnt vmcnt(4)\n\ts_barrier" ::: "memory");
            else
                asm volatile("s_waitcnt vmcnt(3)\n\ts_barrier" ::: "memory");
        } else {
            asm volatile("s_waitcnt vmcnt(0)\n\ts_barrier" ::: "memory");
        }
        __builtin_amdgcn_sched_barrier(0);

        const u16* bu = (const u16*)cur;
        bf16x8 ah[4], bh4[NJ];
        #pragma unroll
        for (int i = 0; i < 4; ++i)
            ah[i] = *(const bf16x8*)&bu[(arow + i * 16) * 32 + kswz];
        #pragma unroll
        for (int j = 0; j < NJ; ++j)
            bh4[j] = *(const bf16x8*)&bu[4096 + (brow + j * 16) * 32 + kswz];
        asm volatile("s_waitcnt lgkmcnt(0)" ::: "memory");
        __builtin_amdgcn_sched_barrier(0);
        asm volatile("s_barrier" ::: "memory");   // all waves done reading cur

        #pragma unroll
        for (int i = 0; i < 4; ++i) {
            #pragma unroll
            for (int j = 0; j < NJ; ++j)
                acc[i][j] = mfma16(ah[i], bh4[j], acc[i][j]);
        }
    }

    // C/D frag: col = lane&15, row = (lane>>4)*4 + reg
    const int crow0 = bm + wr * 64 + ((l >> 4) << 2);
    const int ccol0 = bn + wc * (BN / 2) + (l & 15);
    #pragma unroll
    for (int i = 0; i < 4; ++i) {
        #pragma unroll
        for (int j = 0; j < NJ; ++j) {
            const int col = ccol0 + j * 16;
            #pragma unroll
            for (int r = 0; r < 4; ++r) {
                const int row = crow0 + i * 16 + r;
                const size_t o = (size_t)row * N + col;
                float v = acc[i][j][r];
                if (EPI == 1) {
                    Ch[o] = f2bf(gelu_fast(v));
                } else if (EPI == 2) {
                    Cf[o] += scale[col] * v;
                } else if (EPI == 4) {
                    Cf[o] = scale[col] * v;
                } else if (EPI == 3) {
                    const int which = (col >= 1536) ? 2 : ((col >= 768) ? 1 : 0);
                    const int hcol = col - which * 768;
                    const size_t dst = ((size_t)((row >> 10) * NHEAD + (hcol >> 6)) * 1024
                                        + (row & 1023)) * 64 + (hcol & 63);
                    if (which == 0) {
                        v *= 0.125f;
                        u16 hi, lo;
                        split_bf(v, hi, lo);
                        Qh[dst] = hi; Ql[dst] = lo;
                    } else if (which == 1) {
                        Kh[dst] = f2bf(v);
                    } else {
                        Vh[dst] = f2bf(v);
                    }
                }
            }
        }
    }
}

// --------------------------------------------------- MFMA flash attention
// Paired q-tiles {p, 15-p} share one K/V fragment stream. K hi-only
// (S = Kh*(Qh+Ql)); K AND V register double-buffered; defer-max (THR=8).
// ctx written as single bf16. P redistribution via register shuffles.
__global__ __launch_bounds__(256, 3)
void flash16(const u16* __restrict__ qh, const u16* __restrict__ ql,
             const u16* __restrict__ kh, const u16* __restrict__ vth,
             u16* __restrict__ ch) {
    const int id = blockIdx.x;
    const int r8 = id & 7, s = id >> 3;
    const int bh = r8 + 8 * (s >> 3);
    const int p  = s & 7;
    const int hh = bh % NHEAD, bb = bh / NHEAD;
    const int tid = threadIdx.x, w = tid >> 6, l = tid & 63;
    const int lq = l & 15, lg = l >> 4;
    const size_t hb = (size_t)bh << 16;

    const int wqA = p * 64 + w * 16;
    const int wqB = (15 - p) * 64 + w * 16;
    const int qA = wqA + lq, qB = wqB + lq;

    bf16x8 qA0, qA1, qA2, qA3, qB0, qB1, qB2, qB3;
    {
        const size_t qa = hb + ((size_t)qA << 6) + lg * 8;
        qA0 = *(const bf16x8*)(qh + qa);       qA1 = *(const bf16x8*)(ql + qa);
        qA2 = *(const bf16x8*)(qh + qa + 32);  qA3 = *(const bf16x8*)(ql + qa + 32);
        const size_t qb = hb + ((size_t)qB << 6) + lg * 8;
        qB0 = *(const bf16x8*)(qh + qb);       qB1 = *(const bf16x8*)(ql + qb);
        qB2 = *(const bf16x8*)(qh + qb + 32);  qB3 = *(const bf16x8*)(ql + qb + 32);
    }

    f32x4 oA[4] = {}, oB[4] = {};
    float mA = -30000.f, lsA = 0.f, mB = -30000.f, lsB = 0.f;
    const int ntiles = 32 - 2 * p;              // always even
    const int src0 = 32 * (lg & 1) + lq, src1 = src0 + 16;
    const bool hiHalf = lg >= 2;

    bf16x8 KA[4], KB[4], VA[4], VB[4];
    auto loadK = [&](bf16x8 (&K)[4], int k0) {
        const size_t kb0 = hb + (size_t)(k0 + lq) * 64 + lg * 8;
        const size_t kb1 = kb0 + 16 * 64;
        K[0] = *(const bf16x8*)(kh + kb0);
        K[1] = *(const bf16x8*)(kh + kb0 + 32);
        K[2] = *(const bf16x8*)(kh + kb1);
        K[3] = *(const bf16x8*)(kh + kb1 + 32);
    };
    auto loadV = [&](bf16x8 (&V)[4], int k0) {
        #pragma unroll
        for (int dt = 0; dt < 4; ++dt) {
            const size_t vb = hb + (size_t)(dt * 16 + lq) * 1024 + k0 + lg * 8;
            V[dt] = *(const bf16x8*)(vth + vb);
        }
    };

    auto path = [&](bf16x8 (&Kc)[4], bf16x8 (&vf)[4], int k0, int wqX, int qX,
                    bf16x8 q0, bf16x8 q1, bf16x8 q2, bf16x8 q3,
                    float& mX, float& lsX, f32x4 (&oX)[4]) {
        f32x4 s0 = {}, s1 = {};
        s0 = mfma16(Kc[0], q0, s0); s0 = mfma16(Kc[0], q1, s0);
        s0 = mfma16(Kc[1], q2, s0); s0 = mfma16(Kc[1], q3, s0);
        s1 = mfma16(Kc[2], q0, s1); s1 = mfma16(Kc[2], q1, s1);
        s1 = mfma16(Kc[3], q2, s1); s1 = mfma16(Kc[3], q3, s1);
        if (k0 + 31 > wqX) {
            #pragma unroll
            for (int r = 0; r < 4; ++r) {
                if (k0 + 4 * lg + r > qX)      s0[r] = -30000.f;
                if (k0 + 16 + 4 * lg + r > qX) s1[r] = -30000.f;
            }
        }
        float tmloc = fmaxf(fmaxf(fmaxf(s0[0], s0[1]), fmaxf(s0[2], s0[3])),
                            fmaxf(fmaxf(s1[0], s1[1]), fmaxf(s1[2], s1[3])));
        if (__any(tmloc > mX + 8.f)) {
            float tm = fmaxf(tmloc, __shfl_xor(tmloc, 16));
            tm = fmaxf(tm, __shfl_xor(tm, 32));
            const float mnew = fmaxf(mX, tm);
            const float fac = __expf(mX - mnew);
            mX = mnew;
            lsX *= fac;
            #pragma unroll
            for (int dt = 0; dt < 4; ++dt) {
                oX[dt][0] *= fac; oX[dt][1] *= fac;
                oX[dt][2] *= fac; oX[dt][3] *= fac;
            }
        }
        float ps = 0.f;
        #pragma unroll
        for (int r = 0; r < 4; ++r) {
            s0[r] = __expf(s0[r] - mX); ps += s0[r];
            s1[r] = __expf(s1[r] - mX); ps += s1[r];
        }
        lsX += ps;
        const uint32_t wA0 = cvt_pk_bf16(s0[0], s0[1]);
        const uint32_t wA1 = cvt_pk_bf16(s0[2], s0[3]);
        const uint32_t wB0 = cvt_pk_bf16(s1[0], s1[1]);
        const uint32_t wB1 = cvt_pk_bf16(s1[2], s1[3]);
        const uint32_t a0 = (uint32_t)__shfl((int)wA0, src0);
        const uint32_t b0 = (uint32_t)__shfl((int)wB0, src0);
        const uint32_t a1 = (uint32_t)__shfl((int)wA1, src0);
        const uint32_t b1 = (uint32_t)__shfl((int)wB1, src0);
        const uint32_t a2 = (uint32_t)__shfl((int)wA0, src1);
        const uint32_t b2 = (uint32_t)__shfl((int)wB0, src1);
        const uint32_t a3 = (uint32_t)__shfl((int)wA1, src1);
        const uint32_t b3 = (uint32_t)__shfl((int)wB1, src1);
        u32x4 pw = { hiHalf ? b0 : a0, hiHalf ? b1 : a1,
                     hiHalf ? b2 : a2, hiHalf ? b3 : a3 };
        const bf16x8 pb = __builtin_bit_cast(bf16x8, pw);
        #pragma unroll
        for (int dt = 0; dt < 4; ++dt)
            oX[dt] = mfma16(vf[dt], pb, oX[dt]);
    };

    auto step = [&](bf16x8 (&Kc)[4], bf16x8 (&Vc)[4],
                    bf16x8 (&Kn)[4], bf16x8 (&Vn)[4], int kt) {
        const int k0 = kt * 32;
        const int ktn = (kt + 1 < ntiles) ? kt + 1 : kt;
        loadK(Kn, ktn * 32);
        loadV(Vn, ktn * 32);
        if (k0 <= wqB + 15)
            path(Kc, Vc, k0, wqB, qB, qB0, qB1, qB2, qB3, mB, lsB, oB);
        if (k0 <= wqA + 15)
            path(Kc, Vc, k0, wqA, qA, qA0, qA1, qA2, qA3, mA, lsA, oA);
    };

    loadK(KA, 0);
    loadV(VA, 0);
    for (int kt = 0; kt < ntiles; kt += 2) {
        step(KA, VA, KB, VB, kt);
        step(KB, VB, KA, VA, kt + 1);
    }

    lsA += __shfl_xor(lsA, 16); lsA += __shfl_xor(lsA, 32);
    lsB += __shfl_xor(lsB, 16); lsB += __shfl_xor(lsB, 32);
    const float invA = 1.f / lsA, invB = 1.f / lsB;
    const size_t cbA = ((size_t)(bb * 1024 + qA)) * 768 + hh * 64;
    const size_t cbB = ((size_t)(bb * 1024 + qB)) * 768 + hh * 64;
    #pragma unroll
    for (int dt = 0; dt < 4; ++dt) {
        u16 h4[4];
        #pragma unroll
        for (int r = 0; r < 4; ++r) h4[r] = f2bf(oA[dt][r] * invA);
        size_t co = cbA + dt * 16 + 4 * lg;
        *(uint2*)&ch[co] = make_uint2((uint32_t)h4[0] | ((uint32_t)h4[1] << 16),
                                      (uint32_t)h4[2] | ((uint32_t)h4[3] << 16));
        #pragma unroll
        for (int r = 0; r < 4; ++r) h4[r] = f2bf(oB[dt][r] * invB);
        co = cbB + dt * 16 + 4 * lg;
        *(uint2*)&ch[co] = make_uint2((uint32_t)h4[0] | ((uint32_t)h4[1] << 16),
                                      (uint32_t)h4[2] | ((uint32_t)h4[3] << 16));
    }
}

// ------------------------------------------------------------------- host

extern "C" void kernel_launch(void* const* d_in, const int* in_sizes, int n_in,
                              void* d_out, int out_size, void* d_ws, size_t ws_size,
                              hipStream_t stream) {
    const float* x0     = (const float*)d_in[0];
    const float* aproj  = (const float*)d_in[1];
    const float* mproj  = (const float*)d_in[2];
    const float* Wqkv   = (const float*)d_in[3];
    const float* Wo     = (const float*)d_in[4];
    const float* Wm1    = (const float*)d_in[5];
    const float* Wm2    = (const float*)d_in[6];
    const float* ascale = (const float*)d_in[7];
    const float* mscale = (const float*)d_in[8];
    const float* lns    = (const float*)d_in[9];
    float* out = (float*)d_out;
    char*  base = (char*)d_ws;

    float* p1  = (float*)base;
    float* p2  = p1 + BTD;
    float* p3  = p2 + BTD;
    u16*   xnh = (u16*)(base + 12 * BTD);
    // weight transpose buffers (u16 counts): qkv 1769472 | o 589824 | m1 2359296 | m2 2359296
    u16*   wt0 = (u16*)(base + 14 * BTD);
    u16*   wt1 = wt0 + (size_t)2304 * 768;
    u16*   wt2 = wt1 + (size_t)768 * 768;
    u16*   wt3 = wt2 + (size_t)3072 * 768;
    char*  QB  = (char*)(wt3 + (size_t)768 * 3072);
    u16* qh   = (u16*)QB;        // slot 0
    u16* ql   = qh  + BTD;       // slot 1
    u16* kh   = ql  + BTD;       // slot 2
    u16* vh   = kh  + BTD;       // slot 3
    u16* vth  = vh  + BTD;       // slot 4
    u16* ctxh = vh;              // vh dead after vt_transpose
    u16* midh = qh;              // spans slots 0-3 (q/k/v dead after Wo)

    float* pb[3] = {p1, p2, p3};
    const float* hist[6];
    int nh = 1;
    hist[0] = x0;
    const float* partial_c = x0;
    float* partial_w = nullptr;
    int pidx = 0;

    auto launch_agg = [&](int n, const float* Vl6[6], const float* qvec,
                          const float* lnsl) {
        switch (n) {
        case 2: agg_norm_kernel<2><<<dim3(ROWS), 256, 0, stream>>>(Vl6[0], Vl6[1], Vl6[2], Vl6[3], Vl6[4], Vl6[5], qvec, lnsl, xnh); break;
        case 3: agg_norm_kernel<3><<<dim3(ROWS), 256, 0, stream>>>(Vl6[0], Vl6[1], Vl6[2], Vl6[3], Vl6[4], Vl6[5], qvec, lnsl, xnh); break;
        case 4: agg_norm_kernel<4><<<dim3(ROWS), 256, 0, stream>>>(Vl6[0], Vl6[1], Vl6[2], Vl6[3], Vl6[4], Vl6[5], qvec, lnsl, xnh); break;
        case 5: agg_norm_kernel<5><<<dim3(ROWS), 256, 0, stream>>>(Vl6[0], Vl6[1], Vl6[2], Vl6[3], Vl6[4], Vl6[5], qvec, lnsl, xnh); break;
        default: agg_norm_kernel<6><<<dim3(ROWS), 256, 0, stream>>>(Vl6[0], Vl6[1], Vl6[2], Vl6[3], Vl6[4], Vl6[5], qvec, lnsl, xnh); break;
        }
    };

    for (int l = 0; l < NLAYER; ++l) {
        // ---- all 4 weight transposes in one dispatch (independent of aggs)
        transpose_all<<<dim3(6912), 256, 0, stream>>>(
            Wqkv + (size_t)l * D_MODEL * 3 * D_MODEL,
            Wo   + (size_t)l * D_MODEL * D_MODEL,
            Wm1  + (size_t)l * D_MODEL * 4 * D_MODEL,
            Wm2  + (size_t)l * 4 * D_MODEL * D_MODEL,
            wt0, wt1, wt2, wt3);

        // ---- attention-path aggregate (reads OLD partial) -> xn (bf16)
        const float* Vl6[6] = {nullptr, nullptr, nullptr, nullptr, nullptr, nullptr};
        for (int i = 0; i < nh; ++i) Vl6[i] = hist[i];
        Vl6[nh] = partial_c;
        launch_agg(nh + 1, Vl6, aproj + (size_t)l * D_MODEL, lns + l);

        // ---- block boundary (no fill: Wo EPI=4 initializes the new partial)
        const bool boundary = ((l & 1) == 0);
        if (boundary) {
            hist[nh++] = partial_c;
            float* np = (pidx < 3) ? pb[pidx] : out;
            ++pidx;
            partial_w = np;
            partial_c = np;
        }

        // ---- QKV GEMM -> head-major q (hi/lo), k/v (hi)
        gemm_bf1<3, 128><<<dim3(3 * D_MODEL / 128, ROWS / 128), 256, 0, stream>>>(
            xnh, wt0, nullptr, nullptr, nullptr,
            ROWS, 3 * D_MODEL, D_MODEL, qh, ql, kh, vh);

        // ---- V transpose (hi only) -> vth
        vt_transpose<<<dim3(T_SEQ / 32, HDIM / 32, B_BATCH * NHEAD), 256, 0, stream>>>(
            vh, vth);

        // ---- flash attention -> ctx (single bf16, aliases vh)
        flash16<<<dim3(768), 256, 0, stream>>>(qh, ql, kh, vth, ctxh);

        // ---- Wo GEMM: partial (=|+=) attn_scale * (ctx @ Wo)
        if (boundary)
            gemm_bf1<4, 64><<<dim3(D_MODEL / 64, ROWS / 128), 256, 0, stream>>>(
                ctxh, wt1, partial_w, nullptr,
                ascale + (size_t)l * D_MODEL, ROWS, D_MODEL, D_MODEL,
                nullptr, nullptr, nullptr, nullptr);
        else
            gemm_bf1<2, 64><<<dim3(D_MODEL / 64, ROWS / 128), 256, 0, stream>>>(
                ctxh, wt1, partial_w, nullptr,
                ascale + (size_t)l * D_MODEL, ROWS, D_MODEL, D_MODEL,
                nullptr, nullptr, nullptr, nullptr);

        // ---- mlp-path aggregate (reads NEW partial) -> xn (bf16)
        const float* V26[6] = {nullptr, nullptr, nullptr, nullptr, nullptr, nullptr};
        for (int i = 0; i < nh; ++i) V26[i] = hist[i];
        V26[nh] = partial_c;
        launch_agg(nh + 1, V26, mproj + (size_t)l * D_MODEL, lns + l);

        // ---- MLP: mid = gelu(xn @ Wm1) bf16; partial += mscale*(mid @ Wm2)
        gemm_bf1<1, 128><<<dim3(4 * D_MODEL / 128, ROWS / 128), 256, 0, stream>>>(
            xnh, wt2, nullptr, midh,
            nullptr, ROWS, 4 * D_MODEL, D_MODEL,
            nullptr, nullptr, nullptr, nullptr);
        gemm_bf1<2, 64><<<dim3(D_MODEL / 64, ROWS / 128), 256, 0, stream>>>(
            midh, wt3, partial_w, nullptr,
            mscale + (size_t)l * D_MODEL, ROWS, D_MODEL, 4 * D_MODEL,
            nullptr, nullptr, nullptr, nullptr);
    }
}